// Round 3
// baseline (1630.106 us; speedup 1.0000x reference)
//
#include <hip/hip_runtime.h>
#include <hip/hip_bf16.h>

typedef __hip_bfloat16 bf16;
typedef unsigned short ushort_t;
typedef unsigned int uint_t;
typedef __attribute__((ext_vector_type(8))) short short8;
typedef __attribute__((ext_vector_type(4))) float floatx4;

__device__ __forceinline__ float b2f(bf16 x) { return __bfloat162float(x); }
__device__ __forceinline__ ushort_t f2us(float f) { bf16 h = __float2bfloat16(f); return *(ushort_t*)&h; }
__device__ __forceinline__ float us2f(ushort_t u) { return __uint_as_float(((uint_t)u) << 16); }

constexpr int Bc = 4, Tc = 1024, Dc = 512, Hc = 8, HDc = 64;
constexpr int LCc = 128, MPc = 192;
constexpr float EPSc = 1e-4f;
constexpr int NBT = Bc * Tc;
constexpr long NE = (long)NBT * Dc;
constexpr float NEGB = -1e30f;

__device__ __forceinline__ float wload(const void* p, long i, int f32) {
  return f32 ? ((const float*)p)[i] : b2f(((const bf16*)p)[i]);
}

// ---------------- dtype detector ----------------
__global__ void k_detect(const void* __restrict__ x, int* __restrict__ flag) {
  __shared__ int s[256];
  int t = threadIdx.x;
  const unsigned short* u = (const unsigned short*)x;
  int bad = 0;
  for (int j = t; j < 2048; j += 256) {
    int e = (u[j] >> 7) & 0xFF;
    if (e == 0xFF || e > 0x8F || (e != 0 && e < 0x6F)) bad++;
  }
  s[t] = bad;
  __syncthreads();
  for (int off = 128; off > 0; off >>= 1) { if (t < off) s[t] += s[t + off]; __syncthreads(); }
  if (t == 0) flag[0] = (s[0] > 16) ? 1 : 0;
}

__global__ void k_in(const void* __restrict__ in, float* __restrict__ out, int n,
                     const int* __restrict__ flag) {
  int i = blockIdx.x * 256 + threadIdx.x;
  if (i < n) out[i] = wload(in, i, flag[0]);
}
__global__ void k_out(const float* __restrict__ in, void* __restrict__ out, int n,
                      const int* __restrict__ flag) {
  int i = blockIdx.x * 256 + threadIdx.x;
  if (i >= n) return;
  if (flag[0]) ((float*)out)[i] = in[i];
  else         ((bf16*)out)[i] = __float2bfloat16(in[i]);
}
// convert any weight tensor to bf16 workspace copy
__global__ void k_w2b(const void* __restrict__ src, ushort_t* __restrict__ dst, int n,
                      const int* __restrict__ flag) {
  int i = blockIdx.x * 256 + threadIdx.x;
  if (i < n) dst[i] = f2us(wload(src, i, flag[0]));
}

// ---------------- LayerNorm: writes f32 (residual addend) + bf16 (GEMM A) ----------------
__global__ __launch_bounds__(256) void k_ln(const float* __restrict__ x,
    const void* __restrict__ w, const void* __restrict__ bb, long woff,
    float* __restrict__ o, ushort_t* __restrict__ oA, const int* __restrict__ flag) {
  int f32 = flag[0];
  int row = blockIdx.x;
  int t = threadIdx.x;
  const float* xr = x + (long)row * Dc;
  float x0 = xr[t], x1 = xr[t + 256];
  __shared__ float red[256];
  red[t] = x0 + x1;
  __syncthreads();
  for (int off = 128; off > 0; off >>= 1) { if (t < off) red[t] += red[t + off]; __syncthreads(); }
  float mean = red[0] * (1.0f / Dc);
  __syncthreads();
  float d0 = x0 - mean, d1 = x1 - mean;
  red[t] = d0 * d0 + d1 * d1;
  __syncthreads();
  for (int off = 128; off > 0; off >>= 1) { if (t < off) red[t] += red[t + off]; __syncthreads(); }
  float inv = 1.0f / sqrtf(red[0] * (1.0f / Dc) + EPSc);
  float v0 = d0 * inv * wload(w, woff + t, f32)       + wload(bb, woff + t, f32);
  float v1 = d1 * inv * wload(w, woff + t + 256, f32) + wload(bb, woff + t + 256, f32);
  float* orow = o + (long)row * Dc;
  ushort_t* arow = oA + (long)row * Dc;
  orow[t] = v0; orow[t + 256] = v1;
  arow[t] = f2us(v0); arow[t + 256] = f2us(v1);
}

// ---------------- bf16 MFMA GEMM: C = alpha*A@W^T (+f32 addend) ----------------
template<int BM, int BN, bool OBF>
__global__ __launch_bounds__(256) void k_gemm_b(const ushort_t* __restrict__ A, int lda,
    const ushort_t* __restrict__ W, void* __restrict__ C, int ldc,
    const float* __restrict__ addend, float alpha, int K) {
  constexpr int WGM = BM / 64;          // waves along M
  constexpr int WGN = 4 / WGM;
  constexpr int WN = BN / WGN;
  constexpr int NJ = WN / 16;
  __shared__ ushort_t As[BM * 64];
  __shared__ ushort_t Ws[BN * 64];
  int t = threadIdx.x;
  int m0 = blockIdx.y * BM, n0 = blockIdx.x * BN;
  int lane = t & 63, wv = t >> 6;
  int l15 = lane & 15, quad = lane >> 4;
  int wrow = (WGM == 2) ? (wv >> 1) * 64 : 0;
  int wcol = (WGM == 2) ? (wv & 1) * WN : wv * WN;
  floatx4 acc[4][NJ];
#pragma unroll
  for (int i = 0; i < 4; ++i)
#pragma unroll
    for (int j = 0; j < NJ; ++j) acc[i][j] = 0;
  for (int k0 = 0; k0 < K; k0 += 64) {
#pragma unroll
    for (int i = t; i < BM * 8; i += 256) {
      int r = i >> 3, c = i & 7;
      uint4 v = *(const uint4*)(A + (long)(m0 + r) * lda + k0 + c * 8);
      *(uint4*)&As[r * 64 + ((c ^ (r & 7)) << 3)] = v;
    }
#pragma unroll
    for (int i = t; i < BN * 8; i += 256) {
      int r = i >> 3, c = i & 7;
      uint4 v = *(const uint4*)(W + (long)(n0 + r) * K + k0 + c * 8);
      *(uint4*)&Ws[r * 64 + ((c ^ (r & 7)) << 3)] = v;
    }
    __syncthreads();
#pragma unroll
    for (int half = 0; half < 2; ++half) {
      int sw = ((half * 4 + quad) ^ (l15 & 7)) << 3;
      short8 af[4], bfr[NJ];
#pragma unroll
      for (int i = 0; i < 4; ++i) af[i] = *(short8*)&As[(wrow + i * 16 + l15) * 64 + sw];
#pragma unroll
      for (int j = 0; j < NJ; ++j) bfr[j] = *(short8*)&Ws[(wcol + j * 16 + l15) * 64 + sw];
#pragma unroll
      for (int i = 0; i < 4; ++i)
#pragma unroll
        for (int j = 0; j < NJ; ++j)
          acc[i][j] = __builtin_amdgcn_mfma_f32_16x16x32_bf16(af[i], bfr[j], acc[i][j], 0, 0, 0);
    }
    __syncthreads();
  }
#pragma unroll
  for (int i = 0; i < 4; ++i) {
#pragma unroll
    for (int j = 0; j < NJ; ++j) {
#pragma unroll
      for (int rg = 0; rg < 4; ++rg) {
        int m = m0 + wrow + i * 16 + quad * 4 + rg;
        int n = n0 + wcol + j * 16 + l15;
        float v = alpha * acc[i][j][rg];
        if (addend) v += addend[(long)m * ldc + n];
        if (OBF) ((ushort_t*)C)[(long)m * ldc + n] = f2us(v);
        else     ((float*)C)[(long)m * ldc + n] = v;
      }
    }
  }
}

// ---------------- Rq GEMM (bf16): Rq[(bh*1024+qo)][ri] = q . rel[min(ri,382)] ----------------
__global__ __launch_bounds__(256) void k_rq_b(const ushort_t* __restrict__ qb,
    const ushort_t* __restrict__ relB, bf16* __restrict__ Rq) {
  __shared__ ushort_t As[128 * 64];
  __shared__ ushort_t Ws[128 * 64];
  int t = threadIdx.x;
  int bh = blockIdx.z;
  const ushort_t* A = qb + (long)(bh >> 3) * Tc * Dc + (bh & 7) * 64;
  int m0 = blockIdx.y * 128, n0 = blockIdx.x * 128;
  int lane = t & 63, wv = t >> 6;
  int l15 = lane & 15, quad = lane >> 4;
  int wrow = (wv >> 1) * 64, wcol = (wv & 1) * 64;
  floatx4 acc[4][4];
#pragma unroll
  for (int i = 0; i < 4; ++i)
#pragma unroll
    for (int j = 0; j < 4; ++j) acc[i][j] = 0;
#pragma unroll
  for (int i = t; i < 128 * 8; i += 256) {
    int r = i >> 3, c = i & 7;
    uint4 v = *(const uint4*)(A + (long)(m0 + r) * Dc + c * 8);
    *(uint4*)&As[r * 64 + ((c ^ (r & 7)) << 3)] = v;
  }
#pragma unroll
  for (int i = t; i < 128 * 8; i += 256) {
    int r = i >> 3, c = i & 7;
    int wr = n0 + r; if (wr > 382) wr = 382;
    uint4 v = *(const uint4*)(relB + (long)wr * 64 + c * 8);
    *(uint4*)&Ws[r * 64 + ((c ^ (r & 7)) << 3)] = v;
  }
  __syncthreads();
#pragma unroll
  for (int half = 0; half < 2; ++half) {
    int sw = ((half * 4 + quad) ^ (l15 & 7)) << 3;
    short8 af[4], bfr[4];
#pragma unroll
    for (int i = 0; i < 4; ++i) af[i] = *(short8*)&As[(wrow + i * 16 + l15) * 64 + sw];
#pragma unroll
    for (int j = 0; j < 4; ++j) bfr[j] = *(short8*)&Ws[(wcol + j * 16 + l15) * 64 + sw];
#pragma unroll
    for (int i = 0; i < 4; ++i)
#pragma unroll
      for (int j = 0; j < 4; ++j)
        acc[i][j] = __builtin_amdgcn_mfma_f32_16x16x32_bf16(af[i], bfr[j], acc[i][j], 0, 0, 0);
  }
#pragma unroll
  for (int i = 0; i < 4; ++i)
#pragma unroll
    for (int j = 0; j < 4; ++j)
#pragma unroll
      for (int rg = 0; rg < 4; ++rg) {
        int m = m0 + wrow + i * 16 + quad * 4 + rg;
        int n = n0 + wcol + j * 16 + l15;
        Rq[((long)bh * Tc + m) * 384 + n] = __float2bfloat16(acc[i][j][rg]);
      }
}

// ---------------- unified MFMA flash attention ----------------
// grid (32, 8, 4): x<16 = valid-query band path (3 k-tiles, chunk mask); x>=16 = invalid-query
// full-1152-key softmax path (18 k-tiles). Both run as 512-thread 2-group split-K flash and
// OVERLAP on the device (previously two serial ~50us latency-bound dispatches).
// Rel-bias: per near-diagonal tile, each q-row needs 64 CONTIGUOUS Rq entries -> stage per-row
// 80-entry aligned windows into LDS with coalesced uint4 loads (one vmcnt wait/tile), gather from
// LDS. Far tiles use per-row edge constants. No scattered global 2B reads remain in the loop.
__global__ __launch_bounds__(512) void k_attn(const ushort_t* __restrict__ q,
    const ushort_t* __restrict__ kb, const ushort_t* __restrict__ vb,
    const bf16* __restrict__ Rq, const int* __restrict__ alen, ushort_t* __restrict__ out) {
  int bx = blockIdx.x;
  int inv = bx >> 4;                  // 0 = valid path, 1 = inv path
  int qt = bx & 15, h = blockIdx.y, b = blockIdx.z;
  int len = alen[b];
  int q0 = qt * 64;
  if (inv) { if (q0 + 64 <= len) return; }
  else     { if (q0 >= len) return; }
  int nskip = max(len - q0, 0);
  int nvalid = min(len - q0, 64);
  int g = h >> 2;
  __shared__ __align__(16) ushort_t Qs[64 * 72];        // 9216 B
  __shared__ __align__(16) ushort_t SB[2][8704];        // per group: K/P swz (8192 B) | Vt (9216 B)
  __shared__ __align__(16) ushort_t Bs[2][64 * 88];     // per group: rel-bias band (11264 B)
  int t = threadIdx.x;
  int grp = t >> 8, tl = t & 255;
  int lane = t & 63, w = (t >> 6) & 3;
  int l15 = lane & 15, quad = lane >> 4;
  int qw = w * 16;
  ushort_t* Ksg = &SB[grp][0];
  ushort_t* Vtg = &SB[grp][4096];
  ushort_t* Bsg = &Bs[grp][0];
  if (t < 256) {
    int qi = t >> 2, du = (t & 3) * 16;
    const ushort_t* src = q + ((long)(b * Tc + q0 + qi)) * Dc + h * 64 + du;
    *(uint4*)&Qs[qi * 72 + du] = *(const uint4*)(src);
    *(uint4*)&Qs[qi * 72 + du + 8] = *(const uint4*)(src + 8);
  }
  const int NT = inv ? 18 : 3;
  const int NIT = inv ? 9 : 2;
  const int koB = inv ? -128 : (q0 - 128);
  // K/V prefetch registers
  uint4 kr0, kr1, vr0, vr1;
  int kj = tl >> 2, du = (tl & 3) * 16, c0 = du >> 3;
  auto LOADKV = [&](int ko0x) {
    int ko = ko0x + kj;
    if (ko >= 0) {
      long basek = ((long)(b * Tc + ko)) * 128 + g * 64 + du;
      kr0 = *(const uint4*)(kb + basek);
      kr1 = *(const uint4*)(kb + basek + 8);
      vr0 = *(const uint4*)(vb + basek);
      vr1 = *(const uint4*)(vb + basek + 8);
    } else {
      uint4 z = {0, 0, 0, 0};
      kr0 = z; kr1 = z; vr0 = z; vr1 = z;
    }
  };
  LOADKV(koB + grp * 64);
  float m_[4], l_[4], alpha[4];
  floatx4 acc[4];
#pragma unroll
  for (int r = 0; r < 4; ++r) { m_[r] = NEGB; l_[r] = 0.f; acc[r] = 0; }
  const ushort_t* Rqu = (const ushort_t*)Rq;
  long rqrow = (long)(b * 8 + h) * Tc + q0;
  // per-row rel-bias edge constants (only consumed by inv-path far tiles)
  float rv_hi[4], rv_lo[4];
  if (inv) {
#pragma unroll
    for (int r = 0; r < 4; ++r) {
      long rr = (rqrow + qw + quad * 4 + r) * 384;
      rv_hi[r] = us2f(Rqu[rr + 382]);
      rv_lo[r] = us2f(Rqu[rr]);
    }
  } else {
#pragma unroll
    for (int r = 0; r < 4; ++r) { rv_hi[r] = 0.f; rv_lo[r] = 0.f; }
  }
  __syncthreads();
  short8 aq0 = *(short8*)&Qs[(qw + l15) * 72 + quad * 8];
  short8 aq1 = *(short8*)&Qs[(qw + l15) * 72 + 32 + quad * 8];
  for (int it = 0; it < NIT; ++it) {
    int kt = grp + 2 * it;
    bool act = (kt < NT);               // group-uniform (only false for valid path grp1 it1)
    int ko0 = koB + kt * 64;
    int t0 = q0 - ko0 + 191;            // bias col c(qi,kj) = t0 + qi - kj, clamp [0,382]
    bool far_hi = (q0 - ko0 - 63) >= 191;
    bool far_lo = (q0 + 63 - ko0) <= -191;
    bool near = act && !far_hi && !far_lo;
    __syncthreads();   // A: all group waves done reading K(P)/V/Bs of previous tile
    if (act) {
      // K: swizzled vectorized store; V: transposed scalar stores (from prefetch regs)
      *(uint4*)&Ksg[kj * 64 + ((c0 ^ (kj & 7)) << 3)] = kr0;
      *(uint4*)&Ksg[kj * 64 + (((c0 + 1) ^ (kj & 7)) << 3)] = kr1;
      uint_t wds[8] = {vr0.x, vr0.y, vr0.z, vr0.w, vr1.x, vr1.y, vr1.z, vr1.w};
#pragma unroll
      for (int u = 0; u < 8; ++u) {
        Vtg[(du + 2 * u) * 72 + kj] = (ushort_t)(wds[u] & 0xffff);
        Vtg[(du + 2 * u + 1) * 72 + kj] = (ushort_t)(wds[u] >> 16);
      }
    }
    if (near) {
      // stage per-row 80-entry aligned bias windows (coalesced uint4)
      for (int i = tl; i < 640; i += 256) {
        int row = i / 10, ch = i - row * 10;
        int a = (t0 + row - 63) & ~7;
        int st = min(max(a, 0), 304);
        *(uint4*)&Bsg[row * 88 + ch * 8] = *(const uint4*)(Rqu + (rqrow + row) * 384 + st + ch * 8);
      }
    }
    int kt2 = kt + 2;
    if (kt2 < NT) LOADKV(koB + kt2 * 64);   // prefetch next tile
    __syncthreads();   // B: staging visible to group
    floatx4 s[4];
    if (act) {
#pragma unroll
      for (int nt = 0; nt < 4; ++nt) {
        short8 bk0 = *(short8*)&Ksg[(nt * 16 + l15) * 64 + ((quad ^ (l15 & 7)) << 3)];
        short8 bk1 = *(short8*)&Ksg[(nt * 16 + l15) * 64 + (((4 + quad) ^ (l15 & 7)) << 3)];
        floatx4 z = {0.f, 0.f, 0.f, 0.f};
        z = __builtin_amdgcn_mfma_f32_16x16x32_bf16(aq0, bk0, z, 0, 0, 0);
        z = __builtin_amdgcn_mfma_f32_16x16x32_bf16(aq1, bk1, z, 0, 0, 0);
        s[nt] = z;
      }
    }
    __syncthreads();   // C: all group waves done reading K; region may become P
    if (act) {
      // rel bias from LDS band / edge constants
      if (near) {
        int st_r[4];
#pragma unroll
        for (int r = 0; r < 4; ++r) {
          int a = (t0 + qw + quad * 4 + r - 63) & ~7;
          st_r[r] = min(max(a, 0), 304);
        }
#pragma unroll
        for (int nt = 0; nt < 4; ++nt)
#pragma unroll
          for (int r = 0; r < 4; ++r) {
            int qi2 = qw + quad * 4 + r;
            int c = t0 + qi2 - (nt * 16 + l15);
            c = min(max(c, 0), 382);
            s[nt][r] += us2f(Bsg[qi2 * 88 + (c - st_r[r])]);
          }
      } else if (far_hi) {
#pragma unroll
        for (int nt = 0; nt < 4; ++nt)
#pragma unroll
          for (int r = 0; r < 4; ++r) s[nt][r] += rv_hi[r];
      } else {
#pragma unroll
        for (int nt = 0; nt < 4; ++nt)
#pragma unroll
          for (int r = 0; r < 4; ++r) s[nt][r] += rv_lo[r];
      }
      if (!inv) {
#pragma unroll
        for (int nt = 0; nt < 4; ++nt) {
          int ko = ko0 + nt * 16 + l15;
          if (ko >= len) {
#pragma unroll
            for (int r = 0; r < 4; ++r) s[nt][r] = NEGB;
          }
        }
      }
#pragma unroll
      for (int r = 0; r < 4; ++r) {
        float mx = fmaxf(fmaxf(s[0][r], s[1][r]), fmaxf(s[2][r], s[3][r]));
#pragma unroll
        for (int o = 1; o < 16; o <<= 1) mx = fmaxf(mx, __shfl_xor(mx, o, 64));
        float mn = fmaxf(m_[r], mx);
        alpha[r] = __expf(m_[r] - mn);
        float p0 = __expf(s[0][r] - mn), p1 = __expf(s[1][r] - mn);
        float p2 = __expf(s[2][r] - mn), p3 = __expf(s[3][r] - mn);
        s[0][r] = p0; s[1][r] = p1; s[2][r] = p2; s[3][r] = p3;
        float ps = p0 + p1 + p2 + p3;
#pragma unroll
        for (int o = 1; o < 16; o <<= 1) ps += __shfl_xor(ps, o, 64);
        l_[r] = l_[r] * alpha[r] + ps;
        m_[r] = mn;
      }
      // P into K region (wave-private rows; swizzled like K)
#pragma unroll
      for (int nt = 0; nt < 4; ++nt)
#pragma unroll
        for (int r = 0; r < 4; ++r) {
          int row = qw + quad * 4 + r;
          int col = nt * 16 + l15;
          Ksg[row * 64 + (((col >> 3) ^ (row & 7)) << 3) + (col & 7)] = f2us(s[nt][r]);
        }
#pragma unroll
      for (int j = 0; j < 4; ++j)
#pragma unroll
        for (int r = 0; r < 4; ++r) acc[j][r] *= alpha[r];
      short8 ap0 = *(short8*)&Ksg[(qw + l15) * 64 + ((quad ^ (l15 & 7)) << 3)];
      short8 ap1 = *(short8*)&Ksg[(qw + l15) * 64 + (((4 + quad) ^ (l15 & 7)) << 3)];
#pragma unroll
      for (int j = 0; j < 4; ++j) {
        short8 bv0 = *(short8*)&Vtg[(j * 16 + l15) * 72 + quad * 8];
        short8 bv1 = *(short8*)&Vtg[(j * 16 + l15) * 72 + 32 + quad * 8];
        acc[j] = __builtin_amdgcn_mfma_f32_16x16x32_bf16(ap0, bv0, acc[j], 0, 0, 0);
        acc[j] = __builtin_amdgcn_mfma_f32_16x16x32_bf16(ap1, bv1, acc[j], 0, 0, 0);
      }
    }
  }
  // ---- exact split-K combine over 2 groups ----
  __syncthreads();
  if (grp == 1) {
    float* Cg = (float*)&SB[1][0];         // 64x64 f32 = 16KB (spans SB[1] + start of Bs? no: 16KB < 17408 ok)
    float* MLg = (float*)&SB[1][8192];     // byte 16384: [0..63]=m, [64..127]=l
#pragma unroll
    for (int j = 0; j < 4; ++j)
#pragma unroll
      for (int r = 0; r < 4; ++r)
        Cg[(qw + quad * 4 + r) * 64 + j * 16 + l15] = acc[j][r];
    if (l15 == 0) {
#pragma unroll
      for (int r = 0; r < 4; ++r) {
        int R = qw + quad * 4 + r;
        MLg[R] = m_[r];
        MLg[64 + R] = l_[r];
      }
    }
  }
  __syncthreads();
  if (grp == 0) {
    float* Cg = (float*)&SB[1][0];
    float* MLg = (float*)&SB[1][8192];
#pragma unroll
    for (int r = 0; r < 4; ++r) {
      int R = qw + quad * 4 + r;
      float mo = MLg[R], lo = MLg[64 + R];
      float M = fmaxf(m_[r], mo);
      float s0 = __expf(m_[r] - M);
      float s1 = __expf(mo - M);
      float L = l_[r] * s0 + lo * s1;
      bool wr = inv ? (R >= nskip) : (R < nvalid);
      if (wr) {
        float invL = 1.0f / L;
#pragma unroll
        for (int j = 0; j < 4; ++j) {
          float v = acc[j][r] * s0 + Cg[R * 64 + j * 16 + l15] * s1;
          out[((long)(b * Tc + q0 + R)) * Dc + h * 64 + j * 16 + l15] = f2us(v * invL);
        }
      }
    }
  }
}

// ---------------- elementwise (bf16) ----------------
__global__ void k_glu(ushort_t* __restrict__ h, int n) {
  int i = blockIdx.x * 256 + threadIdx.x;
  if (i >= n) return;
  int r = i >> 9, j = i & 511;
  float a = us2f(h[(long)r * 1024 + j]), g = us2f(h[(long)r * 1024 + 512 + j]);
  h[(long)r * 1024 + j] = f2us(a * (1.0f / (1.0f + __expf(-g))));
}
__global__ void k_swiglu(ushort_t* __restrict__ h, int n) {
  int i = blockIdx.x * 256 + threadIdx.x;
  if (i >= n) return;
  int r = i >> 10, j = i & 1023;
  float a = us2f(h[(long)r * 2048 + j]), bb = us2f(h[(long)r * 2048 + 1024 + j]);
  h[(long)r * 2048 + j] = f2us((a / (1.0f + __expf(-a))) * bb);
}
__global__ void k_dwconv(const ushort_t* __restrict__ in, const ushort_t* __restrict__ dw,
                         ushort_t* __restrict__ out, int n) {
  int i = blockIdx.x * 256 + threadIdx.x;
  if (i >= n) return;
  int d = i & 511;
  int t = (i >> 9) & (Tc - 1);
  int b = i >> 19;
  float acc = 0.0f;
#pragma unroll
  for (int j = 0; j < 9; ++j) {
    int tt = t + j - 4;
    if (tt >= 0 && tt < Tc) acc += us2f(in[((long)(b * Tc + tt) << 10) + d]) * us2f(dw[d * 9 + j]);
  }
  out[i] = f2us(acc * (1.0f / (1.0f + __expf(-acc))));
}

extern "C" void kernel_launch(void* const* d_in, const int* in_sizes, int n_in,
                              void* d_out, int out_size, void* d_ws, size_t ws_size,
                              hipStream_t stream) {
  const void* x_in = d_in[0];
  const int*  alen = (const int*)d_in[1];
  const void* ln1w = d_in[2];
  const void* ln1b = d_in[3];
  const void* wq   = d_in[4];
  const void* wk   = d_in[5];
  const void* wv   = d_in[6];
  const void* wo   = d_in[7];
  const void* rel  = d_in[8];
  const void* ln2w = d_in[9];
  const void* ln2b = d_in[10];
  const void* pw1  = d_in[11];
  const void* dwv  = d_in[12];
  const void* pw2  = d_in[13];
  const void* ln3w = d_in[14];
  const void* ln3b = d_in[15];
  const void* w1   = d_in[16];
  const void* w2   = d_in[17];

  // ---- workspace layout (bytes) ----
  char* base = (char*)d_ws;
  int*      flag = (int*)base;                       // 256
  float*    xf   = (float*)(base + 256);             // 8 MB f32 residual
  float*    lnb  = (float*)(base + 256 + 8388608);   // 8 MB f32 LN out (addend)
  ushort_t* lnA  = (ushort_t*)(base + 16777472);     // 4 MB bf16 LN out (GEMM A)
  ushort_t* wbf  = (ushort_t*)(base + 20971776);     // 24,350,208 B bf16 weights
  char*     U    = base + 45321984;                  // phase union (35.7 MB)
  // attn phase
  ushort_t* qb = (ushort_t*)U;                       // 4 MB
  ushort_t* kb = (ushort_t*)(U + 4194304);           // 1 MB
  ushort_t* vb = (ushort_t*)(U + 5242880);           // 1 MB
  ushort_t* ab = (ushort_t*)(U + 6291456);           // 4 MB
  bf16*     Rq = (bf16*)(U + 10485760);              // 25,165,824 B
  // conv/ffn phase
  ushort_t* big = (ushort_t*)U;                      // up to 16 MB
  ushort_t* cb  = (ushort_t*)(U + 16777216);         // 4 MB
  size_t REQ = 45321984 + 16777216 + 4194304;
  size_t REQ2 = 45321984 + 35651584;
  if (REQ2 > REQ) REQ = REQ2;
  if (ws_size < REQ) return;

  // bf16 weight table offsets (elements)
  ushort_t* wqB  = wbf + 0;
  ushort_t* wkB  = wbf + 1048576;
  ushort_t* wvB  = wbf + 1310720;
  ushort_t* woB  = wbf + 1572864;
  ushort_t* relB = wbf + 2621440;
  ushort_t* pw1B = wbf + 2719488;
  ushort_t* dwB  = wbf + 4816640;
  ushort_t* pw2B = wbf + 4835072;
  ushort_t* w1B  = wbf + 5883648;
  ushort_t* w2B  = wbf + 10077952;

  k_detect<<<1, 256, 0, stream>>>(x_in, flag);
  k_in<<<(int)((NE + 255) / 256), 256, 0, stream>>>(x_in, xf, (int)NE, flag);
  k_w2b<<<4096, 256, 0, stream>>>(wq,  wqB,  1048576, flag);
  k_w2b<<<1024, 256, 0, stream>>>(wk,  wkB,  262144, flag);
  k_w2b<<<1024, 256, 0, stream>>>(wv,  wvB,  262144, flag);
  k_w2b<<<4096, 256, 0, stream>>>(wo,  woB,  1048576, flag);
  k_w2b<<<383,  256, 0, stream>>>(rel, relB, 98048, flag);
  k_w2b<<<8192, 256, 0, stream>>>(pw1, pw1B, 2097152, flag);
  k_w2b<<<72,   256, 0, stream>>>(dwv, dwB,  18432, flag);
  k_w2b<<<4096, 256, 0, stream>>>(pw2, pw2B, 1048576, flag);
  k_w2b<<<16384,256, 0, stream>>>(w1,  w1B,  4194304, flag);
  k_w2b<<<8192, 256, 0, stream>>>(w2,  w2B,  2097152, flag);

  for (int i = 0; i < 4; ++i) {
    long oLN = (long)i * Dc;
    // ---- attention ----
    k_ln<<<NBT, 256, 0, stream>>>(xf, ln1w, ln1b, oLN, lnb, lnA, flag);
    k_gemm_b<64, 128, true><<<dim3(4, 64), 256, 0, stream>>>(lnA, Dc, wqB + (long)i * 262144, qb, Dc, nullptr, 0.125f, 512);
    k_gemm_b<64, 64, true><<<dim3(2, 64), 256, 0, stream>>>(lnA, Dc, wkB + (long)i * 65536, kb, 128, nullptr, 1.0f, 512);
    k_gemm_b<64, 64, true><<<dim3(2, 64), 256, 0, stream>>>(lnA, Dc, wvB + (long)i * 65536, vb, 128, nullptr, 1.0f, 512);
    k_rq_b<<<dim3(3, 8, 32), 256, 0, stream>>>(qb, relB + (long)i * 24512, Rq);
    k_attn<<<dim3(32, 8, 4), 512, 0, stream>>>(qb, kb, vb, Rq, alen, ab);
    k_gemm_b<64, 128, false><<<dim3(4, 64), 256, 0, stream>>>(ab, Dc, woB + (long)i * 262144, xf, Dc, lnb, 1.0f, 512);

    // ---- conv ----
    k_ln<<<NBT, 256, 0, stream>>>(xf, ln2w, ln2b, oLN, lnb, lnA, flag);
    k_gemm_b<128, 128, true><<<dim3(8, 32), 256, 0, stream>>>(lnA, Dc, pw1B + (long)i * 524288, big, 1024, nullptr, 1.0f, 512);
    k_glu<<<NBT * 512 / 256, 256, 0, stream>>>(big, NBT * 512);
    k_dwconv<<<NBT * 512 / 256, 256, 0, stream>>>(big, dwB + (long)i * 4608, cb, NBT * 512);
    k_gemm_b<64, 128, false><<<dim3(4, 64), 256, 0, stream>>>(cb, Dc, pw2B + (long)i * 262144, xf, Dc, lnb, 1.0f, 512);

    // ---- ffn ----
    k_ln<<<NBT, 256, 0, stream>>>(xf, ln3w, ln3b, oLN, lnb, lnA, flag);
    k_gemm_b<128, 128, true><<<dim3(16, 32), 256, 0, stream>>>(lnA, Dc, w1B + (long)i * 1048576, big, 2048, nullptr, 1.0f, 512);
    k_swiglu<<<NBT * 1024 / 256, 256, 0, stream>>>(big, NBT * 1024);
    k_gemm_b<64, 128, false><<<dim3(4, 64), 256, 0, stream>>>(big, 2048, w2B + (long)i * 524288, xf, Dc, lnb, 1.0f, 1024);
  }

  k_out<<<(int)((NE + 255) / 256), 256, 0, stream>>>(xf, d_out, (int)NE, flag);
}

// Round 4
// 1585.250 us; speedup vs baseline: 1.0283x; 1.0283x over previous
//
#include <hip/hip_runtime.h>
#include <hip/hip_bf16.h>

typedef __hip_bfloat16 bf16;
typedef unsigned short ushort_t;
typedef unsigned int uint_t;
typedef __attribute__((ext_vector_type(8))) short short8;
typedef __attribute__((ext_vector_type(4))) float floatx4;

__device__ __forceinline__ float b2f(bf16 x) { return __bfloat162float(x); }
__device__ __forceinline__ ushort_t f2us(float f) { bf16 h = __float2bfloat16(f); return *(ushort_t*)&h; }
__device__ __forceinline__ float us2f(ushort_t u) { return __uint_as_float(((uint_t)u) << 16); }

constexpr int Bc = 4, Tc = 1024, Dc = 512, Hc = 8, HDc = 64;
constexpr int LCc = 128, MPc = 192;
constexpr float EPSc = 1e-4f;
constexpr int NBT = Bc * Tc;
constexpr long NE = (long)NBT * Dc;
constexpr float NEGB = -1e30f;

__device__ __forceinline__ float wload(const void* p, long i, int f32) {
  return f32 ? ((const float*)p)[i] : b2f(((const bf16*)p)[i]);
}

// ---------------- dtype detector ----------------
__global__ void k_detect(const void* __restrict__ x, int* __restrict__ flag) {
  __shared__ int s[256];
  int t = threadIdx.x;
  const unsigned short* u = (const unsigned short*)x;
  int bad = 0;
  for (int j = t; j < 2048; j += 256) {
    int e = (u[j] >> 7) & 0xFF;
    if (e == 0xFF || e > 0x8F || (e != 0 && e < 0x6F)) bad++;
  }
  s[t] = bad;
  __syncthreads();
  for (int off = 128; off > 0; off >>= 1) { if (t < off) s[t] += s[t + off]; __syncthreads(); }
  if (t == 0) flag[0] = (s[0] > 16) ? 1 : 0;
}

__global__ void k_in(const void* __restrict__ in, float* __restrict__ out, int n,
                     const int* __restrict__ flag) {
  int i = blockIdx.x * 256 + threadIdx.x;
  if (i < n) out[i] = wload(in, i, flag[0]);
}
__global__ void k_out(const float* __restrict__ in, void* __restrict__ out, int n,
                      const int* __restrict__ flag) {
  int i = blockIdx.x * 256 + threadIdx.x;
  if (i >= n) return;
  if (flag[0]) ((float*)out)[i] = in[i];
  else         ((bf16*)out)[i] = __float2bfloat16(in[i]);
}
// convert any weight tensor to bf16 workspace copy
__global__ void k_w2b(const void* __restrict__ src, ushort_t* __restrict__ dst, int n,
                      const int* __restrict__ flag) {
  int i = blockIdx.x * 256 + threadIdx.x;
  if (i < n) dst[i] = f2us(wload(src, i, flag[0]));
}

// ---------------- LayerNorm: writes f32 (residual addend) + bf16 (GEMM A) ----------------
__global__ __launch_bounds__(256) void k_ln(const float* __restrict__ x,
    const void* __restrict__ w, const void* __restrict__ bb, long woff,
    float* __restrict__ o, ushort_t* __restrict__ oA, const int* __restrict__ flag) {
  int f32 = flag[0];
  int row = blockIdx.x;
  int t = threadIdx.x;
  const float* xr = x + (long)row * Dc;
  float x0 = xr[t], x1 = xr[t + 256];
  __shared__ float red[256];
  red[t] = x0 + x1;
  __syncthreads();
  for (int off = 128; off > 0; off >>= 1) { if (t < off) red[t] += red[t + off]; __syncthreads(); }
  float mean = red[0] * (1.0f / Dc);
  __syncthreads();
  float d0 = x0 - mean, d1 = x1 - mean;
  red[t] = d0 * d0 + d1 * d1;
  __syncthreads();
  for (int off = 128; off > 0; off >>= 1) { if (t < off) red[t] += red[t + off]; __syncthreads(); }
  float inv = 1.0f / sqrtf(red[0] * (1.0f / Dc) + EPSc);
  float v0 = d0 * inv * wload(w, woff + t, f32)       + wload(bb, woff + t, f32);
  float v1 = d1 * inv * wload(w, woff + t + 256, f32) + wload(bb, woff + t + 256, f32);
  float* orow = o + (long)row * Dc;
  ushort_t* arow = oA + (long)row * Dc;
  orow[t] = v0; orow[t + 256] = v1;
  arow[t] = f2us(v0); arow[t + 256] = f2us(v1);
}

// ---------------- bf16 MFMA GEMM: C = alpha*A@W^T (+f32 addend) ----------------
template<int BM, int BN, bool OBF>
__global__ __launch_bounds__(256) void k_gemm_b(const ushort_t* __restrict__ A, int lda,
    const ushort_t* __restrict__ W, void* __restrict__ C, int ldc,
    const float* __restrict__ addend, float alpha, int K) {
  constexpr int WGM = BM / 64;          // waves along M
  constexpr int WGN = 4 / WGM;
  constexpr int WN = BN / WGN;
  constexpr int NJ = WN / 16;
  __shared__ ushort_t As[BM * 64];
  __shared__ ushort_t Ws[BN * 64];
  int t = threadIdx.x;
  int m0 = blockIdx.y * BM, n0 = blockIdx.x * BN;
  int lane = t & 63, wv = t >> 6;
  int l15 = lane & 15, quad = lane >> 4;
  int wrow = (WGM == 2) ? (wv >> 1) * 64 : 0;
  int wcol = (WGM == 2) ? (wv & 1) * WN : wv * WN;
  floatx4 acc[4][NJ];
#pragma unroll
  for (int i = 0; i < 4; ++i)
#pragma unroll
    for (int j = 0; j < NJ; ++j) acc[i][j] = 0;
  for (int k0 = 0; k0 < K; k0 += 64) {
#pragma unroll
    for (int i = t; i < BM * 8; i += 256) {
      int r = i >> 3, c = i & 7;
      uint4 v = *(const uint4*)(A + (long)(m0 + r) * lda + k0 + c * 8);
      *(uint4*)&As[r * 64 + ((c ^ (r & 7)) << 3)] = v;
    }
#pragma unroll
    for (int i = t; i < BN * 8; i += 256) {
      int r = i >> 3, c = i & 7;
      uint4 v = *(const uint4*)(W + (long)(n0 + r) * K + k0 + c * 8);
      *(uint4*)&Ws[r * 64 + ((c ^ (r & 7)) << 3)] = v;
    }
    __syncthreads();
#pragma unroll
    for (int half = 0; half < 2; ++half) {
      int sw = ((half * 4 + quad) ^ (l15 & 7)) << 3;
      short8 af[4], bfr[NJ];
#pragma unroll
      for (int i = 0; i < 4; ++i) af[i] = *(short8*)&As[(wrow + i * 16 + l15) * 64 + sw];
#pragma unroll
      for (int j = 0; j < NJ; ++j) bfr[j] = *(short8*)&Ws[(wcol + j * 16 + l15) * 64 + sw];
#pragma unroll
      for (int i = 0; i < 4; ++i)
#pragma unroll
        for (int j = 0; j < NJ; ++j)
          acc[i][j] = __builtin_amdgcn_mfma_f32_16x16x32_bf16(af[i], bfr[j], acc[i][j], 0, 0, 0);
    }
    __syncthreads();
  }
#pragma unroll
  for (int i = 0; i < 4; ++i) {
#pragma unroll
    for (int j = 0; j < NJ; ++j) {
#pragma unroll
      for (int rg = 0; rg < 4; ++rg) {
        int m = m0 + wrow + i * 16 + quad * 4 + rg;
        int n = n0 + wcol + j * 16 + l15;
        float v = alpha * acc[i][j][rg];
        if (addend) v += addend[(long)m * ldc + n];
        if (OBF) ((ushort_t*)C)[(long)m * ldc + n] = f2us(v);
        else     ((float*)C)[(long)m * ldc + n] = v;
      }
    }
  }
}

// ---------------- unified MFMA flash attention with in-kernel rel bias ----------------
// grid (32, 8, 4), 256 threads: x<16 = valid band (3 k-tiles); x>=16 = invalid full softmax
// (18 k-tiles). NO Rq precompute: per near-diagonal k-tile, bias tile B2 = Q @ rel_window^T is
// computed by MFMA from the 24KB L2-resident rel table (B-frags loaded straight from L2), stored
// bf16 in LDS (same rounding as the old Rq path), then gathered Toeplitz-style. Far-clamped tiles
// use per-row edge dots computed once per block via one MFMA pair + shfl. This removes the 25MB
// Rq write + ~15MB scattered read that set the old ~190GB/s-effective floor.
__global__ __launch_bounds__(256, 3) void k_attn(const ushort_t* __restrict__ q,
    const ushort_t* __restrict__ kb, const ushort_t* __restrict__ vb,
    const ushort_t* __restrict__ relL, const int* __restrict__ alen,
    ushort_t* __restrict__ out) {
  int bx = blockIdx.x;
  int inv = bx >> 4;                  // 0 = valid path, 1 = inv path
  int qt = bx & 15, h = blockIdx.y, b = blockIdx.z;
  int len = alen[b];
  int q0 = qt * 64;
  if (inv) { if (q0 + 64 <= len) return; }
  else     { if (q0 >= len) return; }
  int nskip = max(len - q0, 0);
  int nvalid = min(len - q0, 64);
  int g = h >> 2;
  __shared__ __align__(16) ushort_t Qs[64 * 72];    // 9216 B
  __shared__ __align__(16) ushort_t Ks[64 * 64];    // 8192 B  K (XOR swz) then P
  __shared__ __align__(16) ushort_t Vt[64 * 72];    // 9216 B  V transposed
  __shared__ __align__(16) ushort_t B2[64 * 132];   // 16896 B bias window (bf16, pitch 132)
  int t = threadIdx.x;
  int lane = t & 63, w = t >> 6;
  int l15 = lane & 15, quad = lane >> 4;
  int qw = w * 16;
  {
    int qi = t >> 2, du = (t & 3) * 16;
    const ushort_t* src = q + ((long)(b * Tc + q0 + qi)) * Dc + h * 64 + du;
    *(uint4*)&Qs[qi * 72 + du] = *(const uint4*)(src);
    *(uint4*)&Qs[qi * 72 + du + 8] = *(const uint4*)(src + 8);
  }
  const int NT = inv ? 18 : 3;
  const int koB = inv ? -128 : (q0 - 128);
  // K/V prefetch registers
  uint4 kr0, kr1, vr0, vr1;
  int kj = t >> 2, du = (t & 3) * 16, c0 = du >> 3;
  auto LOADKV = [&](int ko0x) {
    int ko = ko0x + kj;
    if (ko >= 0) {
      long basek = ((long)(b * Tc + ko)) * 128 + g * 64 + du;
      kr0 = *(const uint4*)(kb + basek);
      kr1 = *(const uint4*)(kb + basek + 8);
      vr0 = *(const uint4*)(vb + basek);
      vr1 = *(const uint4*)(vb + basek + 8);
    } else {
      uint4 z = {0, 0, 0, 0};
      kr0 = z; kr1 = z; vr0 = z; vr1 = z;
    }
  };
  LOADKV(koB);
  float m_[4], l_[4], alpha[4];
  floatx4 acc[4];
#pragma unroll
  for (int r = 0; r < 4; ++r) { m_[r] = NEGB; l_[r] = 0.f; acc[r] = 0; }
  __syncthreads();
  short8 aq0 = *(short8*)&Qs[(qw + l15) * 72 + quad * 8];
  short8 aq1 = *(short8*)&Qs[(qw + l15) * 72 + 32 + quad * 8];
  // per-row rel-bias edge constants via one MFMA pair (inv-path far tiles only)
  float rv_hi[4], rv_lo[4];
  if (inv) {
    int er = (l15 == 1) ? 382 : 0;
    short8 be0 = *(const short8*)(relL + (long)er * 64 + quad * 8);
    short8 be1 = *(const short8*)(relL + (long)er * 64 + 32 + quad * 8);
    floatx4 ec = {0.f, 0.f, 0.f, 0.f};
    ec = __builtin_amdgcn_mfma_f32_16x16x32_bf16(aq0, be0, ec, 0, 0, 0);
    ec = __builtin_amdgcn_mfma_f32_16x16x32_bf16(aq1, be1, ec, 0, 0, 0);
#pragma unroll
    for (int r = 0; r < 4; ++r) {
      rv_lo[r] = __shfl(ec[r], (quad << 4) | 0, 64);
      rv_hi[r] = __shfl(ec[r], (quad << 4) | 1, 64);
    }
  } else {
#pragma unroll
    for (int r = 0; r < 4; ++r) { rv_hi[r] = 0.f; rv_lo[r] = 0.f; }
  }
  for (int kt = 0; kt < NT; ++kt) {
    int ko0 = koB + kt * 64;
    int t0 = q0 - ko0 + 191;            // bias col c(qi,kj) = clamp(t0 + qi - kj, 0, 382)
    bool far_hi = (q0 - ko0 - 63) >= 191;
    bool far_lo = (q0 + 63 - ko0) <= -191;
    bool near = !far_hi && !far_lo;
    int cb = min(max(t0 - 63, 0), 255); // window base; idx = c - cb in [0,127]
    __syncthreads();   // A: all waves done with previous tile's K(P)/V/B2
    {
      // K: swizzled vectorized store; V: transposed scalar stores (from prefetch regs)
      *(uint4*)&Ks[kj * 64 + ((c0 ^ (kj & 7)) << 3)] = kr0;
      *(uint4*)&Ks[kj * 64 + (((c0 + 1) ^ (kj & 7)) << 3)] = kr1;
      uint_t wds[8] = {vr0.x, vr0.y, vr0.z, vr0.w, vr1.x, vr1.y, vr1.z, vr1.w};
#pragma unroll
      for (int u = 0; u < 8; ++u) {
        Vt[(du + 2 * u) * 72 + kj] = (ushort_t)(wds[u] & 0xffff);
        Vt[(du + 2 * u + 1) * 72 + kj] = (ushort_t)(wds[u] >> 16);
      }
    }
    if (near) {
      // B2 = Q @ rel[cb..cb+127]^T via MFMA; B-frags straight from L2-resident rel table.
#pragma unroll
      for (int p = 0; p < 2; ++p) {
        short8 bw0[4], bw1[4];
#pragma unroll
        for (int j = 0; j < 4; ++j) {
          long wr = cb + (p * 4 + j) * 16 + l15;
          bw0[j] = *(const short8*)(relL + wr * 64 + quad * 8);
          bw1[j] = *(const short8*)(relL + wr * 64 + 32 + quad * 8);
        }
#pragma unroll
        for (int j = 0; j < 4; ++j) {
          floatx4 z = {0.f, 0.f, 0.f, 0.f};
          z = __builtin_amdgcn_mfma_f32_16x16x32_bf16(aq0, bw0[j], z, 0, 0, 0);
          z = __builtin_amdgcn_mfma_f32_16x16x32_bf16(aq1, bw1[j], z, 0, 0, 0);
#pragma unroll
          for (int rg = 0; rg < 4; ++rg)
            B2[(qw + quad * 4 + rg) * 132 + (p * 4 + j) * 16 + l15] = f2us(z[rg]);
        }
      }
    }
    if (kt + 1 < NT) LOADKV(koB + (kt + 1) * 64);   // prefetch next tile
    __syncthreads();   // B: staging visible
    floatx4 s[4];
#pragma unroll
    for (int nt = 0; nt < 4; ++nt) {
      short8 bk0 = *(short8*)&Ks[(nt * 16 + l15) * 64 + ((quad ^ (l15 & 7)) << 3)];
      short8 bk1 = *(short8*)&Ks[(nt * 16 + l15) * 64 + (((4 + quad) ^ (l15 & 7)) << 3)];
      floatx4 z = {0.f, 0.f, 0.f, 0.f};
      z = __builtin_amdgcn_mfma_f32_16x16x32_bf16(aq0, bk0, z, 0, 0, 0);
      z = __builtin_amdgcn_mfma_f32_16x16x32_bf16(aq1, bk1, z, 0, 0, 0);
      s[nt] = z;
    }
    __syncthreads();   // C: K reads done; Ks region may become P
    // rel bias from B2 window / edge constants
    if (near) {
#pragma unroll
      for (int nt = 0; nt < 4; ++nt)
#pragma unroll
        for (int r = 0; r < 4; ++r) {
          int qi2 = qw + quad * 4 + r;
          int c = t0 + qi2 - (nt * 16 + l15);
          c = min(max(c, 0), 382);
          s[nt][r] += us2f(B2[qi2 * 132 + (c - cb)]);
        }
    } else if (far_hi) {
#pragma unroll
      for (int nt = 0; nt < 4; ++nt)
#pragma unroll
        for (int r = 0; r < 4; ++r) s[nt][r] += rv_hi[r];
    } else {
#pragma unroll
      for (int nt = 0; nt < 4; ++nt)
#pragma unroll
        for (int r = 0; r < 4; ++r) s[nt][r] += rv_lo[r];
    }
    if (!inv) {
#pragma unroll
      for (int nt = 0; nt < 4; ++nt) {
        int ko = ko0 + nt * 16 + l15;
        if (ko >= len) {
#pragma unroll
          for (int r = 0; r < 4; ++r) s[nt][r] = NEGB;
        }
      }
    }
#pragma unroll
    for (int r = 0; r < 4; ++r) {
      float mx = fmaxf(fmaxf(s[0][r], s[1][r]), fmaxf(s[2][r], s[3][r]));
#pragma unroll
      for (int o = 1; o < 16; o <<= 1) mx = fmaxf(mx, __shfl_xor(mx, o, 64));
      float mn = fmaxf(m_[r], mx);
      alpha[r] = __expf(m_[r] - mn);
      float p0 = __expf(s[0][r] - mn), p1 = __expf(s[1][r] - mn);
      float p2 = __expf(s[2][r] - mn), p3 = __expf(s[3][r] - mn);
      s[0][r] = p0; s[1][r] = p1; s[2][r] = p2; s[3][r] = p3;
      float ps = p0 + p1 + p2 + p3;
#pragma unroll
      for (int o = 1; o < 16; o <<= 1) ps += __shfl_xor(ps, o, 64);
      l_[r] = l_[r] * alpha[r] + ps;
      m_[r] = mn;
    }
    // P into K region (wave-private rows; swizzled like K)
#pragma unroll
    for (int nt = 0; nt < 4; ++nt)
#pragma unroll
      for (int r = 0; r < 4; ++r) {
        int row = qw + quad * 4 + r;
        int col = nt * 16 + l15;
        Ks[row * 64 + (((col >> 3) ^ (row & 7)) << 3) + (col & 7)] = f2us(s[nt][r]);
      }
#pragma unroll
    for (int j = 0; j < 4; ++j)
#pragma unroll
      for (int r = 0; r < 4; ++r) acc[j][r] *= alpha[r];
    short8 ap0 = *(short8*)&Ks[(qw + l15) * 64 + ((quad ^ (l15 & 7)) << 3)];
    short8 ap1 = *(short8*)&Ks[(qw + l15) * 64 + (((4 + quad) ^ (l15 & 7)) << 3)];
#pragma unroll
    for (int j = 0; j < 4; ++j) {
      short8 bv0 = *(short8*)&Vt[(j * 16 + l15) * 72 + quad * 8];
      short8 bv1 = *(short8*)&Vt[(j * 16 + l15) * 72 + 32 + quad * 8];
      acc[j] = __builtin_amdgcn_mfma_f32_16x16x32_bf16(ap0, bv0, acc[j], 0, 0, 0);
      acc[j] = __builtin_amdgcn_mfma_f32_16x16x32_bf16(ap1, bv1, acc[j], 0, 0, 0);
    }
  }
#pragma unroll
  for (int r = 0; r < 4; ++r) {
    int qi = qw + quad * 4 + r;
    bool wr = inv ? (qi >= nskip) : (qi < nvalid);
    if (wr) {
      float invL = 1.0f / l_[r];
#pragma unroll
      for (int j = 0; j < 4; ++j)
        out[((long)(b * Tc + q0 + qi)) * Dc + h * 64 + j * 16 + l15] = f2us(acc[j][r] * invL);
    }
  }
}

// ---------------- elementwise (bf16) ----------------
__global__ void k_glu(ushort_t* __restrict__ h, int n) {
  int i = blockIdx.x * 256 + threadIdx.x;
  if (i >= n) return;
  int r = i >> 9, j = i & 511;
  float a = us2f(h[(long)r * 1024 + j]), g = us2f(h[(long)r * 1024 + 512 + j]);
  h[(long)r * 1024 + j] = f2us(a * (1.0f / (1.0f + __expf(-g))));
}
__global__ void k_swiglu(ushort_t* __restrict__ h, int n) {
  int i = blockIdx.x * 256 + threadIdx.x;
  if (i >= n) return;
  int r = i >> 10, j = i & 1023;
  float a = us2f(h[(long)r * 2048 + j]), bb = us2f(h[(long)r * 2048 + 1024 + j]);
  h[(long)r * 2048 + j] = f2us((a / (1.0f + __expf(-a))) * bb);
}
__global__ void k_dwconv(const ushort_t* __restrict__ in, const ushort_t* __restrict__ dw,
                         ushort_t* __restrict__ out, int n) {
  int i = blockIdx.x * 256 + threadIdx.x;
  if (i >= n) return;
  int d = i & 511;
  int t = (i >> 9) & (Tc - 1);
  int b = i >> 19;
  float acc = 0.0f;
#pragma unroll
  for (int j = 0; j < 9; ++j) {
    int tt = t + j - 4;
    if (tt >= 0 && tt < Tc) acc += us2f(in[((long)(b * Tc + tt) << 10) + d]) * us2f(dw[d * 9 + j]);
  }
  out[i] = f2us(acc * (1.0f / (1.0f + __expf(-acc))));
}

extern "C" void kernel_launch(void* const* d_in, const int* in_sizes, int n_in,
                              void* d_out, int out_size, void* d_ws, size_t ws_size,
                              hipStream_t stream) {
  const void* x_in = d_in[0];
  const int*  alen = (const int*)d_in[1];
  const void* ln1w = d_in[2];
  const void* ln1b = d_in[3];
  const void* wq   = d_in[4];
  const void* wk   = d_in[5];
  const void* wv   = d_in[6];
  const void* wo   = d_in[7];
  const void* rel  = d_in[8];
  const void* ln2w = d_in[9];
  const void* ln2b = d_in[10];
  const void* pw1  = d_in[11];
  const void* dwv  = d_in[12];
  const void* pw2  = d_in[13];
  const void* ln3w = d_in[14];
  const void* ln3b = d_in[15];
  const void* w1   = d_in[16];
  const void* w2   = d_in[17];

  // ---- workspace layout (bytes) ----
  char* base = (char*)d_ws;
  int*      flag = (int*)base;                       // 256
  float*    xf   = (float*)(base + 256);             // 8 MB f32 residual
  float*    lnb  = (float*)(base + 256 + 8388608);   // 8 MB f32 LN out (addend)
  ushort_t* lnA  = (ushort_t*)(base + 16777472);     // 4 MB bf16 LN out (GEMM A)
  ushort_t* wbf  = (ushort_t*)(base + 20971776);     // 24,350,208 B bf16 weights
  char*     U    = base + 45321984;                  // phase union
  // attn phase
  ushort_t* qb = (ushort_t*)U;                       // 4 MB
  ushort_t* kb = (ushort_t*)(U + 4194304);           // 1 MB
  ushort_t* vb = (ushort_t*)(U + 5242880);           // 1 MB
  ushort_t* ab = (ushort_t*)(U + 6291456);           // 4 MB
  // conv/ffn phase
  ushort_t* big = (ushort_t*)U;                      // up to 16 MB
  ushort_t* cb  = (ushort_t*)(U + 16777216);         // 4 MB
  size_t REQ = 45321984 + 16777216 + 4194304;
  if (ws_size < REQ) return;

  // bf16 weight table offsets (elements)
  ushort_t* wqB  = wbf + 0;
  ushort_t* wkB  = wbf + 1048576;
  ushort_t* wvB  = wbf + 1310720;
  ushort_t* woB  = wbf + 1572864;
  ushort_t* relB = wbf + 2621440;
  ushort_t* pw1B = wbf + 2719488;
  ushort_t* dwB  = wbf + 4816640;
  ushort_t* pw2B = wbf + 4835072;
  ushort_t* w1B  = wbf + 5883648;
  ushort_t* w2B  = wbf + 10077952;

  k_detect<<<1, 256, 0, stream>>>(x_in, flag);
  k_in<<<(int)((NE + 255) / 256), 256, 0, stream>>>(x_in, xf, (int)NE, flag);
  k_w2b<<<4096, 256, 0, stream>>>(wq,  wqB,  1048576, flag);
  k_w2b<<<1024, 256, 0, stream>>>(wk,  wkB,  262144, flag);
  k_w2b<<<1024, 256, 0, stream>>>(wv,  wvB,  262144, flag);
  k_w2b<<<4096, 256, 0, stream>>>(wo,  woB,  1048576, flag);
  k_w2b<<<383,  256, 0, stream>>>(rel, relB, 98048, flag);
  k_w2b<<<8192, 256, 0, stream>>>(pw1, pw1B, 2097152, flag);
  k_w2b<<<72,   256, 0, stream>>>(dwv, dwB,  18432, flag);
  k_w2b<<<4096, 256, 0, stream>>>(pw2, pw2B, 1048576, flag);
  k_w2b<<<16384,256, 0, stream>>>(w1,  w1B,  4194304, flag);
  k_w2b<<<8192, 256, 0, stream>>>(w2,  w2B,  2097152, flag);

  for (int i = 0; i < 4; ++i) {
    long oLN = (long)i * Dc;
    // ---- attention ----
    k_ln<<<NBT, 256, 0, stream>>>(xf, ln1w, ln1b, oLN, lnb, lnA, flag);
    k_gemm_b<64, 128, true><<<dim3(4, 64), 256, 0, stream>>>(lnA, Dc, wqB + (long)i * 262144, qb, Dc, nullptr, 0.125f, 512);
    k_gemm_b<64, 64, true><<<dim3(2, 64), 256, 0, stream>>>(lnA, Dc, wkB + (long)i * 65536, kb, 128, nullptr, 1.0f, 512);
    k_gemm_b<64, 64, true><<<dim3(2, 64), 256, 0, stream>>>(lnA, Dc, wvB + (long)i * 65536, vb, 128, nullptr, 1.0f, 512);
    k_attn<<<dim3(32, 8, 4), 256, 0, stream>>>(qb, kb, vb, relB + (long)i * 24512, alen, ab);
    k_gemm_b<64, 128, false><<<dim3(4, 64), 256, 0, stream>>>(ab, Dc, woB + (long)i * 262144, xf, Dc, lnb, 1.0f, 512);

    // ---- conv ----
    k_ln<<<NBT, 256, 0, stream>>>(xf, ln2w, ln2b, oLN, lnb, lnA, flag);
    k_gemm_b<128, 128, true><<<dim3(8, 32), 256, 0, stream>>>(lnA, Dc, pw1B + (long)i * 524288, big, 1024, nullptr, 1.0f, 512);
    k_glu<<<NBT * 512 / 256, 256, 0, stream>>>(big, NBT * 512);
    k_dwconv<<<NBT * 512 / 256, 256, 0, stream>>>(big, dwB + (long)i * 4608, cb, NBT * 512);
    k_gemm_b<64, 128, false><<<dim3(4, 64), 256, 0, stream>>>(cb, Dc, pw2B + (long)i * 262144, xf, Dc, lnb, 1.0f, 512);

    // ---- ffn ----
    k_ln<<<NBT, 256, 0, stream>>>(xf, ln3w, ln3b, oLN, lnb, lnA, flag);
    k_gemm_b<128, 128, true><<<dim3(16, 32), 256, 0, stream>>>(lnA, Dc, w1B + (long)i * 1048576, big, 2048, nullptr, 1.0f, 512);
    k_swiglu<<<NBT * 1024 / 256, 256, 0, stream>>>(big, NBT * 1024);
    k_gemm_b<64, 128, false><<<dim3(4, 64), 256, 0, stream>>>(big, 2048, w2B + (long)i * 524288, xf, Dc, lnb, 1.0f, 1024);
  }

  k_out<<<(int)((NE + 255) / 256), 256, 0, stream>>>(xf, d_out, (int)NE, flag);
}

// Round 5
// 1402.578 us; speedup vs baseline: 1.1622x; 1.1302x over previous
//
#include <hip/hip_runtime.h>
#include <hip/hip_bf16.h>

typedef __hip_bfloat16 bf16;
typedef unsigned short ushort_t;
typedef unsigned int uint_t;
typedef __attribute__((ext_vector_type(8))) short short8;
typedef __attribute__((ext_vector_type(4))) float floatx4;

__device__ __forceinline__ float b2f(bf16 x) { return __bfloat162float(x); }
__device__ __forceinline__ ushort_t f2us(float f) { bf16 h = __float2bfloat16(f); return *(ushort_t*)&h; }
__device__ __forceinline__ float us2f(ushort_t u) { return __uint_as_float(((uint_t)u) << 16); }

constexpr int Bc = 4, Tc = 1024, Dc = 512, Hc = 8, HDc = 64;
constexpr int LCc = 128, MPc = 192;
constexpr float EPSc = 1e-4f;
constexpr int NBT = Bc * Tc;
constexpr long NE = (long)NBT * Dc;
constexpr float NEGB = -1e30f;
constexpr int PSTRIDE = 8704;   // bytes per attention partial: 4096 bf16 C + 64 f32 m + 64 f32 l

__device__ __forceinline__ float wload(const void* p, long i, int f32) {
  return f32 ? ((const float*)p)[i] : b2f(((const bf16*)p)[i]);
}

// ---------------- dtype detector ----------------
__global__ void k_detect(const void* __restrict__ x, int* __restrict__ flag) {
  __shared__ int s[256];
  int t = threadIdx.x;
  const unsigned short* u = (const unsigned short*)x;
  int bad = 0;
  for (int j = t; j < 2048; j += 256) {
    int e = (u[j] >> 7) & 0xFF;
    if (e == 0xFF || e > 0x8F || (e != 0 && e < 0x6F)) bad++;
  }
  s[t] = bad;
  __syncthreads();
  for (int off = 128; off > 0; off >>= 1) { if (t < off) s[t] += s[t + off]; __syncthreads(); }
  if (t == 0) flag[0] = (s[0] > 16) ? 1 : 0;
}

__global__ void k_in(const void* __restrict__ in, float* __restrict__ out, int n,
                     const int* __restrict__ flag) {
  int i = blockIdx.x * 256 + threadIdx.x;
  if (i < n) out[i] = wload(in, i, flag[0]);
}
__global__ void k_out(const float* __restrict__ in, void* __restrict__ out, int n,
                      const int* __restrict__ flag) {
  int i = blockIdx.x * 256 + threadIdx.x;
  if (i >= n) return;
  if (flag[0]) ((float*)out)[i] = in[i];
  else         ((bf16*)out)[i] = __float2bfloat16(in[i]);
}
__global__ void k_w2b(const void* __restrict__ src, ushort_t* __restrict__ dst, int n,
                      const int* __restrict__ flag) {
  int i = blockIdx.x * 256 + threadIdx.x;
  if (i < n) dst[i] = f2us(wload(src, i, flag[0]));
}

// ---------------- LayerNorm: writes f32 (residual addend) + bf16 (GEMM A) ----------------
__global__ __launch_bounds__(256) void k_ln(const float* __restrict__ x,
    const void* __restrict__ w, const void* __restrict__ bb, long woff,
    float* __restrict__ o, ushort_t* __restrict__ oA, const int* __restrict__ flag) {
  int f32 = flag[0];
  int row = blockIdx.x;
  int t = threadIdx.x;
  const float* xr = x + (long)row * Dc;
  float x0 = xr[t], x1 = xr[t + 256];
  __shared__ float red[256];
  red[t] = x0 + x1;
  __syncthreads();
  for (int off = 128; off > 0; off >>= 1) { if (t < off) red[t] += red[t + off]; __syncthreads(); }
  float mean = red[0] * (1.0f / Dc);
  __syncthreads();
  float d0 = x0 - mean, d1 = x1 - mean;
  red[t] = d0 * d0 + d1 * d1;
  __syncthreads();
  for (int off = 128; off > 0; off >>= 1) { if (t < off) red[t] += red[t + off]; __syncthreads(); }
  float inv = 1.0f / sqrtf(red[0] * (1.0f / Dc) + EPSc);
  float v0 = d0 * inv * wload(w, woff + t, f32)       + wload(bb, woff + t, f32);
  float v1 = d1 * inv * wload(w, woff + t + 256, f32) + wload(bb, woff + t + 256, f32);
  float* orow = o + (long)row * Dc;
  ushort_t* arow = oA + (long)row * Dc;
  orow[t] = v0; orow[t + 256] = v1;
  arow[t] = f2us(v0); arow[t + 256] = f2us(v1);
}

// ---------------- bf16 MFMA GEMM: C = alpha*A@W^T (+f32 addend) ----------------
template<int BM, int BN, bool OBF>
__global__ __launch_bounds__(256) void k_gemm_b(const ushort_t* __restrict__ A, int lda,
    const ushort_t* __restrict__ W, void* __restrict__ C, int ldc,
    const float* __restrict__ addend, float alpha, int K) {
  constexpr int WGM = BM / 64;
  constexpr int WGN = 4 / WGM;
  constexpr int WN = BN / WGN;
  constexpr int NJ = WN / 16;
  __shared__ ushort_t As[BM * 64];
  __shared__ ushort_t Ws[BN * 64];
  int t = threadIdx.x;
  int m0 = blockIdx.y * BM, n0 = blockIdx.x * BN;
  int lane = t & 63, wv = t >> 6;
  int l15 = lane & 15, quad = lane >> 4;
  int wrow = (WGM == 2) ? (wv >> 1) * 64 : 0;
  int wcol = (WGM == 2) ? (wv & 1) * WN : wv * WN;
  floatx4 acc[4][NJ];
#pragma unroll
  for (int i = 0; i < 4; ++i)
#pragma unroll
    for (int j = 0; j < NJ; ++j) acc[i][j] = 0;
  for (int k0 = 0; k0 < K; k0 += 64) {
#pragma unroll
    for (int i = t; i < BM * 8; i += 256) {
      int r = i >> 3, c = i & 7;
      uint4 v = *(const uint4*)(A + (long)(m0 + r) * lda + k0 + c * 8);
      *(uint4*)&As[r * 64 + ((c ^ (r & 7)) << 3)] = v;
    }
#pragma unroll
    for (int i = t; i < BN * 8; i += 256) {
      int r = i >> 3, c = i & 7;
      uint4 v = *(const uint4*)(W + (long)(n0 + r) * K + k0 + c * 8);
      *(uint4*)&Ws[r * 64 + ((c ^ (r & 7)) << 3)] = v;
    }
    __syncthreads();
#pragma unroll
    for (int half = 0; half < 2; ++half) {
      int sw = ((half * 4 + quad) ^ (l15 & 7)) << 3;
      short8 af[4], bfr[NJ];
#pragma unroll
      for (int i = 0; i < 4; ++i) af[i] = *(short8*)&As[(wrow + i * 16 + l15) * 64 + sw];
#pragma unroll
      for (int j = 0; j < NJ; ++j) bfr[j] = *(short8*)&Ws[(wcol + j * 16 + l15) * 64 + sw];
#pragma unroll
      for (int i = 0; i < 4; ++i)
#pragma unroll
        for (int j = 0; j < NJ; ++j)
          acc[i][j] = __builtin_amdgcn_mfma_f32_16x16x32_bf16(af[i], bfr[j], acc[i][j], 0, 0, 0);
    }
    __syncthreads();
  }
#pragma unroll
  for (int i = 0; i < 4; ++i) {
#pragma unroll
    for (int j = 0; j < NJ; ++j) {
#pragma unroll
      for (int rg = 0; rg < 4; ++rg) {
        int m = m0 + wrow + i * 16 + quad * 4 + rg;
        int n = n0 + wcol + j * 16 + l15;
        float v = alpha * acc[i][j][rg];
        if (addend) v += addend[(long)m * ldc + n];
        if (OBF) ((ushort_t*)C)[(long)m * ldc + n] = f2us(v);
        else     ((float*)C)[(long)m * ldc + n] = v;
      }
    }
  }
}

// ---------------- flash attention, swapped-QK layout + grid split-K ----------------
// grid (80, 8, 4): x<16 valid band (3 k-tiles, writes out). x>=16: inv full-softmax split 4 ways
// (grp = (x-16)>>4 handles tiles {grp, grp+4, ...} of 18, ~5-tile serial chain) writing bf16
// partials + m/l, combined exactly by k_comb. Swapped QK: z = mfma(K,Q) -> each lane holds 16
// score values of ONE q-row (q = qw+l15): softmax reduce = 15 local fmax + 2 shfl (was 32 shfl).
// P repacked to LDS with 8 packed b32 writes; 2 barriers/tile; K/V prefetch issued after barrier B
// so its vmcnt drain at the next barrier A is covered by the compute phase.
__global__ __launch_bounds__(256, 3) void k_attn(const ushort_t* __restrict__ q,
    const ushort_t* __restrict__ kb, const ushort_t* __restrict__ vb,
    const ushort_t* __restrict__ relL, const int* __restrict__ alen,
    ushort_t* __restrict__ out, char* __restrict__ part) {
  int bx = blockIdx.x;
  int h = blockIdx.y, b = blockIdx.z;
  int len = alen[b];
  int inv, qt, grp;
  if (bx < 16) { inv = 0; qt = bx; grp = 0; }
  else         { inv = 1; qt = (bx - 16) & 15; grp = (bx - 16) >> 4; }
  int q0 = qt * 64;
  if (inv) { if (q0 + 64 <= len) return; }
  else     { if (q0 >= len) return; }
  int nvalid = min(len - q0, 64);
  int g = h >> 2;
  // LDS: UQB = union(Qs 64x72 | B2t 128x68), Ks 64x64 swz, Vt 64x72, Ps 64x64 swz, ML strip
  __shared__ __align__(16) ushort_t UQB[8704];
  __shared__ __align__(16) ushort_t Ks[64 * 64];
  __shared__ __align__(16) ushort_t Vt[64 * 72];
  __shared__ __align__(16) ushort_t Ps[64 * 64];
  __shared__ __align__(16) float fML[128];           // [0..63] alpha, [64..127] l
  ushort_t* Qs = UQB;       // pitch 72 (only before loop)
  ushort_t* B2t = UQB;      // pitch 68, rows=c' (0..127), cols=q (0..63)
  int t = threadIdx.x;
  int lane = t & 63, w = t >> 6;
  int l15 = lane & 15, quad = lane >> 4;
  int qw = w * 16;
  {
    int qi = t >> 2, du = (t & 3) * 16;
    const ushort_t* src = q + ((long)(b * Tc + q0 + qi)) * Dc + h * 64 + du;
    *(uint4*)&Qs[qi * 72 + du] = *(const uint4*)(src);
    *(uint4*)&Qs[qi * 72 + du + 8] = *(const uint4*)(src + 8);
  }
  const int koB = inv ? -128 : (q0 - 128);
  const int NT = inv ? 18 : 3;
  const int KSTEP = inv ? 4 : 1;
  const int nIt = inv ? ((grp < 2) ? 5 : 4) : 3;
  // K/V prefetch regs
  uint4 kr0, kr1, vr0, vr1;
  int kj = t >> 2, du = (t & 3) * 16, c0 = du >> 3;
  auto LOADKV = [&](int kt2) {
    int ko = koB + kt2 * 64 + kj;
    if (ko >= 0) {
      long basek = ((long)(b * Tc + ko)) * 128 + g * 64 + du;
      kr0 = *(const uint4*)(kb + basek);
      kr1 = *(const uint4*)(kb + basek + 8);
      vr0 = *(const uint4*)(vb + basek);
      vr1 = *(const uint4*)(vb + basek + 8);
    } else {
      uint4 z = {0, 0, 0, 0};
      kr0 = z; kr1 = z; vr0 = z; vr1 = z;
    }
  };
  LOADKV(grp);
  float m_ = NEGB, l_ = 0.f;
  floatx4 acc[4];
#pragma unroll
  for (int j = 0; j < 4; ++j) acc[j] = 0;
  __syncthreads();
  short8 aq0 = *(short8*)&Qs[(qw + l15) * 72 + quad * 8];
  short8 aq1 = *(short8*)&Qs[(qw + l15) * 72 + 32 + quad * 8];
  // edge-rel constants for this lane's q-row (inv far tiles): rv = Q[q] . rel[0 / 382]
  float rv_lo = 0.f, rv_hi = 0.f;
  if (inv) {
    int er = (l15 == 1) ? 382 : 0;
    short8 be0 = *(const short8*)(relL + (long)er * 64 + quad * 8);
    short8 be1 = *(const short8*)(relL + (long)er * 64 + 32 + quad * 8);
    floatx4 ec = {0.f, 0.f, 0.f, 0.f};
    ec = __builtin_amdgcn_mfma_f32_16x16x32_bf16(be0, aq0, ec, 0, 0, 0);
    ec = __builtin_amdgcn_mfma_f32_16x16x32_bf16(be1, aq1, ec, 0, 0, 0);
    rv_lo = __shfl(ec[0], l15, 64);
    rv_hi = __shfl(ec[1], l15, 64);
  }
  int sw7 = l15 & 7;
  for (int it = 0; it < nIt; ++it) {
    int kt = inv ? (grp + it * KSTEP) : it;
    int ko0 = koB + kt * 64;
    int t0 = q0 - ko0 + 191;
    bool far_hi = (q0 - ko0 - 63) >= 191;
    bool far_lo = (q0 + 63 - ko0) <= -191;
    bool near = !far_hi && !far_lo;
    int cb = min(max(t0 - 63, 0), 255);
    __syncthreads();   // A: prev tile reads done; prefetch loads drained (covered by compute)
    {
      *(uint4*)&Ks[kj * 64 + ((c0 ^ (kj & 7)) << 3)] = kr0;
      *(uint4*)&Ks[kj * 64 + (((c0 + 1) ^ (kj & 7)) << 3)] = kr1;
      uint_t wds[8] = {vr0.x, vr0.y, vr0.z, vr0.w, vr1.x, vr1.y, vr1.z, vr1.w};
#pragma unroll
      for (int u = 0; u < 8; ++u) {
        Vt[(du + 2 * u) * 72 + kj] = (ushort_t)(wds[u] & 0xffff);
        Vt[(du + 2 * u + 1) * 72 + kj] = (ushort_t)(wds[u] >> 16);
      }
    }
    if (near) {
      // B2t[c'][q] = rel[cb+c'] . Q[q] via swapped MFMA (A = rel rows, B = Q rows)
#pragma unroll
      for (int p = 0; p < 2; ++p) {
        short8 rw0[4], rw1[4];
#pragma unroll
        for (int j = 0; j < 4; ++j) {
          long wr = cb + (p * 4 + j) * 16 + l15;
          rw0[j] = *(const short8*)(relL + wr * 64 + quad * 8);
          rw1[j] = *(const short8*)(relL + wr * 64 + 32 + quad * 8);
        }
#pragma unroll
        for (int j = 0; j < 4; ++j) {
          floatx4 z = {0.f, 0.f, 0.f, 0.f};
          z = __builtin_amdgcn_mfma_f32_16x16x32_bf16(rw0[j], aq0, z, 0, 0, 0);
          z = __builtin_amdgcn_mfma_f32_16x16x32_bf16(rw1[j], aq1, z, 0, 0, 0);
#pragma unroll
          for (int rg = 0; rg < 4; ++rg) {
            int cpr = (p * 4 + j) * 16 + quad * 4 + rg;
            B2t[cpr * 68 + qw + l15] = f2us(z[rg]);
          }
        }
      }
    }
    __syncthreads();   // B: staging visible
    if (it + 1 < nIt) LOADKV(kt + KSTEP);   // issue AFTER barrier: compute covers latency
    // QK^T swapped: s[nt][rg] = S[q=qw+l15][k = nt*16+quad*4+rg]
    floatx4 s[4];
#pragma unroll
    for (int nt = 0; nt < 4; ++nt) {
      short8 ak0 = *(short8*)&Ks[(nt * 16 + l15) * 64 + ((quad ^ sw7) << 3)];
      short8 ak1 = *(short8*)&Ks[(nt * 16 + l15) * 64 + (((4 + quad) ^ sw7) << 3)];
      floatx4 z = {0.f, 0.f, 0.f, 0.f};
      z = __builtin_amdgcn_mfma_f32_16x16x32_bf16(ak0, aq0, z, 0, 0, 0);
      z = __builtin_amdgcn_mfma_f32_16x16x32_bf16(ak1, aq1, z, 0, 0, 0);
      s[nt] = z;
    }
    // rel bias
    if (near) {
#pragma unroll
      for (int nt = 0; nt < 4; ++nt)
#pragma unroll
        for (int rg = 0; rg < 4; ++rg) {
          int c = t0 + qw + l15 - (nt * 16 + quad * 4 + rg);
          c = min(max(c, 0), 382);
          s[nt][rg] += us2f(B2t[(c - cb) * 68 + qw + l15]);
        }
    } else {
      float rv = far_hi ? rv_hi : rv_lo;
#pragma unroll
      for (int nt = 0; nt < 4; ++nt)
#pragma unroll
        for (int rg = 0; rg < 4; ++rg) s[nt][rg] += rv;
    }
    if (!inv) {
#pragma unroll
      for (int nt = 0; nt < 4; ++nt)
#pragma unroll
        for (int rg = 0; rg < 4; ++rg) {
          int ko = ko0 + nt * 16 + quad * 4 + rg;
          if (ko >= len) s[nt][rg] = NEGB;
        }
    }
    // row softmax: 15 local fmax + 2 shfl; sum likewise
    float mx = s[0][0];
#pragma unroll
    for (int nt = 0; nt < 4; ++nt)
#pragma unroll
      for (int rg = 0; rg < 4; ++rg) mx = fmaxf(mx, s[nt][rg]);
    mx = fmaxf(mx, __shfl_xor(mx, 16, 64));
    mx = fmaxf(mx, __shfl_xor(mx, 32, 64));
    float mn = fmaxf(m_, mx);
    float al = __expf(m_ - mn);
    float ps = 0.f;
#pragma unroll
    for (int nt = 0; nt < 4; ++nt)
#pragma unroll
      for (int rg = 0; rg < 4; ++rg) {
        float p = __expf(s[nt][rg] - mn);
        s[nt][rg] = p;
        ps += p;
      }
    ps += __shfl_xor(ps, 16, 64);
    ps += __shfl_xor(ps, 32, 64);
    l_ = l_ * al + ps;
    m_ = mn;
    // alpha strip: written by quad0 lanes, read back as f32x4 per output row group
    if (quad == 0) fML[qw + l15] = al;
    // P into Ps (packed b32, XOR swizzle matching ap reads)
#pragma unroll
    for (int nt = 0; nt < 4; ++nt)
#pragma unroll
      for (int pr = 0; pr < 2; ++pr) {
        uint_t pk = (uint_t)f2us(s[nt][2 * pr]) | ((uint_t)f2us(s[nt][2 * pr + 1]) << 16);
        int e = nt * 16 + quad * 4 + pr * 2;
        *(uint_t*)&Ps[(qw + l15) * 64 + (((e >> 3) ^ sw7) << 3) + (e & 7)] = pk;
      }
    floatx4 av = *(floatx4*)&fML[qw + quad * 4];
#pragma unroll
    for (int j = 0; j < 4; ++j)
#pragma unroll
      for (int rg = 0; rg < 4; ++rg) acc[j][rg] *= av[rg];
    short8 ap0 = *(short8*)&Ps[(qw + l15) * 64 + ((quad ^ sw7) << 3)];
    short8 ap1 = *(short8*)&Ps[(qw + l15) * 64 + (((4 + quad) ^ sw7) << 3)];
#pragma unroll
    for (int j = 0; j < 4; ++j) {
      short8 bv0 = *(short8*)&Vt[(j * 16 + l15) * 72 + quad * 8];
      short8 bv1 = *(short8*)&Vt[(j * 16 + l15) * 72 + 32 + quad * 8];
      acc[j] = __builtin_amdgcn_mfma_f32_16x16x32_bf16(ap0, bv0, acc[j], 0, 0, 0);
      acc[j] = __builtin_amdgcn_mfma_f32_16x16x32_bf16(ap1, bv1, acc[j], 0, 0, 0);
    }
  }
  if (inv) {
    // write partial: bf16 C + f32 m/l
    char* pp = part + (long)((((b * 8 + h) * 16 + qt) * 4 + grp)) * PSTRIDE;
    ushort_t* Cp = (ushort_t*)pp;
    float* mp = (float*)(pp + 8192);
#pragma unroll
    for (int j = 0; j < 4; ++j)
#pragma unroll
      for (int rg = 0; rg < 4; ++rg)
        Cp[(qw + quad * 4 + rg) * 64 + j * 16 + l15] = f2us(acc[j][rg]);
    if (quad == 0) { mp[qw + l15] = m_; mp[64 + qw + l15] = l_; }
  } else {
    if (quad == 0) fML[64 + qw + l15] = l_;
    floatx4 lv = *(floatx4*)&fML[64 + qw + quad * 4];
#pragma unroll
    for (int rg = 0; rg < 4; ++rg) {
      int R = qw + quad * 4 + rg;
      if (R < nvalid) {
        float invL = 1.0f / lv[rg];
#pragma unroll
        for (int j = 0; j < 4; ++j)
          out[((long)(b * Tc + q0 + R)) * Dc + h * 64 + j * 16 + l15] = f2us(acc[j][rg] * invL);
      }
    }
  }
}

// ---------------- exact split-K combine for inv partials ----------------
__global__ __launch_bounds__(256) void k_comb(const char* __restrict__ part,
    const int* __restrict__ alen, ushort_t* __restrict__ out) {
  int qt = blockIdx.x, h = blockIdx.y, b = blockIdx.z;
  int len = alen[b];
  int q0 = qt * 64;
  if (q0 + 64 <= len) return;
  int nskip = max(len - q0, 0);
  int t = threadIdx.x;
  int d = t & 63, r0 = (t >> 6) * 16;
  const char* pb = part + (long)(((b * 8 + h) * 16 + qt) * 4) * PSTRIDE;
#pragma unroll 4
  for (int i = 0; i < 16; ++i) {
    int r = r0 + i;
    if (r < nskip) continue;
    float mg[4], lg[4], M = NEGB;
#pragma unroll
    for (int g2 = 0; g2 < 4; ++g2) {
      const float* mp = (const float*)(pb + g2 * PSTRIDE + 8192);
      mg[g2] = mp[r];
      lg[g2] = mp[64 + r];
      M = fmaxf(M, mg[g2]);
    }
    float L = 0.f, wgt[4];
#pragma unroll
    for (int g2 = 0; g2 < 4; ++g2) { wgt[g2] = __expf(mg[g2] - M); L += lg[g2] * wgt[g2]; }
    float v = 0.f;
#pragma unroll
    for (int g2 = 0; g2 < 4; ++g2)
      v += us2f(((const ushort_t*)(pb + g2 * PSTRIDE))[r * 64 + d]) * wgt[g2];
    out[((long)(b * Tc + q0 + r)) * Dc + h * 64 + d] = f2us(v / L);
  }
}

// ---------------- elementwise (bf16) ----------------
__global__ void k_glu(ushort_t* __restrict__ h, int n) {
  int i = blockIdx.x * 256 + threadIdx.x;
  if (i >= n) return;
  int r = i >> 9, j = i & 511;
  float a = us2f(h[(long)r * 1024 + j]), g = us2f(h[(long)r * 1024 + 512 + j]);
  h[(long)r * 1024 + j] = f2us(a * (1.0f / (1.0f + __expf(-g))));
}
__global__ void k_swiglu(ushort_t* __restrict__ h, int n) {
  int i = blockIdx.x * 256 + threadIdx.x;
  if (i >= n) return;
  int r = i >> 10, j = i & 1023;
  float a = us2f(h[(long)r * 2048 + j]), bb = us2f(h[(long)r * 2048 + 1024 + j]);
  h[(long)r * 2048 + j] = f2us((a / (1.0f + __expf(-a))) * bb);
}
__global__ void k_dwconv(const ushort_t* __restrict__ in, const ushort_t* __restrict__ dw,
                         ushort_t* __restrict__ out, int n) {
  int i = blockIdx.x * 256 + threadIdx.x;
  if (i >= n) return;
  int d = i & 511;
  int t = (i >> 9) & (Tc - 1);
  int b = i >> 19;
  float acc = 0.0f;
#pragma unroll
  for (int j = 0; j < 9; ++j) {
    int tt = t + j - 4;
    if (tt >= 0 && tt < Tc) acc += us2f(in[((long)(b * Tc + tt) << 10) + d]) * us2f(dw[d * 9 + j]);
  }
  out[i] = f2us(acc * (1.0f / (1.0f + __expf(-acc))));
}

extern "C" void kernel_launch(void* const* d_in, const int* in_sizes, int n_in,
                              void* d_out, int out_size, void* d_ws, size_t ws_size,
                              hipStream_t stream) {
  const void* x_in = d_in[0];
  const int*  alen = (const int*)d_in[1];
  const void* ln1w = d_in[2];
  const void* ln1b = d_in[3];
  const void* wq   = d_in[4];
  const void* wk   = d_in[5];
  const void* wv   = d_in[6];
  const void* wo   = d_in[7];
  const void* rel  = d_in[8];
  const void* ln2w = d_in[9];
  const void* ln2b = d_in[10];
  const void* pw1  = d_in[11];
  const void* dwv  = d_in[12];
  const void* pw2  = d_in[13];
  const void* ln3w = d_in[14];
  const void* ln3b = d_in[15];
  const void* w1   = d_in[16];
  const void* w2   = d_in[17];

  // ---- workspace layout (bytes) ----
  char* base = (char*)d_ws;
  int*      flag = (int*)base;                       // 256
  float*    xf   = (float*)(base + 256);             // 8 MB f32 residual
  float*    lnb  = (float*)(base + 256 + 8388608);   // 8 MB f32 LN out (addend)
  ushort_t* lnA  = (ushort_t*)(base + 16777472);     // 4 MB bf16 LN out (GEMM A)
  ushort_t* wbf  = (ushort_t*)(base + 20971776);     // 24,350,208 B bf16 weights
  char*     U    = base + 45321984;                  // phase union
  // attn phase
  ushort_t* qb = (ushort_t*)U;                       // 4 MB
  ushort_t* kb = (ushort_t*)(U + 4194304);           // 1 MB
  ushort_t* vb = (ushort_t*)(U + 5242880);           // 1 MB
  ushort_t* ab = (ushort_t*)(U + 6291456);           // 4 MB
  char*     partA = U + 10485760;                    // 17,825,792 B attn partials (old Rq spot)
  // conv/ffn phase
  ushort_t* big = (ushort_t*)U;                      // up to 16 MB
  ushort_t* cb  = (ushort_t*)(U + 16777216);         // 4 MB
  size_t REQ = 45321984 + 16777216 + 4194304;
  size_t REQ2 = 45321984 + 35651584;                 // proven available in prior rounds
  if (REQ2 > REQ) REQ = REQ2;
  if (ws_size < REQ) return;

  // bf16 weight table offsets (elements)
  ushort_t* wqB  = wbf + 0;
  ushort_t* wkB  = wbf + 1048576;
  ushort_t* wvB  = wbf + 1310720;
  ushort_t* woB  = wbf + 1572864;
  ushort_t* relB = wbf + 2621440;
  ushort_t* pw1B = wbf + 2719488;
  ushort_t* dwB  = wbf + 4816640;
  ushort_t* pw2B = wbf + 4835072;
  ushort_t* w1B  = wbf + 5883648;
  ushort_t* w2B  = wbf + 10077952;

  k_detect<<<1, 256, 0, stream>>>(x_in, flag);
  k_in<<<(int)((NE + 255) / 256), 256, 0, stream>>>(x_in, xf, (int)NE, flag);
  k_w2b<<<4096, 256, 0, stream>>>(wq,  wqB,  1048576, flag);
  k_w2b<<<1024, 256, 0, stream>>>(wk,  wkB,  262144, flag);
  k_w2b<<<1024, 256, 0, stream>>>(wv,  wvB,  262144, flag);
  k_w2b<<<4096, 256, 0, stream>>>(wo,  woB,  1048576, flag);
  k_w2b<<<383,  256, 0, stream>>>(rel, relB, 98048, flag);
  k_w2b<<<8192, 256, 0, stream>>>(pw1, pw1B, 2097152, flag);
  k_w2b<<<72,   256, 0, stream>>>(dwv, dwB,  18432, flag);
  k_w2b<<<4096, 256, 0, stream>>>(pw2, pw2B, 1048576, flag);
  k_w2b<<<16384,256, 0, stream>>>(w1,  w1B,  4194304, flag);
  k_w2b<<<8192, 256, 0, stream>>>(w2,  w2B,  2097152, flag);

  for (int i = 0; i < 4; ++i) {
    long oLN = (long)i * Dc;
    // ---- attention ----
    k_ln<<<NBT, 256, 0, stream>>>(xf, ln1w, ln1b, oLN, lnb, lnA, flag);
    k_gemm_b<64, 128, true><<<dim3(4, 64), 256, 0, stream>>>(lnA, Dc, wqB + (long)i * 262144, qb, Dc, nullptr, 0.125f, 512);
    k_gemm_b<64, 64, true><<<dim3(2, 64), 256, 0, stream>>>(lnA, Dc, wkB + (long)i * 65536, kb, 128, nullptr, 1.0f, 512);
    k_gemm_b<64, 64, true><<<dim3(2, 64), 256, 0, stream>>>(lnA, Dc, wvB + (long)i * 65536, vb, 128, nullptr, 1.0f, 512);
    k_attn<<<dim3(80, 8, 4), 256, 0, stream>>>(qb, kb, vb, relB + (long)i * 24512, alen, ab, partA);
    k_comb<<<dim3(16, 8, 4), 256, 0, stream>>>(partA, alen, ab);
    k_gemm_b<64, 128, false><<<dim3(4, 64), 256, 0, stream>>>(ab, Dc, woB + (long)i * 262144, xf, Dc, lnb, 1.0f, 512);

    // ---- conv ----
    k_ln<<<NBT, 256, 0, stream>>>(xf, ln2w, ln2b, oLN, lnb, lnA, flag);
    k_gemm_b<128, 128, true><<<dim3(8, 32), 256, 0, stream>>>(lnA, Dc, pw1B + (long)i * 524288, big, 1024, nullptr, 1.0f, 512);
    k_glu<<<NBT * 512 / 256, 256, 0, stream>>>(big, NBT * 512);
    k_dwconv<<<NBT * 512 / 256, 256, 0, stream>>>(big, dwB + (long)i * 4608, cb, NBT * 512);
    k_gemm_b<64, 128, false><<<dim3(4, 64), 256, 0, stream>>>(cb, Dc, pw2B + (long)i * 262144, xf, Dc, lnb, 1.0f, 512);

    // ---- ffn ----
    k_ln<<<NBT, 256, 0, stream>>>(xf, ln3w, ln3b, oLN, lnb, lnA, flag);
    k_gemm_b<128, 128, true><<<dim3(16, 32), 256, 0, stream>>>(lnA, Dc, w1B + (long)i * 1048576, big, 2048, nullptr, 1.0f, 512);
    k_swiglu<<<NBT * 1024 / 256, 256, 0, stream>>>(big, NBT * 1024);
    k_gemm_b<64, 128, false><<<dim3(4, 64), 256, 0, stream>>>(big, 2048, w2B + (long)i * 524288, xf, Dc, lnb, 1.0f, 1024);
  }

  k_out<<<(int)((NE + 255) / 256), 256, 0, stream>>>(xf, d_out, (int)NE, flag);
}

// Round 6
// 1028.479 us; speedup vs baseline: 1.5850x; 1.3637x over previous
//
#include <hip/hip_runtime.h>
#include <hip/hip_bf16.h>

typedef __hip_bfloat16 bf16;
typedef unsigned short ushort_t;
typedef unsigned int uint_t;
typedef __attribute__((ext_vector_type(8))) short short8;
typedef __attribute__((ext_vector_type(4))) float floatx4;

__device__ __forceinline__ float b2f(bf16 x) { return __bfloat162float(x); }
__device__ __forceinline__ ushort_t f2us(float f) { bf16 h = __float2bfloat16(f); return *(ushort_t*)&h; }
__device__ __forceinline__ float us2f(ushort_t u) { return __uint_as_float(((uint_t)u) << 16); }

constexpr int Bc = 4, Tc = 1024, Dc = 512, Hc = 8, HDc = 64;
constexpr int LCc = 128, MPc = 192;
constexpr float EPSc = 1e-4f;
constexpr int NBT = Bc * Tc;
constexpr long NE = (long)NBT * Dc;
constexpr float NEGB = -1e30f;
constexpr int PSTRIDE = 8704;   // bytes per attention partial: 4096 bf16 C + 64 f32 m + 64 f32 l

__device__ __forceinline__ float wload(const void* p, long i, int f32) {
  return f32 ? ((const float*)p)[i] : b2f(((const bf16*)p)[i]);
}

// async global->LDS staging of a ROWSx64 bf16 tile with XOR swizzle.
// LDS dest is LINEAR (global_load_lds writes base+lane*16); the swizzle is applied by
// PRE-SWIZZLING the global source chunk index (T21: source perm == read perm).
// LDS slot s of row r holds global chunk s^(r&7); read side uses the same XOR.
__device__ __forceinline__ void stage_swz(const ushort_t* __restrict__ G, int rowStride,
                                          int rowBase, int k0, ushort_t* L, int nChunk, int t) {
#pragma unroll
  for (int i = t; i < nChunk; i += 256) {
    int r = i >> 3;
    int cs = (i & 7) ^ (r & 7);
    const ushort_t* gp = G + (long)(rowBase + r) * rowStride + k0 + cs * 8;
    __builtin_amdgcn_global_load_lds(
        (const __attribute__((address_space(1))) void*)gp,
        (__attribute__((address_space(3))) void*)&L[(i & ~63) * 8], 16, 0, 0);
  }
}

// ---------------- dtype detector ----------------
__global__ void k_detect(const void* __restrict__ x, int* __restrict__ flag) {
  __shared__ int s[256];
  int t = threadIdx.x;
  const unsigned short* u = (const unsigned short*)x;
  int bad = 0;
  for (int j = t; j < 2048; j += 256) {
    int e = (u[j] >> 7) & 0xFF;
    if (e == 0xFF || e > 0x8F || (e != 0 && e < 0x6F)) bad++;
  }
  s[t] = bad;
  __syncthreads();
  for (int off = 128; off > 0; off >>= 1) { if (t < off) s[t] += s[t + off]; __syncthreads(); }
  if (t == 0) flag[0] = (s[0] > 16) ? 1 : 0;
}

__global__ void k_in(const void* __restrict__ in, float* __restrict__ out, int n,
                     const int* __restrict__ flag) {
  int i = blockIdx.x * 256 + threadIdx.x;
  if (i < n) out[i] = wload(in, i, flag[0]);
}
__global__ void k_out(const float* __restrict__ in, void* __restrict__ out, int n,
                      const int* __restrict__ flag) {
  int i = blockIdx.x * 256 + threadIdx.x;
  if (i >= n) return;
  if (flag[0]) ((float*)out)[i] = in[i];
  else         ((bf16*)out)[i] = __float2bfloat16(in[i]);
}
__global__ void k_w2b(const void* __restrict__ src, ushort_t* __restrict__ dst, int n,
                      const int* __restrict__ flag) {
  int i = blockIdx.x * 256 + threadIdx.x;
  if (i < n) dst[i] = f2us(wload(src, i, flag[0]));
}
// depthwise conv weights, transposed to [L][9][512] for coalesced tap loads
__global__ void k_w2bT(const void* __restrict__ src, ushort_t* __restrict__ dst,
                       const int* __restrict__ flag) {
  int i = blockIdx.x * 256 + threadIdx.x;
  if (i >= 18432) return;
  int l = i / 4608, rem = i - l * 4608;
  int j = rem >> 9, d = rem & 511;
  dst[i] = f2us(wload(src, (long)l * 4608 + d * 9 + j, flag[0]));
}

// ---------------- LayerNorm: wave-shuffle reduce, float2 loads, 2 barriers ----------------
__global__ __launch_bounds__(256) void k_ln(const float* __restrict__ x,
    const void* __restrict__ w, const void* __restrict__ bb, long woff,
    float* __restrict__ o, ushort_t* __restrict__ oA, const int* __restrict__ flag) {
  int f32 = flag[0];
  int row = blockIdx.x;
  int t = threadIdx.x;
  int lane = t & 63, wv = t >> 6;
  float2 v = ((const float2*)(x + (long)row * Dc))[t];
  float s = v.x + v.y;
#pragma unroll
  for (int o2 = 1; o2 < 64; o2 <<= 1) s += __shfl_xor(s, o2, 64);
  __shared__ float ws[8];
  if (lane == 0) ws[wv] = s;
  __syncthreads();
  float mean = (ws[0] + ws[1] + ws[2] + ws[3]) * (1.0f / Dc);
  float dx = v.x - mean, dy = v.y - mean;
  float s2 = dx * dx + dy * dy;
#pragma unroll
  for (int o2 = 1; o2 < 64; o2 <<= 1) s2 += __shfl_xor(s2, o2, 64);
  if (lane == 0) ws[4 + wv] = s2;
  __syncthreads();
  float inv = 1.0f / sqrtf((ws[4] + ws[5] + ws[6] + ws[7]) * (1.0f / Dc) + EPSc);
  float v0 = dx * inv * wload(w, woff + 2 * t, f32)     + wload(bb, woff + 2 * t, f32);
  float v1 = dy * inv * wload(w, woff + 2 * t + 1, f32) + wload(bb, woff + 2 * t + 1, f32);
  float2 ov; ov.x = v0; ov.y = v1;
  ((float2*)(o + (long)row * Dc))[t] = ov;
  ((uint_t*)(oA + (long)row * Dc))[t] = (uint_t)f2us(v0) | ((uint_t)f2us(v1) << 16);
}

// ---------------- bf16 MFMA GEMM: C = alpha*A@W^T (+f32 addend), async LDS staging ----------------
template<int BM, int BN, bool OBF>
__global__ __launch_bounds__(256) void k_gemm_b(const ushort_t* __restrict__ A, int lda,
    const ushort_t* __restrict__ W, void* __restrict__ C, int ldc,
    const float* __restrict__ addend, float alpha, int K) {
  constexpr int WGM = BM / 64;
  constexpr int WGN = 4 / WGM;
  constexpr int WN = BN / WGN;
  constexpr int NJ = WN / 16;
  __shared__ ushort_t As[BM * 64];
  __shared__ ushort_t Ws[BN * 64];
  int t = threadIdx.x;
  int m0 = blockIdx.y * BM, n0 = blockIdx.x * BN;
  int lane = t & 63, wv = t >> 6;
  int l15 = lane & 15, quad = lane >> 4;
  int wrow = (WGM == 2) ? (wv >> 1) * 64 : 0;
  int wcol = (WGM == 2) ? (wv & 1) * WN : wv * WN;
  floatx4 acc[4][NJ];
#pragma unroll
  for (int i = 0; i < 4; ++i)
#pragma unroll
    for (int j = 0; j < NJ; ++j) acc[i][j] = 0;
  for (int k0 = 0; k0 < K; k0 += 64) {
    stage_swz(A, lda, m0, k0, As, BM * 8, t);
    stage_swz(W, K,  n0, k0, Ws, BN * 8, t);
    __syncthreads();   // compiler drains vmcnt before s_barrier
#pragma unroll
    for (int half = 0; half < 2; ++half) {
      int sw = ((half * 4 + quad) ^ (l15 & 7)) << 3;
      short8 af[4], bfr[NJ];
#pragma unroll
      for (int i = 0; i < 4; ++i) af[i] = *(short8*)&As[(wrow + i * 16 + l15) * 64 + sw];
#pragma unroll
      for (int j = 0; j < NJ; ++j) bfr[j] = *(short8*)&Ws[(wcol + j * 16 + l15) * 64 + sw];
#pragma unroll
      for (int i = 0; i < 4; ++i)
#pragma unroll
        for (int j = 0; j < NJ; ++j)
          acc[i][j] = __builtin_amdgcn_mfma_f32_16x16x32_bf16(af[i], bfr[j], acc[i][j], 0, 0, 0);
    }
    __syncthreads();
  }
#pragma unroll
  for (int i = 0; i < 4; ++i) {
#pragma unroll
    for (int j = 0; j < NJ; ++j) {
#pragma unroll
      for (int rg = 0; rg < 4; ++rg) {
        int m = m0 + wrow + i * 16 + quad * 4 + rg;
        int n = n0 + wcol + j * 16 + l15;
        float v = alpha * acc[i][j][rg];
        if (addend) v += addend[(long)m * ldc + n];
        if (OBF) ((ushort_t*)C)[(long)m * ldc + n] = f2us(v);
        else     ((float*)C)[(long)m * ldc + n] = v;
      }
    }
  }
}

// ---------------- flash attention, swapped-QK layout + grid split-K (r5 structure + setprio) ----
__global__ __launch_bounds__(256, 3) void k_attn(const ushort_t* __restrict__ q,
    const ushort_t* __restrict__ kb, const ushort_t* __restrict__ vb,
    const ushort_t* __restrict__ relL, const int* __restrict__ alen,
    ushort_t* __restrict__ out, char* __restrict__ part) {
  int bx = blockIdx.x;
  int h = blockIdx.y, b = blockIdx.z;
  int len = alen[b];
  int inv, qt, grp;
  if (bx < 16) { inv = 0; qt = bx; grp = 0; }
  else         { inv = 1; qt = (bx - 16) & 15; grp = (bx - 16) >> 4; }
  int q0 = qt * 64;
  if (inv) { if (q0 + 64 <= len) return; }
  else     { if (q0 >= len) return; }
  int nvalid = min(len - q0, 64);
  int g = h >> 2;
  __shared__ __align__(16) ushort_t UQB[8704];
  __shared__ __align__(16) ushort_t Ks[64 * 64];
  __shared__ __align__(16) ushort_t Vt[64 * 72];
  __shared__ __align__(16) ushort_t Ps[64 * 64];
  __shared__ __align__(16) float fML[128];
  ushort_t* Qs = UQB;
  ushort_t* B2t = UQB;
  int t = threadIdx.x;
  int lane = t & 63, w = t >> 6;
  int l15 = lane & 15, quad = lane >> 4;
  int qw = w * 16;
  {
    int qi = t >> 2, du = (t & 3) * 16;
    const ushort_t* src = q + ((long)(b * Tc + q0 + qi)) * Dc + h * 64 + du;
    *(uint4*)&Qs[qi * 72 + du] = *(const uint4*)(src);
    *(uint4*)&Qs[qi * 72 + du + 8] = *(const uint4*)(src + 8);
  }
  const int koB = inv ? -128 : (q0 - 128);
  const int KSTEP = inv ? 4 : 1;
  const int nIt = inv ? ((grp < 2) ? 5 : 4) : 3;
  uint4 kr0, kr1, vr0, vr1;
  int kj = t >> 2, du = (t & 3) * 16, c0 = du >> 3;
  auto LOADKV = [&](int kt2) {
    int ko = koB + kt2 * 64 + kj;
    if (ko >= 0) {
      long basek = ((long)(b * Tc + ko)) * 128 + g * 64 + du;
      kr0 = *(const uint4*)(kb + basek);
      kr1 = *(const uint4*)(kb + basek + 8);
      vr0 = *(const uint4*)(vb + basek);
      vr1 = *(const uint4*)(vb + basek + 8);
    } else {
      uint4 z = {0, 0, 0, 0};
      kr0 = z; kr1 = z; vr0 = z; vr1 = z;
    }
  };
  LOADKV(grp);
  float m_ = NEGB, l_ = 0.f;
  floatx4 acc[4];
#pragma unroll
  for (int j = 0; j < 4; ++j) acc[j] = 0;
  __syncthreads();
  short8 aq0 = *(short8*)&Qs[(qw + l15) * 72 + quad * 8];
  short8 aq1 = *(short8*)&Qs[(qw + l15) * 72 + 32 + quad * 8];
  float rv_lo = 0.f, rv_hi = 0.f;
  if (inv) {
    int er = (l15 == 1) ? 382 : 0;
    short8 be0 = *(const short8*)(relL + (long)er * 64 + quad * 8);
    short8 be1 = *(const short8*)(relL + (long)er * 64 + 32 + quad * 8);
    floatx4 ec = {0.f, 0.f, 0.f, 0.f};
    ec = __builtin_amdgcn_mfma_f32_16x16x32_bf16(be0, aq0, ec, 0, 0, 0);
    ec = __builtin_amdgcn_mfma_f32_16x16x32_bf16(be1, aq1, ec, 0, 0, 0);
    rv_lo = __shfl(ec[0], l15, 64);
    rv_hi = __shfl(ec[1], l15, 64);
  }
  int sw7 = l15 & 7;
  for (int it = 0; it < nIt; ++it) {
    int kt = inv ? (grp + it * KSTEP) : it;
    int ko0 = koB + kt * 64;
    int t0 = q0 - ko0 + 191;
    bool far_hi = (q0 - ko0 - 63) >= 191;
    bool far_lo = (q0 + 63 - ko0) <= -191;
    bool near = !far_hi && !far_lo;
    int cb = min(max(t0 - 63, 0), 255);
    __syncthreads();   // A
    {
      *(uint4*)&Ks[kj * 64 + ((c0 ^ (kj & 7)) << 3)] = kr0;
      *(uint4*)&Ks[kj * 64 + (((c0 + 1) ^ (kj & 7)) << 3)] = kr1;
      uint_t wds[8] = {vr0.x, vr0.y, vr0.z, vr0.w, vr1.x, vr1.y, vr1.z, vr1.w};
#pragma unroll
      for (int u = 0; u < 8; ++u) {
        Vt[(du + 2 * u) * 72 + kj] = (ushort_t)(wds[u] & 0xffff);
        Vt[(du + 2 * u + 1) * 72 + kj] = (ushort_t)(wds[u] >> 16);
      }
    }
    if (near) {
      __builtin_amdgcn_s_setprio(1);
#pragma unroll
      for (int p = 0; p < 2; ++p) {
        short8 rw0[4], rw1[4];
#pragma unroll
        for (int j = 0; j < 4; ++j) {
          long wr = cb + (p * 4 + j) * 16 + l15;
          rw0[j] = *(const short8*)(relL + wr * 64 + quad * 8);
          rw1[j] = *(const short8*)(relL + wr * 64 + 32 + quad * 8);
        }
#pragma unroll
        for (int j = 0; j < 4; ++j) {
          floatx4 z = {0.f, 0.f, 0.f, 0.f};
          z = __builtin_amdgcn_mfma_f32_16x16x32_bf16(rw0[j], aq0, z, 0, 0, 0);
          z = __builtin_amdgcn_mfma_f32_16x16x32_bf16(rw1[j], aq1, z, 0, 0, 0);
#pragma unroll
          for (int rg = 0; rg < 4; ++rg) {
            int cpr = (p * 4 + j) * 16 + quad * 4 + rg;
            B2t[cpr * 68 + qw + l15] = f2us(z[rg]);
          }
        }
      }
      __builtin_amdgcn_s_setprio(0);
    }
    __syncthreads();   // B
    if (it + 1 < nIt) LOADKV(kt + KSTEP);
    floatx4 s[4];
    __builtin_amdgcn_s_setprio(1);
#pragma unroll
    for (int nt = 0; nt < 4; ++nt) {
      short8 ak0 = *(short8*)&Ks[(nt * 16 + l15) * 64 + ((quad ^ sw7) << 3)];
      short8 ak1 = *(short8*)&Ks[(nt * 16 + l15) * 64 + (((4 + quad) ^ sw7) << 3)];
      floatx4 z = {0.f, 0.f, 0.f, 0.f};
      z = __builtin_amdgcn_mfma_f32_16x16x32_bf16(ak0, aq0, z, 0, 0, 0);
      z = __builtin_amdgcn_mfma_f32_16x16x32_bf16(ak1, aq1, z, 0, 0, 0);
      s[nt] = z;
    }
    __builtin_amdgcn_s_setprio(0);
    if (near) {
#pragma unroll
      for (int nt = 0; nt < 4; ++nt)
#pragma unroll
        for (int rg = 0; rg < 4; ++rg) {
          int c = t0 + qw + l15 - (nt * 16 + quad * 4 + rg);
          c = min(max(c, 0), 382);
          s[nt][rg] += us2f(B2t[(c - cb) * 68 + qw + l15]);
        }
    } else {
      float rv = far_hi ? rv_hi : rv_lo;
#pragma unroll
      for (int nt = 0; nt < 4; ++nt)
#pragma unroll
        for (int rg = 0; rg < 4; ++rg) s[nt][rg] += rv;
    }
    if (!inv) {
#pragma unroll
      for (int nt = 0; nt < 4; ++nt)
#pragma unroll
        for (int rg = 0; rg < 4; ++rg) {
          int ko = ko0 + nt * 16 + quad * 4 + rg;
          if (ko >= len) s[nt][rg] = NEGB;
        }
    }
    float mx = s[0][0];
#pragma unroll
    for (int nt = 0; nt < 4; ++nt)
#pragma unroll
      for (int rg = 0; rg < 4; ++rg) mx = fmaxf(mx, s[nt][rg]);
    mx = fmaxf(mx, __shfl_xor(mx, 16, 64));
    mx = fmaxf(mx, __shfl_xor(mx, 32, 64));
    float mn = fmaxf(m_, mx);
    float al = __expf(m_ - mn);
    float ps = 0.f;
#pragma unroll
    for (int nt = 0; nt < 4; ++nt)
#pragma unroll
      for (int rg = 0; rg < 4; ++rg) {
        float p = __expf(s[nt][rg] - mn);
        s[nt][rg] = p;
        ps += p;
      }
    ps += __shfl_xor(ps, 16, 64);
    ps += __shfl_xor(ps, 32, 64);
    l_ = l_ * al + ps;
    m_ = mn;
    if (quad == 0) fML[qw + l15] = al;
#pragma unroll
    for (int nt = 0; nt < 4; ++nt)
#pragma unroll
      for (int pr = 0; pr < 2; ++pr) {
        uint_t pk = (uint_t)f2us(s[nt][2 * pr]) | ((uint_t)f2us(s[nt][2 * pr + 1]) << 16);
        int e = nt * 16 + quad * 4 + pr * 2;
        *(uint_t*)&Ps[(qw + l15) * 64 + (((e >> 3) ^ sw7) << 3) + (e & 7)] = pk;
      }
    floatx4 av = *(floatx4*)&fML[qw + quad * 4];
#pragma unroll
    for (int j = 0; j < 4; ++j)
#pragma unroll
      for (int rg = 0; rg < 4; ++rg) acc[j][rg] *= av[rg];
    short8 ap0 = *(short8*)&Ps[(qw + l15) * 64 + ((quad ^ sw7) << 3)];
    short8 ap1 = *(short8*)&Ps[(qw + l15) * 64 + (((4 + quad) ^ sw7) << 3)];
    __builtin_amdgcn_s_setprio(1);
#pragma unroll
    for (int j = 0; j < 4; ++j) {
      short8 bv0 = *(short8*)&Vt[(j * 16 + l15) * 72 + quad * 8];
      short8 bv1 = *(short8*)&Vt[(j * 16 + l15) * 72 + 32 + quad * 8];
      acc[j] = __builtin_amdgcn_mfma_f32_16x16x32_bf16(ap0, bv0, acc[j], 0, 0, 0);
      acc[j] = __builtin_amdgcn_mfma_f32_16x16x32_bf16(ap1, bv1, acc[j], 0, 0, 0);
    }
    __builtin_amdgcn_s_setprio(0);
  }
  if (inv) {
    char* pp = part + (long)((((b * 8 + h) * 16 + qt) * 4 + grp)) * PSTRIDE;
    ushort_t* Cp = (ushort_t*)pp;
    float* mp = (float*)(pp + 8192);
#pragma unroll
    for (int j = 0; j < 4; ++j)
#pragma unroll
      for (int rg = 0; rg < 4; ++rg)
        Cp[(qw + quad * 4 + rg) * 64 + j * 16 + l15] = f2us(acc[j][rg]);
    if (quad == 0) { mp[qw + l15] = m_; mp[64 + qw + l15] = l_; }
  } else {
    if (quad == 0) fML[64 + qw + l15] = l_;
    floatx4 lv = *(floatx4*)&fML[64 + qw + quad * 4];
#pragma unroll
    for (int rg = 0; rg < 4; ++rg) {
      int R = qw + quad * 4 + rg;
      if (R < nvalid) {
        float invL = 1.0f / lv[rg];
#pragma unroll
        for (int j = 0; j < 4; ++j)
          out[((long)(b * Tc + q0 + R)) * Dc + h * 64 + j * 16 + l15] = f2us(acc[j][rg] * invL);
      }
    }
  }
}

// ---------------- exact split-K combine for inv partials ----------------
__global__ __launch_bounds__(256) void k_comb(const char* __restrict__ part,
    const int* __restrict__ alen, ushort_t* __restrict__ out) {
  int qt = blockIdx.x, h = blockIdx.y, b = blockIdx.z;
  int len = alen[b];
  int q0 = qt * 64;
  if (q0 + 64 <= len) return;
  int nskip = max(len - q0, 0);
  int t = threadIdx.x;
  int d = t & 63, r0 = (t >> 6) * 16;
  const char* pb = part + (long)(((b * 8 + h) * 16 + qt) * 4) * PSTRIDE;
#pragma unroll 4
  for (int i = 0; i < 16; ++i) {
    int r = r0 + i;
    if (r < nskip) continue;
    float mg[4], lg[4], M = NEGB;
#pragma unroll
    for (int g2 = 0; g2 < 4; ++g2) {
      const float* mp = (const float*)(pb + g2 * PSTRIDE + 8192);
      mg[g2] = mp[r];
      lg[g2] = mp[64 + r];
      M = fmaxf(M, mg[g2]);
    }
    float L = 0.f, wgt[4];
#pragma unroll
    for (int g2 = 0; g2 < 4; ++g2) { wgt[g2] = __expf(mg[g2] - M); L += lg[g2] * wgt[g2]; }
    float v = 0.f;
#pragma unroll
    for (int g2 = 0; g2 < 4; ++g2)
      v += us2f(((const ushort_t*)(pb + g2 * PSTRIDE))[r * 64 + d]) * wgt[g2];
    out[((long)(b * Tc + q0 + r)) * Dc + h * 64 + d] = f2us(v / L);
  }
}

// ---------------- elementwise (bf16, short8-vectorized) ----------------
__global__ void k_glu(ushort_t* __restrict__ h, int n8) {
  int i = blockIdx.x * 256 + threadIdx.x;
  if (i >= n8) return;
  long r = i >> 6;
  int j8 = (i & 63) << 3;
  short8 a8 = *(short8*)&h[r * 1024 + j8];
  short8 g8 = *(short8*)&h[r * 1024 + 512 + j8];
  short8 o8;
#pragma unroll
  for (int e = 0; e < 8; ++e) {
    float a = us2f((ushort_t)a8[e]), g = us2f((ushort_t)g8[e]);
    o8[e] = (short)f2us(a * (1.0f / (1.0f + __expf(-g))));
  }
  *(short8*)&h[r * 1024 + j8] = o8;
}
__global__ void k_swiglu(ushort_t* __restrict__ h, int n8) {
  int i = blockIdx.x * 256 + threadIdx.x;
  if (i >= n8) return;
  long r = i >> 7;
  int j8 = (i & 127) << 3;
  short8 a8 = *(short8*)&h[r * 2048 + j8];
  short8 b8 = *(short8*)&h[r * 2048 + 1024 + j8];
  short8 o8;
#pragma unroll
  for (int e = 0; e < 8; ++e) {
    float a = us2f((ushort_t)a8[e]), bb = us2f((ushort_t)b8[e]);
    o8[e] = (short)f2us((a / (1.0f + __expf(-a))) * bb);
  }
  *(short8*)&h[r * 2048 + j8] = o8;
}
__global__ void k_dwconv(const ushort_t* __restrict__ in, const ushort_t* __restrict__ dwT,
                         ushort_t* __restrict__ out, int n8) {
  int i = blockIdx.x * 256 + threadIdx.x;
  if (i >= n8) return;
  int row = i >> 6;            // 0..4095
  int d8 = (i & 63) << 3;
  int t = row & (Tc - 1);
  int b = row >> 10;
  float acc[8] = {0, 0, 0, 0, 0, 0, 0, 0};
#pragma unroll
  for (int j = 0; j < 9; ++j) {
    int tt = t + j - 4;
    if (tt < 0 || tt >= Tc) continue;
    short8 vv = *(const short8*)&in[((long)(b * Tc + tt) << 10) + d8];
    short8 dv = *(const short8*)&dwT[j * 512 + d8];
#pragma unroll
    for (int e = 0; e < 8; ++e)
      acc[e] += us2f((ushort_t)vv[e]) * us2f((ushort_t)dv[e]);
  }
  short8 o8;
#pragma unroll
  for (int e = 0; e < 8; ++e)
    o8[e] = (short)f2us(acc[e] * (1.0f / (1.0f + __expf(-acc[e]))));
  *(short8*)&out[(long)row * 512 + d8] = o8;
}

extern "C" void kernel_launch(void* const* d_in, const int* in_sizes, int n_in,
                              void* d_out, int out_size, void* d_ws, size_t ws_size,
                              hipStream_t stream) {
  const void* x_in = d_in[0];
  const int*  alen = (const int*)d_in[1];
  const void* ln1w = d_in[2];
  const void* ln1b = d_in[3];
  const void* wq   = d_in[4];
  const void* wk   = d_in[5];
  const void* wv   = d_in[6];
  const void* wo   = d_in[7];
  const void* rel  = d_in[8];
  const void* ln2w = d_in[9];
  const void* ln2b = d_in[10];
  const void* pw1  = d_in[11];
  const void* dwv  = d_in[12];
  const void* pw2  = d_in[13];
  const void* ln3w = d_in[14];
  const void* ln3b = d_in[15];
  const void* w1   = d_in[16];
  const void* w2   = d_in[17];

  // ---- workspace layout (bytes) ----
  char* base = (char*)d_ws;
  int*      flag = (int*)base;                       // 256
  float*    xf   = (float*)(base + 256);             // 8 MB f32 residual
  float*    lnb  = (float*)(base + 256 + 8388608);   // 8 MB f32 LN out (addend)
  ushort_t* lnA  = (ushort_t*)(base + 16777472);     // 4 MB bf16 LN out (GEMM A)
  ushort_t* wbf  = (ushort_t*)(base + 20971776);     // bf16 weights
  char*     U    = base + 45321984;                  // phase union
  // attn phase
  ushort_t* qb = (ushort_t*)U;                       // 4 MB
  ushort_t* kb = (ushort_t*)(U + 4194304);           // 1 MB
  ushort_t* vb = (ushort_t*)(U + 5242880);           // 1 MB
  ushort_t* ab = (ushort_t*)(U + 6291456);           // 4 MB
  char*     partA = U + 10485760;                    // 17.8 MB attn partials
  // conv/ffn phase
  ushort_t* big = (ushort_t*)U;                      // up to 16 MB
  ushort_t* cb  = (ushort_t*)(U + 16777216);         // 4 MB
  size_t REQ = 45321984 + 16777216 + 4194304;
  size_t REQ2 = 45321984 + 35651584;
  if (REQ2 > REQ) REQ = REQ2;
  if (ws_size < REQ) return;

  // bf16 weight table offsets (elements)
  ushort_t* wqB  = wbf + 0;
  ushort_t* wkB  = wbf + 1048576;
  ushort_t* wvB  = wbf + 1310720;
  ushort_t* woB  = wbf + 1572864;
  ushort_t* relB = wbf + 2621440;
  ushort_t* pw1B = wbf + 2719488;
  ushort_t* dwB  = wbf + 4816640;
  ushort_t* pw2B = wbf + 4835072;
  ushort_t* w1B  = wbf + 5883648;
  ushort_t* w2B  = wbf + 10077952;

  k_detect<<<1, 256, 0, stream>>>(x_in, flag);
  k_in<<<(int)((NE + 255) / 256), 256, 0, stream>>>(x_in, xf, (int)NE, flag);
  k_w2b<<<4096, 256, 0, stream>>>(wq,  wqB,  1048576, flag);
  k_w2b<<<1024, 256, 0, stream>>>(wk,  wkB,  262144, flag);
  k_w2b<<<1024, 256, 0, stream>>>(wv,  wvB,  262144, flag);
  k_w2b<<<4096, 256, 0, stream>>>(wo,  woB,  1048576, flag);
  k_w2b<<<383,  256, 0, stream>>>(rel, relB, 98048, flag);
  k_w2b<<<8192, 256, 0, stream>>>(pw1, pw1B, 2097152, flag);
  k_w2bT<<<72,  256, 0, stream>>>(dwv, dwB, flag);
  k_w2b<<<4096, 256, 0, stream>>>(pw2, pw2B, 1048576, flag);
  k_w2b<<<16384,256, 0, stream>>>(w1,  w1B,  4194304, flag);
  k_w2b<<<8192, 256, 0, stream>>>(w2,  w2B,  2097152, flag);

  for (int i = 0; i < 4; ++i) {
    long oLN = (long)i * Dc;
    // ---- attention ----
    k_ln<<<NBT, 256, 0, stream>>>(xf, ln1w, ln1b, oLN, lnb, lnA, flag);
    k_gemm_b<64, 128, true><<<dim3(4, 64), 256, 0, stream>>>(lnA, Dc, wqB + (long)i * 262144, qb, Dc, nullptr, 0.125f, 512);
    k_gemm_b<64, 64, true><<<dim3(2, 64), 256, 0, stream>>>(lnA, Dc, wkB + (long)i * 65536, kb, 128, nullptr, 1.0f, 512);
    k_gemm_b<64, 64, true><<<dim3(2, 64), 256, 0, stream>>>(lnA, Dc, wvB + (long)i * 65536, vb, 128, nullptr, 1.0f, 512);
    k_attn<<<dim3(80, 8, 4), 256, 0, stream>>>(qb, kb, vb, relB + (long)i * 24512, alen, ab, partA);
    k_comb<<<dim3(16, 8, 4), 256, 0, stream>>>(partA, alen, ab);
    k_gemm_b<64, 128, false><<<dim3(4, 64), 256, 0, stream>>>(ab, Dc, woB + (long)i * 262144, xf, Dc, lnb, 1.0f, 512);

    // ---- conv ----
    k_ln<<<NBT, 256, 0, stream>>>(xf, ln2w, ln2b, oLN, lnb, lnA, flag);
    k_gemm_b<128, 128, true><<<dim3(8, 32), 256, 0, stream>>>(lnA, Dc, pw1B + (long)i * 524288, big, 1024, nullptr, 1.0f, 512);
    k_glu<<<NBT * 512 / 8 / 256, 256, 0, stream>>>(big, NBT * 512 / 8);
    k_dwconv<<<NBT * 512 / 8 / 256, 256, 0, stream>>>(big, dwB + (long)i * 4608, cb, NBT * 512 / 8);
    k_gemm_b<64, 128, false><<<dim3(4, 64), 256, 0, stream>>>(cb, Dc, pw2B + (long)i * 262144, xf, Dc, lnb, 1.0f, 512);

    // ---- ffn ----
    k_ln<<<NBT, 256, 0, stream>>>(xf, ln3w, ln3b, oLN, lnb, lnA, flag);
    k_gemm_b<128, 128, true><<<dim3(16, 32), 256, 0, stream>>>(lnA, Dc, w1B + (long)i * 1048576, big, 2048, nullptr, 1.0f, 512);
    k_swiglu<<<NBT * 1024 / 8 / 256, 256, 0, stream>>>(big, NBT * 1024 / 8);
    k_gemm_b<64, 128, false><<<dim3(4, 64), 256, 0, stream>>>(big, 2048, w2B + (long)i * 524288, xf, Dc, lnb, 1.0f, 1024);
  }

  k_out<<<(int)((NE + 255) / 256), 256, 0, stream>>>(xf, d_out, (int)NE, flag);
}

// Round 7
// 945.604 us; speedup vs baseline: 1.7239x; 1.0876x over previous
//
#include <hip/hip_runtime.h>
#include <hip/hip_bf16.h>

typedef __hip_bfloat16 bf16;
typedef unsigned short ushort_t;
typedef unsigned int uint_t;
typedef __attribute__((ext_vector_type(8))) short short8;
typedef __attribute__((ext_vector_type(4))) float floatx4;

__device__ __forceinline__ float b2f(bf16 x) { return __bfloat162float(x); }
__device__ __forceinline__ ushort_t f2us(float f) { bf16 h = __float2bfloat16(f); return *(ushort_t*)&h; }
__device__ __forceinline__ float us2f(ushort_t u) { return __uint_as_float(((uint_t)u) << 16); }

constexpr int Bc = 4, Tc = 1024, Dc = 512, Hc = 8, HDc = 64;
constexpr int LCc = 128, MPc = 192;
constexpr float EPSc = 1e-4f;
constexpr int NBT = Bc * Tc;
constexpr long NE = (long)NBT * Dc;
constexpr float NEGB = -1e30f;
constexpr int PSTRIDE = 8704;   // bytes per attention partial: 4096 bf16 C + 64 f32 m + 64 f32 l

__device__ __forceinline__ float wload(const void* p, long i, int f32) {
  return f32 ? ((const float*)p)[i] : b2f(((const bf16*)p)[i]);
}

// async global->LDS staging of a ROWSx64 bf16 tile with XOR swizzle.
// LDS dest is LINEAR (global_load_lds writes base+lane*16); the swizzle is applied by
// PRE-SWIZZLING the global source chunk index (T21: source perm == read perm).
__device__ __forceinline__ void stage_swz(const ushort_t* __restrict__ G, int rowStride,
                                          int rowBase, int k0, ushort_t* L, int nChunk, int t) {
#pragma unroll
  for (int i = t; i < nChunk; i += 256) {
    int r = i >> 3;
    int cs = (i & 7) ^ (r & 7);
    const ushort_t* gp = G + (long)(rowBase + r) * rowStride + k0 + cs * 8;
    __builtin_amdgcn_global_load_lds(
        (const __attribute__((address_space(1))) void*)gp,
        (__attribute__((address_space(3))) void*)&L[(i & ~63) * 8], 16, 0, 0);
  }
}

// ---------------- dtype detector ----------------
__global__ void k_detect(const void* __restrict__ x, int* __restrict__ flag) {
  __shared__ int s[256];
  int t = threadIdx.x;
  const unsigned short* u = (const unsigned short*)x;
  int bad = 0;
  for (int j = t; j < 2048; j += 256) {
    int e = (u[j] >> 7) & 0xFF;
    if (e == 0xFF || e > 0x8F || (e != 0 && e < 0x6F)) bad++;
  }
  s[t] = bad;
  __syncthreads();
  for (int off = 128; off > 0; off >>= 1) { if (t < off) s[t] += s[t + off]; __syncthreads(); }
  if (t == 0) flag[0] = (s[0] > 16) ? 1 : 0;
}

__global__ void k_in(const void* __restrict__ in, float* __restrict__ out, int n,
                     const int* __restrict__ flag) {
  int i = blockIdx.x * 256 + threadIdx.x;
  if (i < n) out[i] = wload(in, i, flag[0]);
}
__global__ void k_out(const float* __restrict__ in, void* __restrict__ out, int n,
                      const int* __restrict__ flag) {
  int i = blockIdx.x * 256 + threadIdx.x;
  if (i >= n) return;
  if (flag[0]) ((float*)out)[i] = in[i];
  else         ((bf16*)out)[i] = __float2bfloat16(in[i]);
}

// ---------------- one-shot weight conversion (all tensors, one dispatch) ----------------
// segments in combined element space (dst = wbf + idx):
//  [0,1048576)            wq      direct
//  [1048576,1572864)      wk|wv   interleaved [L][256][512] (r<128: wk row r, else wv row r-128)
//  [1572864,2621440)      wo      direct
//  [2621440,2719488)      rel     direct
//  [2719488,4816640)      pw1     direct
//  [4816640,4835072)      dw      transposed [L][9][512]
//  [4835072,5883648)      pw2     direct
//  [5883648,10077952)     w1      direct
//  [10077952,12175104)    w2      direct
__global__ void k_w2all(const void* wq, const void* wk, const void* wv, const void* wo,
                        const void* rel, const void* pw1, const void* dwv, const void* pw2,
                        const void* w1, const void* w2,
                        ushort_t* __restrict__ wbf, const int* __restrict__ flag) {
  int f32 = flag[0];
  long i = (long)blockIdx.x * 256 + threadIdx.x;
  if (i >= 12175104L) return;
  float v;
  if (i < 1048576) {
    v = wload(wq, i, f32);
  } else if (i < 1572864) {
    long r2 = i - 1048576;
    long l = r2 / 131072, rem = r2 - l * 131072;
    int r = (int)(rem >> 9), c = (int)(rem & 511);
    if (r < 128) v = wload(wk, l * 65536 + (long)r * 512 + c, f32);
    else         v = wload(wv, l * 65536 + (long)(r - 128) * 512 + c, f32);
  } else if (i < 2621440) {
    v = wload(wo, i - 1572864, f32);
  } else if (i < 2719488) {
    v = wload(rel, i - 2621440, f32);
  } else if (i < 4816640) {
    v = wload(pw1, i - 2719488, f32);
  } else if (i < 4835072) {
    long r2 = i - 4816640;
    long l = r2 / 4608, rem = r2 - l * 4608;
    int j = (int)(rem >> 9), d = (int)(rem & 511);
    v = wload(dwv, l * 4608 + (long)d * 9 + j, f32);
  } else if (i < 5883648) {
    v = wload(pw2, i - 4835072, f32);
  } else if (i < 10077952) {
    v = wload(w1, i - 5883648, f32);
  } else {
    v = wload(w2, i - 10077952, f32);
  }
  wbf[i] = f2us(v);
}

// ---------------- LayerNorm: wave-shuffle reduce, float2 loads, 2 barriers ----------------
__global__ __launch_bounds__(256) void k_ln(const float* __restrict__ x,
    const void* __restrict__ w, const void* __restrict__ bb, long woff,
    float* __restrict__ o, ushort_t* __restrict__ oA, const int* __restrict__ flag) {
  int f32 = flag[0];
  int row = blockIdx.x;
  int t = threadIdx.x;
  int lane = t & 63, wv = t >> 6;
  float2 v = ((const float2*)(x + (long)row * Dc))[t];
  float s = v.x + v.y;
#pragma unroll
  for (int o2 = 1; o2 < 64; o2 <<= 1) s += __shfl_xor(s, o2, 64);
  __shared__ float ws[8];
  if (lane == 0) ws[wv] = s;
  __syncthreads();
  float mean = (ws[0] + ws[1] + ws[2] + ws[3]) * (1.0f / Dc);
  float dx = v.x - mean, dy = v.y - mean;
  float s2 = dx * dx + dy * dy;
#pragma unroll
  for (int o2 = 1; o2 < 64; o2 <<= 1) s2 += __shfl_xor(s2, o2, 64);
  if (lane == 0) ws[4 + wv] = s2;
  __syncthreads();
  float inv = 1.0f / sqrtf((ws[4] + ws[5] + ws[6] + ws[7]) * (1.0f / Dc) + EPSc);
  float v0 = dx * inv * wload(w, woff + 2 * t, f32)     + wload(bb, woff + 2 * t, f32);
  float v1 = dy * inv * wload(w, woff + 2 * t + 1, f32) + wload(bb, woff + 2 * t + 1, f32);
  float2 ov; ov.x = v0; ov.y = v1;
  ((float2*)(o + (long)row * Dc))[t] = ov;
  ((uint_t*)(oA + (long)row * Dc))[t] = (uint_t)f2us(v0) | ((uint_t)f2us(v1) << 16);
}

// ---------------- bf16 MFMA GEMM: C = alpha*A@W^T (+f32 addend), async LDS staging ----------------
template<int BM, int BN, bool OBF>
__global__ __launch_bounds__(256) void k_gemm_b(const ushort_t* __restrict__ A, int lda,
    const ushort_t* __restrict__ W, void* __restrict__ C, int ldc,
    const float* __restrict__ addend, float alpha, int K) {
  constexpr int WGM = BM / 64;
  constexpr int WGN = 4 / WGM;
  constexpr int WN = BN / WGN;
  constexpr int NJ = WN / 16;
  __shared__ ushort_t As[BM * 64];
  __shared__ ushort_t Ws[BN * 64];
  int t = threadIdx.x;
  int m0 = blockIdx.y * BM, n0 = blockIdx.x * BN;
  int lane = t & 63, wv = t >> 6;
  int l15 = lane & 15, quad = lane >> 4;
  int wrow = (WGM == 2) ? (wv >> 1) * 64 : 0;
  int wcol = (WGM == 2) ? (wv & 1) * WN : wv * WN;
  floatx4 acc[4][NJ];
#pragma unroll
  for (int i = 0; i < 4; ++i)
#pragma unroll
    for (int j = 0; j < NJ; ++j) acc[i][j] = 0;
  for (int k0 = 0; k0 < K; k0 += 64) {
    stage_swz(A, lda, m0, k0, As, BM * 8, t);
    stage_swz(W, K,  n0, k0, Ws, BN * 8, t);
    __syncthreads();
#pragma unroll
    for (int half = 0; half < 2; ++half) {
      int sw = ((half * 4 + quad) ^ (l15 & 7)) << 3;
      short8 af[4], bfr[NJ];
#pragma unroll
      for (int i = 0; i < 4; ++i) af[i] = *(short8*)&As[(wrow + i * 16 + l15) * 64 + sw];
#pragma unroll
      for (int j = 0; j < NJ; ++j) bfr[j] = *(short8*)&Ws[(wcol + j * 16 + l15) * 64 + sw];
#pragma unroll
      for (int i = 0; i < 4; ++i)
#pragma unroll
        for (int j = 0; j < NJ; ++j)
          acc[i][j] = __builtin_amdgcn_mfma_f32_16x16x32_bf16(af[i], bfr[j], acc[i][j], 0, 0, 0);
    }
    __syncthreads();
  }
#pragma unroll
  for (int i = 0; i < 4; ++i) {
#pragma unroll
    for (int j = 0; j < NJ; ++j) {
#pragma unroll
      for (int rg = 0; rg < 4; ++rg) {
        int m = m0 + wrow + i * 16 + quad * 4 + rg;
        int n = n0 + wcol + j * 16 + l15;
        float v = alpha * acc[i][j][rg];
        if (addend) v += addend[(long)m * ldc + n];
        if (OBF) ((ushort_t*)C)[(long)m * ldc + n] = f2us(v);
        else     ((float*)C)[(long)m * ldc + n] = v;
      }
    }
  }
}

// ---------------- gated GEMM: C = gate(A@Wa^T, A@Wg^T), bf16 out ----------------
// MODE 0 (glu):    C = a * sigmoid(g)
// MODE 1 (swiglu): C = silu(a) * g
// BM=64, BN=128: 4 waves, each owns 32 cols (NJ=2), two accumulator sets.
template<int MODE>
__global__ __launch_bounds__(256) void k_gemm_gate(const ushort_t* __restrict__ A, int lda,
    const ushort_t* __restrict__ Wa, const ushort_t* __restrict__ Wg,
    ushort_t* __restrict__ C, int ldc, int K) {
  __shared__ ushort_t As[64 * 64];
  __shared__ ushort_t Wsa[128 * 64];
  __shared__ ushort_t Wsg[128 * 64];
  int t = threadIdx.x;
  int m0 = blockIdx.y * 64, n0 = blockIdx.x * 128;
  int lane = t & 63, wv = t >> 6;
  int l15 = lane & 15, quad = lane >> 4;
  int wcol = wv * 32;
  floatx4 acca[4][2], accg[4][2];
#pragma unroll
  for (int i = 0; i < 4; ++i)
#pragma unroll
    for (int j = 0; j < 2; ++j) { acca[i][j] = 0; accg[i][j] = 0; }
  for (int k0 = 0; k0 < K; k0 += 64) {
    stage_swz(A, lda, m0, k0, As, 512, t);
    stage_swz(Wa, K, n0, k0, Wsa, 1024, t);
    stage_swz(Wg, K, n0, k0, Wsg, 1024, t);
    __syncthreads();
#pragma unroll
    for (int half = 0; half < 2; ++half) {
      int sw = ((half * 4 + quad) ^ (l15 & 7)) << 3;
      short8 af[4], ba[2], bg[2];
#pragma unroll
      for (int i = 0; i < 4; ++i) af[i] = *(short8*)&As[(i * 16 + l15) * 64 + sw];
#pragma unroll
      for (int j = 0; j < 2; ++j) {
        ba[j] = *(short8*)&Wsa[(wcol + j * 16 + l15) * 64 + sw];
        bg[j] = *(short8*)&Wsg[(wcol + j * 16 + l15) * 64 + sw];
      }
#pragma unroll
      for (int i = 0; i < 4; ++i)
#pragma unroll
        for (int j = 0; j < 2; ++j) {
          acca[i][j] = __builtin_amdgcn_mfma_f32_16x16x32_bf16(af[i], ba[j], acca[i][j], 0, 0, 0);
          accg[i][j] = __builtin_amdgcn_mfma_f32_16x16x32_bf16(af[i], bg[j], accg[i][j], 0, 0, 0);
        }
    }
    __syncthreads();
  }
#pragma unroll
  for (int i = 0; i < 4; ++i) {
#pragma unroll
    for (int j = 0; j < 2; ++j) {
#pragma unroll
      for (int rg = 0; rg < 4; ++rg) {
        int m = m0 + i * 16 + quad * 4 + rg;
        int n = n0 + wcol + j * 16 + l15;
        float a = acca[i][j][rg], g = accg[i][j][rg];
        float v;
        if (MODE == 0) v = a * (1.0f / (1.0f + __expf(-g)));
        else           v = (a / (1.0f + __expf(-a))) * g;
        C[(long)m * ldc + n] = f2us(v);
      }
    }
  }
}

// ---------------- flash attention, swapped-QK layout + grid split-K (r5/r6 structure) ----------
// kvb layout: [4096][256] bf16, K at cols 0..127 (g*64 slice), V at cols 128..255.
__global__ __launch_bounds__(256, 3) void k_attn(const ushort_t* __restrict__ q,
    const ushort_t* __restrict__ kvb,
    const ushort_t* __restrict__ relL, const int* __restrict__ alen,
    ushort_t* __restrict__ out, char* __restrict__ part) {
  int bx = blockIdx.x;
  int h = blockIdx.y, b = blockIdx.z;
  int len = alen[b];
  int inv, qt, grp;
  if (bx < 16) { inv = 0; qt = bx; grp = 0; }
  else         { inv = 1; qt = (bx - 16) & 15; grp = (bx - 16) >> 4; }
  int q0 = qt * 64;
  if (inv) { if (q0 + 64 <= len) return; }
  else     { if (q0 >= len) return; }
  int nvalid = min(len - q0, 64);
  int g = h >> 2;
  __shared__ __align__(16) ushort_t UQB[8704];
  __shared__ __align__(16) ushort_t Ks[64 * 64];
  __shared__ __align__(16) ushort_t Vt[64 * 72];
  __shared__ __align__(16) ushort_t Ps[64 * 64];
  __shared__ __align__(16) float fML[128];
  ushort_t* Qs = UQB;
  ushort_t* B2t = UQB;
  int t = threadIdx.x;
  int lane = t & 63, w = t >> 6;
  int l15 = lane & 15, quad = lane >> 4;
  int qw = w * 16;
  {
    int qi = t >> 2, du = (t & 3) * 16;
    const ushort_t* src = q + ((long)(b * Tc + q0 + qi)) * Dc + h * 64 + du;
    *(uint4*)&Qs[qi * 72 + du] = *(const uint4*)(src);
    *(uint4*)&Qs[qi * 72 + du + 8] = *(const uint4*)(src + 8);
  }
  const int koB = inv ? -128 : (q0 - 128);
  const int KSTEP = inv ? 4 : 1;
  const int nIt = inv ? ((grp < 2) ? 5 : 4) : 3;
  uint4 kr0, kr1, vr0, vr1;
  int kj = t >> 2, du = (t & 3) * 16, c0 = du >> 3;
  auto LOADKV = [&](int kt2) {
    int ko = koB + kt2 * 64 + kj;
    if (ko >= 0) {
      long basek = ((long)(b * Tc + ko)) * 256 + g * 64 + du;
      kr0 = *(const uint4*)(kvb + basek);
      kr1 = *(const uint4*)(kvb + basek + 8);
      vr0 = *(const uint4*)(kvb + basek + 128);
      vr1 = *(const uint4*)(kvb + basek + 136);
    } else {
      uint4 z = {0, 0, 0, 0};
      kr0 = z; kr1 = z; vr0 = z; vr1 = z;
    }
  };
  LOADKV(grp);
  float m_ = NEGB, l_ = 0.f;
  floatx4 acc[4];
#pragma unroll
  for (int j = 0; j < 4; ++j) acc[j] = 0;
  __syncthreads();
  short8 aq0 = *(short8*)&Qs[(qw + l15) * 72 + quad * 8];
  short8 aq1 = *(short8*)&Qs[(qw + l15) * 72 + 32 + quad * 8];
  float rv_lo = 0.f, rv_hi = 0.f;
  if (inv) {
    int er = (l15 == 1) ? 382 : 0;
    short8 be0 = *(const short8*)(relL + (long)er * 64 + quad * 8);
    short8 be1 = *(const short8*)(relL + (long)er * 64 + 32 + quad * 8);
    floatx4 ec = {0.f, 0.f, 0.f, 0.f};
    ec = __builtin_amdgcn_mfma_f32_16x16x32_bf16(be0, aq0, ec, 0, 0, 0);
    ec = __builtin_amdgcn_mfma_f32_16x16x32_bf16(be1, aq1, ec, 0, 0, 0);
    rv_lo = __shfl(ec[0], l15, 64);
    rv_hi = __shfl(ec[1], l15, 64);
  }
  int sw7 = l15 & 7;
  for (int it = 0; it < nIt; ++it) {
    int kt = inv ? (grp + it * KSTEP) : it;
    int ko0 = koB + kt * 64;
    int t0 = q0 - ko0 + 191;
    bool far_hi = (q0 - ko0 - 63) >= 191;
    bool far_lo = (q0 + 63 - ko0) <= -191;
    bool near = !far_hi && !far_lo;
    int cb = min(max(t0 - 63, 0), 255);
    __syncthreads();   // A
    {
      *(uint4*)&Ks[kj * 64 + ((c0 ^ (kj & 7)) << 3)] = kr0;
      *(uint4*)&Ks[kj * 64 + (((c0 + 1) ^ (kj & 7)) << 3)] = kr1;
      uint_t wds[8] = {vr0.x, vr0.y, vr0.z, vr0.w, vr1.x, vr1.y, vr1.z, vr1.w};
#pragma unroll
      for (int u = 0; u < 8; ++u) {
        Vt[(du + 2 * u) * 72 + kj] = (ushort_t)(wds[u] & 0xffff);
        Vt[(du + 2 * u + 1) * 72 + kj] = (ushort_t)(wds[u] >> 16);
      }
    }
    if (near) {
      __builtin_amdgcn_s_setprio(1);
#pragma unroll
      for (int p = 0; p < 2; ++p) {
        short8 rw0[4], rw1[4];
#pragma unroll
        for (int j = 0; j < 4; ++j) {
          long wr = cb + (p * 4 + j) * 16 + l15;
          rw0[j] = *(const short8*)(relL + wr * 64 + quad * 8);
          rw1[j] = *(const short8*)(relL + wr * 64 + 32 + quad * 8);
        }
#pragma unroll
        for (int j = 0; j < 4; ++j) {
          floatx4 z = {0.f, 0.f, 0.f, 0.f};
          z = __builtin_amdgcn_mfma_f32_16x16x32_bf16(rw0[j], aq0, z, 0, 0, 0);
          z = __builtin_amdgcn_mfma_f32_16x16x32_bf16(rw1[j], aq1, z, 0, 0, 0);
#pragma unroll
          for (int rg = 0; rg < 4; ++rg) {
            int cpr = (p * 4 + j) * 16 + quad * 4 + rg;
            B2t[cpr * 68 + qw + l15] = f2us(z[rg]);
          }
        }
      }
      __builtin_amdgcn_s_setprio(0);
    }
    __syncthreads();   // B
    if (it + 1 < nIt) LOADKV(kt + KSTEP);
    floatx4 s[4];
    __builtin_amdgcn_s_setprio(1);
#pragma unroll
    for (int nt = 0; nt < 4; ++nt) {
      short8 ak0 = *(short8*)&Ks[(nt * 16 + l15) * 64 + ((quad ^ sw7) << 3)];
      short8 ak1 = *(short8*)&Ks[(nt * 16 + l15) * 64 + (((4 + quad) ^ sw7) << 3)];
      floatx4 z = {0.f, 0.f, 0.f, 0.f};
      z = __builtin_amdgcn_mfma_f32_16x16x32_bf16(ak0, aq0, z, 0, 0, 0);
      z = __builtin_amdgcn_mfma_f32_16x16x32_bf16(ak1, aq1, z, 0, 0, 0);
      s[nt] = z;
    }
    __builtin_amdgcn_s_setprio(0);
    if (near) {
#pragma unroll
      for (int nt = 0; nt < 4; ++nt)
#pragma unroll
        for (int rg = 0; rg < 4; ++rg) {
          int c = t0 + qw + l15 - (nt * 16 + quad * 4 + rg);
          c = min(max(c, 0), 382);
          s[nt][rg] += us2f(B2t[(c - cb) * 68 + qw + l15]);
        }
    } else {
      float rv = far_hi ? rv_hi : rv_lo;
#pragma unroll
      for (int nt = 0; nt < 4; ++nt)
#pragma unroll
        for (int rg = 0; rg < 4; ++rg) s[nt][rg] += rv;
    }
    if (!inv) {
#pragma unroll
      for (int nt = 0; nt < 4; ++nt)
#pragma unroll
        for (int rg = 0; rg < 4; ++rg) {
          int ko = ko0 + nt * 16 + quad * 4 + rg;
          if (ko >= len) s[nt][rg] = NEGB;
        }
    }
    float mx = s[0][0];
#pragma unroll
    for (int nt = 0; nt < 4; ++nt)
#pragma unroll
      for (int rg = 0; rg < 4; ++rg) mx = fmaxf(mx, s[nt][rg]);
    mx = fmaxf(mx, __shfl_xor(mx, 16, 64));
    mx = fmaxf(mx, __shfl_xor(mx, 32, 64));
    float mn = fmaxf(m_, mx);
    float al = __expf(m_ - mn);
    float ps = 0.f;
#pragma unroll
    for (int nt = 0; nt < 4; ++nt)
#pragma unroll
      for (int rg = 0; rg < 4; ++rg) {
        float p = __expf(s[nt][rg] - mn);
        s[nt][rg] = p;
        ps += p;
      }
    ps += __shfl_xor(ps, 16, 64);
    ps += __shfl_xor(ps, 32, 64);
    l_ = l_ * al + ps;
    m_ = mn;
    if (quad == 0) fML[qw + l15] = al;
#pragma unroll
    for (int nt = 0; nt < 4; ++nt)
#pragma unroll
      for (int pr = 0; pr < 2; ++pr) {
        uint_t pk = (uint_t)f2us(s[nt][2 * pr]) | ((uint_t)f2us(s[nt][2 * pr + 1]) << 16);
        int e = nt * 16 + quad * 4 + pr * 2;
        *(uint_t*)&Ps[(qw + l15) * 64 + (((e >> 3) ^ sw7) << 3) + (e & 7)] = pk;
      }
    floatx4 av = *(floatx4*)&fML[qw + quad * 4];
#pragma unroll
    for (int j = 0; j < 4; ++j)
#pragma unroll
      for (int rg = 0; rg < 4; ++rg) acc[j][rg] *= av[rg];
    short8 ap0 = *(short8*)&Ps[(qw + l15) * 64 + ((quad ^ sw7) << 3)];
    short8 ap1 = *(short8*)&Ps[(qw + l15) * 64 + (((4 + quad) ^ sw7) << 3)];
    __builtin_amdgcn_s_setprio(1);
#pragma unroll
    for (int j = 0; j < 4; ++j) {
      short8 bv0 = *(short8*)&Vt[(j * 16 + l15) * 72 + quad * 8];
      short8 bv1 = *(short8*)&Vt[(j * 16 + l15) * 72 + 32 + quad * 8];
      acc[j] = __builtin_amdgcn_mfma_f32_16x16x32_bf16(ap0, bv0, acc[j], 0, 0, 0);
      acc[j] = __builtin_amdgcn_mfma_f32_16x16x32_bf16(ap1, bv1, acc[j], 0, 0, 0);
    }
    __builtin_amdgcn_s_setprio(0);
  }
  if (inv) {
    char* pp = part + (long)((((b * 8 + h) * 16 + qt) * 4 + grp)) * PSTRIDE;
    ushort_t* Cp = (ushort_t*)pp;
    float* mp = (float*)(pp + 8192);
#pragma unroll
    for (int j = 0; j < 4; ++j)
#pragma unroll
      for (int rg = 0; rg < 4; ++rg)
        Cp[(qw + quad * 4 + rg) * 64 + j * 16 + l15] = f2us(acc[j][rg]);
    if (quad == 0) { mp[qw + l15] = m_; mp[64 + qw + l15] = l_; }
  } else {
    if (quad == 0) fML[64 + qw + l15] = l_;
    floatx4 lv = *(floatx4*)&fML[64 + qw + quad * 4];
#pragma unroll
    for (int rg = 0; rg < 4; ++rg) {
      int R = qw + quad * 4 + rg;
      if (R < nvalid) {
        float invL = 1.0f / lv[rg];
#pragma unroll
        for (int j = 0; j < 4; ++j)
          out[((long)(b * Tc + q0 + R)) * Dc + h * 64 + j * 16 + l15] = f2us(acc[j][rg] * invL);
      }
    }
  }
}

// ---------------- exact split-K combine for inv partials ----------------
__global__ __launch_bounds__(256) void k_comb(const char* __restrict__ part,
    const int* __restrict__ alen, ushort_t* __restrict__ out) {
  int qt = blockIdx.x, h = blockIdx.y, b = blockIdx.z;
  int len = alen[b];
  int q0 = qt * 64;
  if (q0 + 64 <= len) return;
  int nskip = max(len - q0, 0);
  int t = threadIdx.x;
  int d = t & 63, r0 = (t >> 6) * 16;
  const char* pb = part + (long)(((b * 8 + h) * 16 + qt) * 4) * PSTRIDE;
#pragma unroll 4
  for (int i = 0; i < 16; ++i) {
    int r = r0 + i;
    if (r < nskip) continue;
    float mg[4], lg[4], M = NEGB;
#pragma unroll
    for (int g2 = 0; g2 < 4; ++g2) {
      const float* mp = (const float*)(pb + g2 * PSTRIDE + 8192);
      mg[g2] = mp[r];
      lg[g2] = mp[64 + r];
      M = fmaxf(M, mg[g2]);
    }
    float L = 0.f, wgt[4];
#pragma unroll
    for (int g2 = 0; g2 < 4; ++g2) { wgt[g2] = __expf(mg[g2] - M); L += lg[g2] * wgt[g2]; }
    float v = 0.f;
#pragma unroll
    for (int g2 = 0; g2 < 4; ++g2)
      v += us2f(((const ushort_t*)(pb + g2 * PSTRIDE))[r * 64 + d]) * wgt[g2];
    out[((long)(b * Tc + q0 + r)) * Dc + h * 64 + d] = f2us(v / L);
  }
}

// ---------------- depthwise conv (gated input [4096][512], short8) ----------------
__global__ void k_dwconv(const ushort_t* __restrict__ in, const ushort_t* __restrict__ dwT,
                         ushort_t* __restrict__ out, int n8) {
  int i = blockIdx.x * 256 + threadIdx.x;
  if (i >= n8) return;
  int row = i >> 6;            // 0..4095
  int d8 = (i & 63) << 3;
  int t = row & (Tc - 1);
  int b = row >> 10;
  float acc[8] = {0, 0, 0, 0, 0, 0, 0, 0};
#pragma unroll
  for (int j = 0; j < 9; ++j) {
    int tt = t + j - 4;
    if (tt < 0 || tt >= Tc) continue;
    short8 vv = *(const short8*)&in[((long)(b * Tc + tt) << 9) + d8];
    short8 dv = *(const short8*)&dwT[j * 512 + d8];
#pragma unroll
    for (int e = 0; e < 8; ++e)
      acc[e] += us2f((ushort_t)vv[e]) * us2f((ushort_t)dv[e]);
  }
  short8 o8;
#pragma unroll
  for (int e = 0; e < 8; ++e)
    o8[e] = (short)f2us(acc[e] * (1.0f / (1.0f + __expf(-acc[e]))));
  *(short8*)&out[(long)row * 512 + d8] = o8;
}

extern "C" void kernel_launch(void* const* d_in, const int* in_sizes, int n_in,
                              void* d_out, int out_size, void* d_ws, size_t ws_size,
                              hipStream_t stream) {
  const void* x_in = d_in[0];
  const int*  alen = (const int*)d_in[1];
  const void* ln1w = d_in[2];
  const void* ln1b = d_in[3];
  const void* wq   = d_in[4];
  const void* wk   = d_in[5];
  const void* wv   = d_in[6];
  const void* wo   = d_in[7];
  const void* rel  = d_in[8];
  const void* ln2w = d_in[9];
  const void* ln2b = d_in[10];
  const void* pw1  = d_in[11];
  const void* dwv  = d_in[12];
  const void* pw2  = d_in[13];
  const void* ln3w = d_in[14];
  const void* ln3b = d_in[15];
  const void* w1   = d_in[16];
  const void* w2   = d_in[17];

  // ---- workspace layout (bytes) ----
  char* base = (char*)d_ws;
  int*      flag = (int*)base;                       // 256
  float*    xf   = (float*)(base + 256);             // 8 MB f32 residual
  float*    lnb  = (float*)(base + 256 + 8388608);   // 8 MB f32 LN out (addend)
  ushort_t* lnA  = (ushort_t*)(base + 16777472);     // 4 MB bf16 LN out (GEMM A)
  ushort_t* wbf  = (ushort_t*)(base + 20971776);     // bf16 weights
  char*     U    = base + 45321984;                  // phase union
  // attn phase
  ushort_t* qb  = (ushort_t*)U;                      // 4 MB
  ushort_t* kvb = (ushort_t*)(U + 4194304);          // 2 MB interleaved K|V [4096][256]
  ushort_t* ab  = (ushort_t*)(U + 6291456);          // 4 MB
  char*     partA = U + 10485760;                    // 17.8 MB attn partials
  // conv/ffn phase
  ushort_t* big = (ushort_t*)U;                      // up to 8 MB (gated outputs)
  ushort_t* cb  = (ushort_t*)(U + 16777216);         // 4 MB
  size_t REQ = 45321984 + 16777216 + 4194304;
  size_t REQ2 = 45321984 + 35651584;
  if (REQ2 > REQ) REQ = REQ2;
  if (ws_size < REQ) return;

  // bf16 weight table offsets (elements)
  ushort_t* wqB   = wbf + 0;
  ushort_t* wkvB  = wbf + 1048576;   // [L][256][512] interleaved wk|wv
  ushort_t* woB   = wbf + 1572864;
  ushort_t* relB  = wbf + 2621440;
  ushort_t* pw1B  = wbf + 2719488;
  ushort_t* dwB   = wbf + 4816640;   // [L][9][512] transposed
  ushort_t* pw2B  = wbf + 4835072;
  ushort_t* w1B   = wbf + 5883648;
  ushort_t* w2B   = wbf + 10077952;

  k_detect<<<1, 256, 0, stream>>>(x_in, flag);
  k_in<<<(int)((NE + 255) / 256), 256, 0, stream>>>(x_in, xf, (int)NE, flag);
  k_w2all<<<47559, 256, 0, stream>>>(wq, wk, wv, wo, rel, pw1, dwv, pw2, w1, w2, wbf, flag);

  for (int i = 0; i < 4; ++i) {
    long oLN = (long)i * Dc;
    // ---- attention ----
    k_ln<<<NBT, 256, 0, stream>>>(xf, ln1w, ln1b, oLN, lnb, lnA, flag);
    k_gemm_b<64, 128, true><<<dim3(4, 64), 256, 0, stream>>>(lnA, Dc, wqB + (long)i * 262144, qb, Dc, nullptr, 0.125f, 512);
    k_gemm_b<64, 128, true><<<dim3(2, 64), 256, 0, stream>>>(lnA, Dc, wkvB + (long)i * 131072, kvb, 256, nullptr, 1.0f, 512);
    k_attn<<<dim3(80, 8, 4), 256, 0, stream>>>(qb, kvb, relB + (long)i * 24512, alen, ab, partA);
    k_comb<<<dim3(16, 8, 4), 256, 0, stream>>>(partA, alen, ab);
    k_gemm_b<64, 128, false><<<dim3(4, 64), 256, 0, stream>>>(ab, Dc, woB + (long)i * 262144, xf, Dc, lnb, 1.0f, 512);

    // ---- conv ----
    k_ln<<<NBT, 256, 0, stream>>>(xf, ln2w, ln2b, oLN, lnb, lnA, flag);
    k_gemm_gate<0><<<dim3(4, 64), 256, 0, stream>>>(lnA, Dc, pw1B + (long)i * 524288,
        pw1B + (long)i * 524288 + 262144, big, 512, 512);
    k_dwconv<<<NBT * 512 / 8 / 256, 256, 0, stream>>>(big, dwB + (long)i * 4608, cb, NBT * 512 / 8);
    k_gemm_b<64, 128, false><<<dim3(4, 64), 256, 0, stream>>>(cb, Dc, pw2B + (long)i * 262144, xf, Dc, lnb, 1.0f, 512);

    // ---- ffn ----
    k_ln<<<NBT, 256, 0, stream>>>(xf, ln3w, ln3b, oLN, lnb, lnA, flag);
    k_gemm_gate<1><<<dim3(8, 64), 256, 0, stream>>>(lnA, Dc, w1B + (long)i * 1048576,
        w1B + (long)i * 1048576 + 524288, big, 1024, 512);
    k_gemm_b<64, 128, false><<<dim3(4, 64), 256, 0, stream>>>(big, 1024, w2B + (long)i * 524288, xf, Dc, lnb, 1.0f, 1024);
  }

  k_out<<<(int)((NE + 255) / 256), 256, 0, stream>>>(xf, d_out, (int)NE, flag);
}

// Round 8
// 932.180 us; speedup vs baseline: 1.7487x; 1.0144x over previous
//
#include <hip/hip_runtime.h>
#include <hip/hip_bf16.h>

typedef __hip_bfloat16 bf16;
typedef unsigned short ushort_t;
typedef unsigned int uint_t;
typedef __attribute__((ext_vector_type(8))) short short8;
typedef __attribute__((ext_vector_type(4))) float floatx4;

__device__ __forceinline__ float b2f(bf16 x) { return __bfloat162float(x); }
__device__ __forceinline__ ushort_t f2us(float f) { bf16 h = __float2bfloat16(f); return *(ushort_t*)&h; }
__device__ __forceinline__ float us2f(ushort_t u) { return __uint_as_float(((uint_t)u) << 16); }

constexpr int Bc = 4, Tc = 1024, Dc = 512, Hc = 8, HDc = 64;
constexpr int LCc = 128, MPc = 192;
constexpr float EPSc = 1e-4f;
constexpr int NBT = Bc * Tc;
constexpr long NE = (long)NBT * Dc;
constexpr float NEGB = -1e30f;
constexpr int PSTRIDE = 8704;   // bytes per attention partial: 4096 bf16 C + 64 f32 m + 64 f32 l
constexpr int QSTR = 768;       // fused qkv row stride (bf16 elems): q 0..511 | K 512..639 | V 640..767

__device__ __forceinline__ float wload(const void* p, long i, int f32) {
  return f32 ? ((const float*)p)[i] : b2f(((const bf16*)p)[i]);
}

// async global->LDS staging of a ROWSx64 bf16 tile with XOR swizzle.
// LDS dest is LINEAR (global_load_lds writes base+lane*16); the swizzle is applied by
// PRE-SWIZZLING the global source chunk index (T21: source perm == read perm).
__device__ __forceinline__ void stage_swz(const ushort_t* __restrict__ G, int rowStride,
                                          int rowBase, int k0, ushort_t* L, int nChunk, int t) {
#pragma unroll
  for (int i = t; i < nChunk; i += 256) {
    int r = i >> 3;
    int cs = (i & 7) ^ (r & 7);
    const ushort_t* gp = G + (long)(rowBase + r) * rowStride + k0 + cs * 8;
    __builtin_amdgcn_global_load_lds(
        (const __attribute__((address_space(1))) void*)gp,
        (__attribute__((address_space(3))) void*)&L[(i & ~63) * 8], 16, 0, 0);
  }
}

// ---------------- dtype detector ----------------
__global__ void k_detect(const void* __restrict__ x, int* __restrict__ flag) {
  __shared__ int s[256];
  int t = threadIdx.x;
  const unsigned short* u = (const unsigned short*)x;
  int bad = 0;
  for (int j = t; j < 2048; j += 256) {
    int e = (u[j] >> 7) & 0xFF;
    if (e == 0xFF || e > 0x8F || (e != 0 && e < 0x6F)) bad++;
  }
  s[t] = bad;
  __syncthreads();
  for (int off = 128; off > 0; off >>= 1) { if (t < off) s[t] += s[t + off]; __syncthreads(); }
  if (t == 0) flag[0] = (s[0] > 16) ? 1 : 0;
}

__global__ void k_in(const void* __restrict__ in, float* __restrict__ out, int n,
                     const int* __restrict__ flag) {
  int i = blockIdx.x * 256 + threadIdx.x;
  if (i < n) out[i] = wload(in, i, flag[0]);
}
__global__ void k_out(const float* __restrict__ in, void* __restrict__ out, int n,
                      const int* __restrict__ flag) {
  int i = blockIdx.x * 256 + threadIdx.x;
  if (i >= n) return;
  if (flag[0]) ((float*)out)[i] = in[i];
  else         ((bf16*)out)[i] = __float2bfloat16(in[i]);
}

// ---------------- one-shot weight conversion (all tensors, one dispatch) ----------------
// combined element space (dst = wbf + idx):
//  [0,1572864)            qkv     [L][768][512]: r<512 -> 0.125*wq[r] (exact, pow2);
//                                 r<640 -> wk[r-512]; else wv[r-640]
//  [1572864,2621440)      wo      direct
//  [2621440,2719488)      rel     direct
//  [2719488,4816640)      pw1     direct
//  [4816640,4835072)      dw      transposed [L][9][512]
//  [4835072,5883648)      pw2     direct
//  [5883648,10077952)     w1      direct
//  [10077952,12175104)    w2      direct
__global__ void k_w2all(const void* wq, const void* wk, const void* wv, const void* wo,
                        const void* rel, const void* pw1, const void* dwv, const void* pw2,
                        const void* w1, const void* w2,
                        ushort_t* __restrict__ wbf, const int* __restrict__ flag) {
  int f32 = flag[0];
  long i = (long)blockIdx.x * 256 + threadIdx.x;
  if (i >= 12175104L) return;
  float v;
  if (i < 1572864) {
    long l = i / 393216, rem = i - l * 393216;
    int r = (int)(rem >> 9), c = (int)(rem & 511);
    if (r < 512)      v = 0.125f * wload(wq, l * 262144 + (long)r * 512 + c, f32);
    else if (r < 640) v = wload(wk, l * 65536 + (long)(r - 512) * 512 + c, f32);
    else              v = wload(wv, l * 65536 + (long)(r - 640) * 512 + c, f32);
  } else if (i < 2621440) {
    v = wload(wo, i - 1572864, f32);
  } else if (i < 2719488) {
    v = wload(rel, i - 2621440, f32);
  } else if (i < 4816640) {
    v = wload(pw1, i - 2719488, f32);
  } else if (i < 4835072) {
    long r2 = i - 4816640;
    long l = r2 / 4608, rem = r2 - l * 4608;
    int j = (int)(rem >> 9), d = (int)(rem & 511);
    v = wload(dwv, l * 4608 + (long)d * 9 + j, f32);
  } else if (i < 5883648) {
    v = wload(pw2, i - 4835072, f32);
  } else if (i < 10077952) {
    v = wload(w1, i - 5883648, f32);
  } else {
    v = wload(w2, i - 10077952, f32);
  }
  wbf[i] = f2us(v);
}

// ---------------- LayerNorm: wave-shuffle reduce, float2 loads, 2 barriers ----------------
__global__ __launch_bounds__(256) void k_ln(const float* __restrict__ x,
    const void* __restrict__ w, const void* __restrict__ bb, long woff,
    float* __restrict__ o, ushort_t* __restrict__ oA, const int* __restrict__ flag) {
  int f32 = flag[0];
  int row = blockIdx.x;
  int t = threadIdx.x;
  int lane = t & 63, wv = t >> 6;
  float2 v = ((const float2*)(x + (long)row * Dc))[t];
  float s = v.x + v.y;
#pragma unroll
  for (int o2 = 1; o2 < 64; o2 <<= 1) s += __shfl_xor(s, o2, 64);
  __shared__ float ws[8];
  if (lane == 0) ws[wv] = s;
  __syncthreads();
  float mean = (ws[0] + ws[1] + ws[2] + ws[3]) * (1.0f / Dc);
  float dx = v.x - mean, dy = v.y - mean;
  float s2 = dx * dx + dy * dy;
#pragma unroll
  for (int o2 = 1; o2 < 64; o2 <<= 1) s2 += __shfl_xor(s2, o2, 64);
  if (lane == 0) ws[4 + wv] = s2;
  __syncthreads();
  float inv = 1.0f / sqrtf((ws[4] + ws[5] + ws[6] + ws[7]) * (1.0f / Dc) + EPSc);
  float v0 = dx * inv * wload(w, woff + 2 * t, f32)     + wload(bb, woff + 2 * t, f32);
  float v1 = dy * inv * wload(w, woff + 2 * t + 1, f32) + wload(bb, woff + 2 * t + 1, f32);
  float2 ov; ov.x = v0; ov.y = v1;
  ((float2*)(o + (long)row * Dc))[t] = ov;
  ((uint_t*)(oA + (long)row * Dc))[t] = (uint_t)f2us(v0) | ((uint_t)f2us(v1) << 16);
}

// ---------------- bf16 MFMA GEMM, 2-phase double-buffered async staging ----------------
// Per K-iter: issue next tile's global_load_lds into buf^1, compute current buf, barrier.
// The barrier's vmcnt drain is covered by the MFMA phase (T3-min recipe).
template<int BM, int BN, bool OBF>
__global__ __launch_bounds__(256) void k_gemm_b(const ushort_t* __restrict__ A, int lda,
    const ushort_t* __restrict__ W, void* __restrict__ C, int ldc,
    const float* __restrict__ addend, float alpha, int K) {
  constexpr int WGM = BM / 64;
  constexpr int WGN = 4 / WGM;
  constexpr int WN = BN / WGN;
  constexpr int NJ = WN / 16;
  __shared__ ushort_t As[2][BM * 64];
  __shared__ ushort_t Ws[2][BN * 64];
  int t = threadIdx.x;
  int m0 = blockIdx.y * BM, n0 = blockIdx.x * BN;
  int lane = t & 63, wv = t >> 6;
  int l15 = lane & 15, quad = lane >> 4;
  int wrow = (WGM == 2) ? (wv >> 1) * 64 : 0;
  int wcol = (WGM == 2) ? (wv & 1) * WN : wv * WN;
  floatx4 acc[4][NJ];
#pragma unroll
  for (int i = 0; i < 4; ++i)
#pragma unroll
    for (int j = 0; j < NJ; ++j) acc[i][j] = 0;
  stage_swz(A, lda, m0, 0, As[0], BM * 8, t);
  stage_swz(W, K,  n0, 0, Ws[0], BN * 8, t);
  __syncthreads();
  int cur = 0;
  for (int k0 = 0; k0 < K; k0 += 64) {
    int nk = k0 + 64;
    if (nk < K) {
      stage_swz(A, lda, m0, nk, As[cur ^ 1], BM * 8, t);
      stage_swz(W, K,  n0, nk, Ws[cur ^ 1], BN * 8, t);
    }
    const ushort_t* Asc = As[cur];
    const ushort_t* Wsc = Ws[cur];
#pragma unroll
    for (int half = 0; half < 2; ++half) {
      int sw = ((half * 4 + quad) ^ (l15 & 7)) << 3;
      short8 af[4], bfr[NJ];
#pragma unroll
      for (int i = 0; i < 4; ++i) af[i] = *(short8*)&Asc[(wrow + i * 16 + l15) * 64 + sw];
#pragma unroll
      for (int j = 0; j < NJ; ++j) bfr[j] = *(short8*)&Wsc[(wcol + j * 16 + l15) * 64 + sw];
#pragma unroll
      for (int i = 0; i < 4; ++i)
#pragma unroll
        for (int j = 0; j < NJ; ++j)
          acc[i][j] = __builtin_amdgcn_mfma_f32_16x16x32_bf16(af[i], bfr[j], acc[i][j], 0, 0, 0);
    }
    __syncthreads();
    cur ^= 1;
  }
#pragma unroll
  for (int i = 0; i < 4; ++i) {
#pragma unroll
    for (int j = 0; j < NJ; ++j) {
#pragma unroll
      for (int rg = 0; rg < 4; ++rg) {
        int m = m0 + wrow + i * 16 + quad * 4 + rg;
        int n = n0 + wcol + j * 16 + l15;
        float v = alpha * acc[i][j][rg];
        if (addend) v += addend[(long)m * ldc + n];
        if (OBF) ((ushort_t*)C)[(long)m * ldc + n] = f2us(v);
        else     ((float*)C)[(long)m * ldc + n] = v;
      }
    }
  }
}

// ---------------- gated GEMM (2-phase dbuf): C = gate(A@Wa^T, A@Wg^T), bf16 out ----------------
// MODE 0 (glu): C = a*sigmoid(g);  MODE 1 (swiglu): C = silu(a)*g.
// BM=64, BN=64: 4 waves x 16 cols; 48KB LDS -> up to 3 blocks/CU.
template<int MODE>
__global__ __launch_bounds__(256) void k_gemm_gate(const ushort_t* __restrict__ A, int lda,
    const ushort_t* __restrict__ Wa, const ushort_t* __restrict__ Wg,
    ushort_t* __restrict__ C, int ldc, int K) {
  __shared__ ushort_t As[2][64 * 64];
  __shared__ ushort_t Wsa[2][64 * 64];
  __shared__ ushort_t Wsg[2][64 * 64];
  int t = threadIdx.x;
  int m0 = blockIdx.y * 64, n0 = blockIdx.x * 64;
  int lane = t & 63, wv = t >> 6;
  int l15 = lane & 15, quad = lane >> 4;
  int wcol = wv * 16;
  floatx4 acca[4], accg[4];
#pragma unroll
  for (int i = 0; i < 4; ++i) { acca[i] = 0; accg[i] = 0; }
  stage_swz(A, lda, m0, 0, As[0], 512, t);
  stage_swz(Wa, K, n0, 0, Wsa[0], 512, t);
  stage_swz(Wg, K, n0, 0, Wsg[0], 512, t);
  __syncthreads();
  int cur = 0;
  for (int k0 = 0; k0 < K; k0 += 64) {
    int nk = k0 + 64;
    if (nk < K) {
      stage_swz(A, lda, m0, nk, As[cur ^ 1], 512, t);
      stage_swz(Wa, K, n0, nk, Wsa[cur ^ 1], 512, t);
      stage_swz(Wg, K, n0, nk, Wsg[cur ^ 1], 512, t);
    }
    const ushort_t* Asc = As[cur];
    const ushort_t* Wac = Wsa[cur];
    const ushort_t* Wgc = Wsg[cur];
#pragma unroll
    for (int half = 0; half < 2; ++half) {
      int sw = ((half * 4 + quad) ^ (l15 & 7)) << 3;
      short8 af[4], ba, bg;
#pragma unroll
      for (int i = 0; i < 4; ++i) af[i] = *(short8*)&Asc[(i * 16 + l15) * 64 + sw];
      ba = *(short8*)&Wac[(wcol + l15) * 64 + sw];
      bg = *(short8*)&Wgc[(wcol + l15) * 64 + sw];
#pragma unroll
      for (int i = 0; i < 4; ++i) {
        acca[i] = __builtin_amdgcn_mfma_f32_16x16x32_bf16(af[i], ba, acca[i], 0, 0, 0);
        accg[i] = __builtin_amdgcn_mfma_f32_16x16x32_bf16(af[i], bg, accg[i], 0, 0, 0);
      }
    }
    __syncthreads();
    cur ^= 1;
  }
#pragma unroll
  for (int i = 0; i < 4; ++i) {
#pragma unroll
    for (int rg = 0; rg < 4; ++rg) {
      int m = m0 + i * 16 + quad * 4 + rg;
      int n = n0 + wcol + l15;
      float a = acca[i][rg], g = accg[i][rg];
      float v;
      if (MODE == 0) v = a * (1.0f / (1.0f + __expf(-g)));
      else           v = (a / (1.0f + __expf(-a))) * g;
      C[(long)m * ldc + n] = f2us(v);
    }
  }
}

// ---------------- flash attention, swapped-QK layout + grid split-K (r5-r7 structure) ----------
// qkv layout: [4096][768] bf16 — q cols 0..511, K cols 512..639 (g*64), V cols 640..767.
__global__ __launch_bounds__(256, 3) void k_attn(const ushort_t* __restrict__ qkv,
    const ushort_t* __restrict__ relL, const int* __restrict__ alen,
    ushort_t* __restrict__ out, char* __restrict__ part) {
  int bx = blockIdx.x;
  int h = blockIdx.y, b = blockIdx.z;
  int len = alen[b];
  int inv, qt, grp;
  if (bx < 16) { inv = 0; qt = bx; grp = 0; }
  else         { inv = 1; qt = (bx - 16) & 15; grp = (bx - 16) >> 4; }
  int q0 = qt * 64;
  if (inv) { if (q0 + 64 <= len) return; }
  else     { if (q0 >= len) return; }
  int nvalid = min(len - q0, 64);
  int g = h >> 2;
  __shared__ __align__(16) ushort_t UQB[8704];
  __shared__ __align__(16) ushort_t Ks[64 * 64];
  __shared__ __align__(16) ushort_t Vt[64 * 72];
  __shared__ __align__(16) ushort_t Ps[64 * 64];
  __shared__ __align__(16) float fML[128];
  ushort_t* Qs = UQB;
  ushort_t* B2t = UQB;
  int t = threadIdx.x;
  int lane = t & 63, w = t >> 6;
  int l15 = lane & 15, quad = lane >> 4;
  int qw = w * 16;
  {
    int qi = t >> 2, du = (t & 3) * 16;
    const ushort_t* src = qkv + ((long)(b * Tc + q0 + qi)) * QSTR + h * 64 + du;
    *(uint4*)&Qs[qi * 72 + du] = *(const uint4*)(src);
    *(uint4*)&Qs[qi * 72 + du + 8] = *(const uint4*)(src + 8);
  }
  const int koB = inv ? -128 : (q0 - 128);
  const int KSTEP = inv ? 4 : 1;
  const int nIt = inv ? ((grp < 2) ? 5 : 4) : 3;
  uint4 kr0, kr1, vr0, vr1;
  int kj = t >> 2, du = (t & 3) * 16, c0 = du >> 3;
  auto LOADKV = [&](int kt2) {
    int ko = koB + kt2 * 64 + kj;
    if (ko >= 0) {
      long basek = ((long)(b * Tc + ko)) * QSTR + 512 + g * 64 + du;
      kr0 = *(const uint4*)(qkv + basek);
      kr1 = *(const uint4*)(qkv + basek + 8);
      vr0 = *(const uint4*)(qkv + basek + 128);
      vr1 = *(const uint4*)(qkv + basek + 136);
    } else {
      uint4 z = {0, 0, 0, 0};
      kr0 = z; kr1 = z; vr0 = z; vr1 = z;
    }
  };
  LOADKV(grp);
  float m_ = NEGB, l_ = 0.f;
  floatx4 acc[4];
#pragma unroll
  for (int j = 0; j < 4; ++j) acc[j] = 0;
  __syncthreads();
  short8 aq0 = *(short8*)&Qs[(qw + l15) * 72 + quad * 8];
  short8 aq1 = *(short8*)&Qs[(qw + l15) * 72 + 32 + quad * 8];
  float rv_lo = 0.f, rv_hi = 0.f;
  if (inv) {
    int er = (l15 == 1) ? 382 : 0;
    short8 be0 = *(const short8*)(relL + (long)er * 64 + quad * 8);
    short8 be1 = *(const short8*)(relL + (long)er * 64 + 32 + quad * 8);
    floatx4 ec = {0.f, 0.f, 0.f, 0.f};
    ec = __builtin_amdgcn_mfma_f32_16x16x32_bf16(be0, aq0, ec, 0, 0, 0);
    ec = __builtin_amdgcn_mfma_f32_16x16x32_bf16(be1, aq1, ec, 0, 0, 0);
    rv_lo = __shfl(ec[0], l15, 64);
    rv_hi = __shfl(ec[1], l15, 64);
  }
  int sw7 = l15 & 7;
  for (int it = 0; it < nIt; ++it) {
    int kt = inv ? (grp + it * KSTEP) : it;
    int ko0 = koB + kt * 64;
    int t0 = q0 - ko0 + 191;
    bool far_hi = (q0 - ko0 - 63) >= 191;
    bool far_lo = (q0 + 63 - ko0) <= -191;
    bool near = !far_hi && !far_lo;
    int cb = min(max(t0 - 63, 0), 255);
    __syncthreads();   // A
    {
      *(uint4*)&Ks[kj * 64 + ((c0 ^ (kj & 7)) << 3)] = kr0;
      *(uint4*)&Ks[kj * 64 + (((c0 + 1) ^ (kj & 7)) << 3)] = kr1;
      uint_t wds[8] = {vr0.x, vr0.y, vr0.z, vr0.w, vr1.x, vr1.y, vr1.z, vr1.w};
#pragma unroll
      for (int u = 0; u < 8; ++u) {
        Vt[(du + 2 * u) * 72 + kj] = (ushort_t)(wds[u] & 0xffff);
        Vt[(du + 2 * u + 1) * 72 + kj] = (ushort_t)(wds[u] >> 16);
      }
    }
    if (near) {
      __builtin_amdgcn_s_setprio(1);
#pragma unroll
      for (int p = 0; p < 2; ++p) {
        short8 rw0[4], rw1[4];
#pragma unroll
        for (int j = 0; j < 4; ++j) {
          long wr = cb + (p * 4 + j) * 16 + l15;
          rw0[j] = *(const short8*)(relL + wr * 64 + quad * 8);
          rw1[j] = *(const short8*)(relL + wr * 64 + 32 + quad * 8);
        }
#pragma unroll
        for (int j = 0; j < 4; ++j) {
          floatx4 z = {0.f, 0.f, 0.f, 0.f};
          z = __builtin_amdgcn_mfma_f32_16x16x32_bf16(rw0[j], aq0, z, 0, 0, 0);
          z = __builtin_amdgcn_mfma_f32_16x16x32_bf16(rw1[j], aq1, z, 0, 0, 0);
#pragma unroll
          for (int rg = 0; rg < 4; ++rg) {
            int cpr = (p * 4 + j) * 16 + quad * 4 + rg;
            B2t[cpr * 68 + qw + l15] = f2us(z[rg]);
          }
        }
      }
      __builtin_amdgcn_s_setprio(0);
    }
    __syncthreads();   // B
    if (it + 1 < nIt) LOADKV(kt + KSTEP);
    floatx4 s[4];
    __builtin_amdgcn_s_setprio(1);
#pragma unroll
    for (int nt = 0; nt < 4; ++nt) {
      short8 ak0 = *(short8*)&Ks[(nt * 16 + l15) * 64 + ((quad ^ sw7) << 3)];
      short8 ak1 = *(short8*)&Ks[(nt * 16 + l15) * 64 + (((4 + quad) ^ sw7) << 3)];
      floatx4 z = {0.f, 0.f, 0.f, 0.f};
      z = __builtin_amdgcn_mfma_f32_16x16x32_bf16(ak0, aq0, z, 0, 0, 0);
      z = __builtin_amdgcn_mfma_f32_16x16x32_bf16(ak1, aq1, z, 0, 0, 0);
      s[nt] = z;
    }
    __builtin_amdgcn_s_setprio(0);
    if (near) {
#pragma unroll
      for (int nt = 0; nt < 4; ++nt)
#pragma unroll
        for (int rg = 0; rg < 4; ++rg) {
          int c = t0 + qw + l15 - (nt * 16 + quad * 4 + rg);
          c = min(max(c, 0), 382);
          s[nt][rg] += us2f(B2t[(c - cb) * 68 + qw + l15]);
        }
    } else {
      float rv = far_hi ? rv_hi : rv_lo;
#pragma unroll
      for (int nt = 0; nt < 4; ++nt)
#pragma unroll
        for (int rg = 0; rg < 4; ++rg) s[nt][rg] += rv;
    }
    if (!inv) {
#pragma unroll
      for (int nt = 0; nt < 4; ++nt)
#pragma unroll
        for (int rg = 0; rg < 4; ++rg) {
          int ko = ko0 + nt * 16 + quad * 4 + rg;
          if (ko >= len) s[nt][rg] = NEGB;
        }
    }
    float mx = s[0][0];
#pragma unroll
    for (int nt = 0; nt < 4; ++nt)
#pragma unroll
      for (int rg = 0; rg < 4; ++rg) mx = fmaxf(mx, s[nt][rg]);
    mx = fmaxf(mx, __shfl_xor(mx, 16, 64));
    mx = fmaxf(mx, __shfl_xor(mx, 32, 64));
    float mn = fmaxf(m_, mx);
    float al = __expf(m_ - mn);
    float ps = 0.f;
#pragma unroll
    for (int nt = 0; nt < 4; ++nt)
#pragma unroll
      for (int rg = 0; rg < 4; ++rg) {
        float p = __expf(s[nt][rg] - mn);
        s[nt][rg] = p;
        ps += p;
      }
    ps += __shfl_xor(ps, 16, 64);
    ps += __shfl_xor(ps, 32, 64);
    l_ = l_ * al + ps;
    m_ = mn;
    if (quad == 0) fML[qw + l15] = al;
#pragma unroll
    for (int nt = 0; nt < 4; ++nt)
#pragma unroll
      for (int pr = 0; pr < 2; ++pr) {
        uint_t pk = (uint_t)f2us(s[nt][2 * pr]) | ((uint_t)f2us(s[nt][2 * pr + 1]) << 16);
        int e = nt * 16 + quad * 4 + pr * 2;
        *(uint_t*)&Ps[(qw + l15) * 64 + (((e >> 3) ^ sw7) << 3) + (e & 7)] = pk;
      }
    floatx4 av = *(floatx4*)&fML[qw + quad * 4];
#pragma unroll
    for (int j = 0; j < 4; ++j)
#pragma unroll
      for (int rg = 0; rg < 4; ++rg) acc[j][rg] *= av[rg];
    short8 ap0 = *(short8*)&Ps[(qw + l15) * 64 + ((quad ^ sw7) << 3)];
    short8 ap1 = *(short8*)&Ps[(qw + l15) * 64 + (((4 + quad) ^ sw7) << 3)];
    __builtin_amdgcn_s_setprio(1);
#pragma unroll
    for (int j = 0; j < 4; ++j) {
      short8 bv0 = *(short8*)&Vt[(j * 16 + l15) * 72 + quad * 8];
      short8 bv1 = *(short8*)&Vt[(j * 16 + l15) * 72 + 32 + quad * 8];
      acc[j] = __builtin_amdgcn_mfma_f32_16x16x32_bf16(ap0, bv0, acc[j], 0, 0, 0);
      acc[j] = __builtin_amdgcn_mfma_f32_16x16x32_bf16(ap1, bv1, acc[j], 0, 0, 0);
    }
    __builtin_amdgcn_s_setprio(0);
  }
  if (inv) {
    char* pp = part + (long)((((b * 8 + h) * 16 + qt) * 4 + grp)) * PSTRIDE;
    ushort_t* Cp = (ushort_t*)pp;
    float* mp = (float*)(pp + 8192);
#pragma unroll
    for (int j = 0; j < 4; ++j)
#pragma unroll
      for (int rg = 0; rg < 4; ++rg)
        Cp[(qw + quad * 4 + rg) * 64 + j * 16 + l15] = f2us(acc[j][rg]);
    if (quad == 0) { mp[qw + l15] = m_; mp[64 + qw + l15] = l_; }
  } else {
    if (quad == 0) fML[64 + qw + l15] = l_;
    floatx4 lv = *(floatx4*)&fML[64 + qw + quad * 4];
#pragma unroll
    for (int rg = 0; rg < 4; ++rg) {
      int R = qw + quad * 4 + rg;
      if (R < nvalid) {
        float invL = 1.0f / lv[rg];
#pragma unroll
        for (int j = 0; j < 4; ++j)
          out[((long)(b * Tc + q0 + R)) * Dc + h * 64 + j * 16 + l15] = f2us(acc[j][rg] * invL);
      }
    }
  }
}

// ---------------- exact split-K combine for inv partials ----------------
__global__ __launch_bounds__(256) void k_comb(const char* __restrict__ part,
    const int* __restrict__ alen, ushort_t* __restrict__ out) {
  int qt = blockIdx.x, h = blockIdx.y, b = blockIdx.z;
  int len = alen[b];
  int q0 = qt * 64;
  if (q0 + 64 <= len) return;
  int nskip = max(len - q0, 0);
  int t = threadIdx.x;
  int d = t & 63, r0 = (t >> 6) * 16;
  const char* pb = part + (long)(((b * 8 + h) * 16 + qt) * 4) * PSTRIDE;
#pragma unroll 4
  for (int i = 0; i < 16; ++i) {
    int r = r0 + i;
    if (r < nskip) continue;
    float mg[4], lg[4], M = NEGB;
#pragma unroll
    for (int g2 = 0; g2 < 4; ++g2) {
      const float* mp = (const float*)(pb + g2 * PSTRIDE + 8192);
      mg[g2] = mp[r];
      lg[g2] = mp[64 + r];
      M = fmaxf(M, mg[g2]);
    }
    float L = 0.f, wgt[4];
#pragma unroll
    for (int g2 = 0; g2 < 4; ++g2) { wgt[g2] = __expf(mg[g2] - M); L += lg[g2] * wgt[g2]; }
    float v = 0.f;
#pragma unroll
    for (int g2 = 0; g2 < 4; ++g2)
      v += us2f(((const ushort_t*)(pb + g2 * PSTRIDE))[r * 64 + d]) * wgt[g2];
    out[((long)(b * Tc + q0 + r)) * Dc + h * 64 + d] = f2us(v / L);
  }
}

// ---------------- depthwise conv (gated input [4096][512], short8) ----------------
__global__ void k_dwconv(const ushort_t* __restrict__ in, const ushort_t* __restrict__ dwT,
                         ushort_t* __restrict__ out, int n8) {
  int i = blockIdx.x * 256 + threadIdx.x;
  if (i >= n8) return;
  int row = i >> 6;            // 0..4095
  int d8 = (i & 63) << 3;
  int t = row & (Tc - 1);
  int b = row >> 10;
  float acc[8] = {0, 0, 0, 0, 0, 0, 0, 0};
#pragma unroll
  for (int j = 0; j < 9; ++j) {
    int tt = t + j - 4;
    if (tt < 0 || tt >= Tc) continue;
    short8 vv = *(const short8*)&in[((long)(b * Tc + tt) << 9) + d8];
    short8 dv = *(const short8*)&dwT[j * 512 + d8];
#pragma unroll
    for (int e = 0; e < 8; ++e)
      acc[e] += us2f((ushort_t)vv[e]) * us2f((ushort_t)dv[e]);
  }
  short8 o8;
#pragma unroll
  for (int e = 0; e < 8; ++e)
    o8[e] = (short)f2us(acc[e] * (1.0f / (1.0f + __expf(-acc[e]))));
  *(short8*)&out[(long)row * 512 + d8] = o8;
}

extern "C" void kernel_launch(void* const* d_in, const int* in_sizes, int n_in,
                              void* d_out, int out_size, void* d_ws, size_t ws_size,
                              hipStream_t stream) {
  const void* x_in = d_in[0];
  const int*  alen = (const int*)d_in[1];
  const void* ln1w = d_in[2];
  const void* ln1b = d_in[3];
  const void* wq   = d_in[4];
  const void* wk   = d_in[5];
  const void* wv   = d_in[6];
  const void* wo   = d_in[7];
  const void* rel  = d_in[8];
  const void* ln2w = d_in[9];
  const void* ln2b = d_in[10];
  const void* pw1  = d_in[11];
  const void* dwv  = d_in[12];
  const void* pw2  = d_in[13];
  const void* ln3w = d_in[14];
  const void* ln3b = d_in[15];
  const void* w1   = d_in[16];
  const void* w2   = d_in[17];

  // ---- workspace layout (bytes) ----
  char* base = (char*)d_ws;
  int*      flag = (int*)base;                       // 256
  float*    xf   = (float*)(base + 256);             // 8 MB f32 residual
  float*    lnb  = (float*)(base + 256 + 8388608);   // 8 MB f32 LN out (addend)
  ushort_t* lnA  = (ushort_t*)(base + 16777472);     // 4 MB bf16 LN out (GEMM A)
  ushort_t* wbf  = (ushort_t*)(base + 20971776);     // bf16 weights
  char*     U    = base + 45321984;                  // phase union
  // attn phase
  ushort_t* qkv = (ushort_t*)U;                      // 6 MB fused q|K|V [4096][768]
  ushort_t* ab  = (ushort_t*)(U + 6291456);          // 4 MB
  char*     partA = U + 10485760;                    // 17.8 MB attn partials
  // conv/ffn phase
  ushort_t* big = (ushort_t*)U;                      // up to 8 MB (gated outputs)
  ushort_t* cb  = (ushort_t*)(U + 16777216);         // 4 MB
  size_t REQ = 45321984 + 16777216 + 4194304;
  size_t REQ2 = 45321984 + 35651584;
  if (REQ2 > REQ) REQ = REQ2;
  if (ws_size < REQ) return;

  // bf16 weight table offsets (elements)
  ushort_t* qkvB  = wbf + 0;         // [L][768][512] (wq pre-scaled by 0.125)
  ushort_t* woB   = wbf + 1572864;
  ushort_t* relB  = wbf + 2621440;
  ushort_t* pw1B  = wbf + 2719488;
  ushort_t* dwB   = wbf + 4816640;   // [L][9][512] transposed
  ushort_t* pw2B  = wbf + 4835072;
  ushort_t* w1B   = wbf + 5883648;
  ushort_t* w2B   = wbf + 10077952;

  k_detect<<<1, 256, 0, stream>>>(x_in, flag);
  k_in<<<(int)((NE + 255) / 256), 256, 0, stream>>>(x_in, xf, (int)NE, flag);
  k_w2all<<<47559, 256, 0, stream>>>(wq, wk, wv, wo, rel, pw1, dwv, pw2, w1, w2, wbf, flag);

  for (int i = 0; i < 4; ++i) {
    long oLN = (long)i * Dc;
    // ---- attention ----
    k_ln<<<NBT, 256, 0, stream>>>(xf, ln1w, ln1b, oLN, lnb, lnA, flag);
    k_gemm_b<64, 128, true><<<dim3(6, 64), 256, 0, stream>>>(lnA, Dc, qkvB + (long)i * 393216, qkv, QSTR, nullptr, 1.0f, 512);
    k_attn<<<dim3(80, 8, 4), 256, 0, stream>>>(qkv, relB + (long)i * 24512, alen, ab, partA);
    k_comb<<<dim3(16, 8, 4), 256, 0, stream>>>(partA, alen, ab);
    k_gemm_b<64, 128, false><<<dim3(4, 64), 256, 0, stream>>>(ab, Dc, woB + (long)i * 262144, xf, Dc, lnb, 1.0f, 512);

    // ---- conv ----
    k_ln<<<NBT, 256, 0, stream>>>(xf, ln2w, ln2b, oLN, lnb, lnA, flag);
    k_gemm_gate<0><<<dim3(8, 64), 256, 0, stream>>>(lnA, Dc, pw1B + (long)i * 524288,
        pw1B + (long)i * 524288 + 262144, big, 512, 512);
    k_dwconv<<<NBT * 512 / 8 / 256, 256, 0, stream>>>(big, dwB + (long)i * 4608, cb, NBT * 512 / 8);
    k_gemm_b<64, 128, false><<<dim3(4, 64), 256, 0, stream>>>(cb, Dc, pw2B + (long)i * 262144, xf, Dc, lnb, 1.0f, 512);

    // ---- ffn ----
    k_ln<<<NBT, 256, 0, stream>>>(xf, ln3w, ln3b, oLN, lnb, lnA, flag);
    k_gemm_gate<1><<<dim3(16, 64), 256, 0, stream>>>(lnA, Dc, w1B + (long)i * 1048576,
        w1B + (long)i * 1048576 + 524288, big, 1024, 512);
    k_gemm_b<64, 128, false><<<dim3(4, 64), 256, 0, stream>>>(big, 1024, w2B + (long)i * 524288, xf, Dc, lnb, 1.0f, 1024);
  }

  k_out<<<(int)((NE + 255) / 256), 256, 0, stream>>>(xf, d_out, (int)NE, flag);
}

// Round 9
// 833.407 us; speedup vs baseline: 1.9560x; 1.1185x over previous
//
#include <hip/hip_runtime.h>
#include <hip/hip_bf16.h>

typedef __hip_bfloat16 bf16;
typedef unsigned short ushort_t;
typedef unsigned int uint_t;
typedef __attribute__((ext_vector_type(8))) short short8;
typedef __attribute__((ext_vector_type(4))) float floatx4;

__device__ __forceinline__ float b2f(bf16 x) { return __bfloat162float(x); }
__device__ __forceinline__ ushort_t f2us(float f) { bf16 h = __float2bfloat16(f); return *(ushort_t*)&h; }
__device__ __forceinline__ float us2f(ushort_t u) { return __uint_as_float(((uint_t)u) << 16); }

constexpr int Bc = 4, Tc = 1024, Dc = 512, Hc = 8, HDc = 64;
constexpr int LCc = 128, MPc = 192;
constexpr float EPSc = 1e-4f;
constexpr int NBT = Bc * Tc;
constexpr long NE = (long)NBT * Dc;
constexpr float NEGB = -1e30f;
constexpr int PSTRIDE = 8704;   // bytes per attention partial: 4096 bf16 C + 64 f32 m + 64 f32 l
constexpr int QSTR = 768;       // fused qkv row stride: q 0..511 | K 512..639 | V 640..767

__device__ __forceinline__ float wload(const void* p, long i, int f32) {
  return f32 ? ((const float*)p)[i] : b2f(((const bf16*)p)[i]);
}

// counted vmcnt wait (T4): wait until at most N of this wave's vector-mem ops outstanding.
// NEVER vmcnt(0) inside the pipelined loop — that re-creates the barrier-drain stall.
template<int N> __device__ __forceinline__ void vmwait() {
  if constexpr (N == 0)      asm volatile("s_waitcnt vmcnt(0)" ::: "memory");
  else if constexpr (N == 4) asm volatile("s_waitcnt vmcnt(4)" ::: "memory");
  else if constexpr (N == 6) asm volatile("s_waitcnt vmcnt(6)" ::: "memory");
  else if constexpr (N == 8) asm volatile("s_waitcnt vmcnt(8)" ::: "memory");
  else if constexpr (N == 12) asm volatile("s_waitcnt vmcnt(12)" ::: "memory");
  else static_assert(N == 0, "unsupported vmcnt literal");
}

// async global->LDS staging of a ROWSx64 bf16 tile with XOR swizzle.
// LDS dest is LINEAR (global_load_lds writes base+lane*16); swizzle applied by
// PRE-SWIZZLING the global source chunk index (T21: source perm == read perm).
__device__ __forceinline__ void stage_swz(const ushort_t* __restrict__ G, int rowStride,
                                          int rowBase, int k0, ushort_t* L, int nChunk, int t) {
#pragma unroll
  for (int i = t; i < nChunk; i += 256) {
    int r = i >> 3;
    int cs = (i & 7) ^ (r & 7);
    const ushort_t* gp = G + (long)(rowBase + r) * rowStride + k0 + cs * 8;
    __builtin_amdgcn_global_load_lds(
        (const __attribute__((address_space(1))) void*)gp,
        (__attribute__((address_space(3))) void*)&L[(i & ~63) * 8], 16, 0, 0);
  }
}

// ---------------- dtype detector ----------------
__global__ void k_detect(const void* __restrict__ x, int* __restrict__ flag) {
  __shared__ int s[256];
  int t = threadIdx.x;
  const unsigned short* u = (const unsigned short*)x;
  int bad = 0;
  for (int j = t; j < 2048; j += 256) {
    int e = (u[j] >> 7) & 0xFF;
    if (e == 0xFF || e > 0x8F || (e != 0 && e < 0x6F)) bad++;
  }
  s[t] = bad;
  __syncthreads();
  for (int off = 128; off > 0; off >>= 1) { if (t < off) s[t] += s[t + off]; __syncthreads(); }
  if (t == 0) flag[0] = (s[0] > 16) ? 1 : 0;
}

__global__ void k_in(const void* __restrict__ in, float* __restrict__ out, int n,
                     const int* __restrict__ flag) {
  int i = blockIdx.x * 256 + threadIdx.x;
  if (i < n) out[i] = wload(in, i, flag[0]);
}
__global__ void k_out(const float* __restrict__ in, void* __restrict__ out, int n,
                      const int* __restrict__ flag) {
  int i = blockIdx.x * 256 + threadIdx.x;
  if (i >= n) return;
  if (flag[0]) ((float*)out)[i] = in[i];
  else         ((bf16*)out)[i] = __float2bfloat16(in[i]);
}

// ---------------- one-shot weight conversion (all tensors, one dispatch) ----------------
//  [0,1572864)            qkv     [L][768][512]: r<512 -> 0.125*wq[r] (exact, pow2);
//                                 r<640 -> wk[r-512]; else wv[r-640]
//  [1572864,2621440)      wo      direct
//  [2621440,2719488)      rel     direct
//  [2719488,4816640)      pw1     direct
//  [4816640,4835072)      dw      transposed [L][9][512]
//  [4835072,5883648)      pw2     direct
//  [5883648,10077952)     w1      direct
//  [10077952,12175104)    w2      direct
__global__ void k_w2all(const void* wq, const void* wk, const void* wv, const void* wo,
                        const void* rel, const void* pw1, const void* dwv, const void* pw2,
                        const void* w1, const void* w2,
                        ushort_t* __restrict__ wbf, const int* __restrict__ flag) {
  int f32 = flag[0];
  long i = (long)blockIdx.x * 256 + threadIdx.x;
  if (i >= 12175104L) return;
  float v;
  if (i < 1572864) {
    long l = i / 393216, rem = i - l * 393216;
    int r = (int)(rem >> 9), c = (int)(rem & 511);
    if (r < 512)      v = 0.125f * wload(wq, l * 262144 + (long)r * 512 + c, f32);
    else if (r < 640) v = wload(wk, l * 65536 + (long)(r - 512) * 512 + c, f32);
    else              v = wload(wv, l * 65536 + (long)(r - 640) * 512 + c, f32);
  } else if (i < 2621440) {
    v = wload(wo, i - 1572864, f32);
  } else if (i < 2719488) {
    v = wload(rel, i - 2621440, f32);
  } else if (i < 4816640) {
    v = wload(pw1, i - 2719488, f32);
  } else if (i < 4835072) {
    long r2 = i - 4816640;
    long l = r2 / 4608, rem = r2 - l * 4608;
    int j = (int)(rem >> 9), d = (int)(rem & 511);
    v = wload(dwv, l * 4608 + (long)d * 9 + j, f32);
  } else if (i < 5883648) {
    v = wload(pw2, i - 4835072, f32);
  } else if (i < 10077952) {
    v = wload(w1, i - 5883648, f32);
  } else {
    v = wload(w2, i - 10077952, f32);
  }
  wbf[i] = f2us(v);
}

// ---------------- LayerNorm: wave-shuffle reduce, float2 loads, 2 barriers ----------------
__global__ __launch_bounds__(256) void k_ln(const float* __restrict__ x,
    const void* __restrict__ w, const void* __restrict__ bb, long woff,
    float* __restrict__ o, ushort_t* __restrict__ oA, const int* __restrict__ flag) {
  int f32 = flag[0];
  int row = blockIdx.x;
  int t = threadIdx.x;
  int lane = t & 63, wv = t >> 6;
  float2 v = ((const float2*)(x + (long)row * Dc))[t];
  float s = v.x + v.y;
#pragma unroll
  for (int o2 = 1; o2 < 64; o2 <<= 1) s += __shfl_xor(s, o2, 64);
  __shared__ float ws[8];
  if (lane == 0) ws[wv] = s;
  __syncthreads();
  float mean = (ws[0] + ws[1] + ws[2] + ws[3]) * (1.0f / Dc);
  float dx = v.x - mean, dy = v.y - mean;
  float s2 = dx * dx + dy * dy;
#pragma unroll
  for (int o2 = 1; o2 < 64; o2 <<= 1) s2 += __shfl_xor(s2, o2, 64);
  if (lane == 0) ws[4 + wv] = s2;
  __syncthreads();
  float inv = 1.0f / sqrtf((ws[4] + ws[5] + ws[6] + ws[7]) * (1.0f / Dc) + EPSc);
  float v0 = dx * inv * wload(w, woff + 2 * t, f32)     + wload(bb, woff + 2 * t, f32);
  float v1 = dy * inv * wload(w, woff + 2 * t + 1, f32) + wload(bb, woff + 2 * t + 1, f32);
  float2 ov; ov.x = v0; ov.y = v1;
  ((float2*)(o + (long)row * Dc))[t] = ov;
  ((uint_t*)(oA + (long)row * Dc))[t] = (uint_t)f2us(v0) | ((uint_t)f2us(v1) << 16);
}

// ---------------- bf16 MFMA GEMM, counted-vmcnt 2-phase pipeline (T3-min + T4) --------------
// Per K-iter: issue next tile's global_load_lds into buf^1; s_waitcnt vmcnt(LPI) waits ONLY for
// the current tile (LPI = next tile's in-flight loads/thread); raw s_barrier (no compiler drain);
// compute; raw s_barrier. Prefetch stays in flight across the barriers.
template<int BM, int BN, bool OBF>
__global__ __launch_bounds__(256) void k_gemm_b(const ushort_t* __restrict__ A, int lda,
    const ushort_t* __restrict__ W, void* __restrict__ C, int ldc,
    const float* __restrict__ addend, float alpha, int K) {
  constexpr int WGM = BM / 64;
  constexpr int WGN = 4 / WGM;
  constexpr int WN = BN / WGN;
  constexpr int NJ = WN / 16;
  constexpr int LPI = (BM * 8 + BN * 8) / 256;
  __shared__ ushort_t As[2][BM * 64];
  __shared__ ushort_t Ws[2][BN * 64];
  int t = threadIdx.x;
  int m0 = blockIdx.y * BM, n0 = blockIdx.x * BN;
  int lane = t & 63, wv = t >> 6;
  int l15 = lane & 15, quad = lane >> 4;
  int wrow = (WGM == 2) ? (wv >> 1) * 64 : 0;
  int wcol = (WGM == 2) ? (wv & 1) * WN : wv * WN;
  floatx4 acc[4][NJ];
#pragma unroll
  for (int i = 0; i < 4; ++i)
#pragma unroll
    for (int j = 0; j < NJ; ++j) acc[i][j] = 0;
  stage_swz(A, lda, m0, 0, As[0], BM * 8, t);
  stage_swz(W, K,  n0, 0, Ws[0], BN * 8, t);
  int cur = 0;
  for (int k0 = 0; k0 < K; k0 += 64) {
    int nk = k0 + 64;
    if (nk < K) {
      stage_swz(A, lda, m0, nk, As[cur ^ 1], BM * 8, t);
      stage_swz(W, K,  n0, nk, Ws[cur ^ 1], BN * 8, t);
      vmwait<LPI>();                 // current tile landed; next tile stays in flight
    } else {
      vmwait<0>();
    }
    __builtin_amdgcn_s_barrier();
    __builtin_amdgcn_sched_barrier(0);
    const ushort_t* Asc = As[cur];
    const ushort_t* Wsc = Ws[cur];
#pragma unroll
    for (int half = 0; half < 2; ++half) {
      int sw = ((half * 4 + quad) ^ (l15 & 7)) << 3;
      short8 af[4], bfr[NJ];
#pragma unroll
      for (int i = 0; i < 4; ++i) af[i] = *(short8*)&Asc[(wrow + i * 16 + l15) * 64 + sw];
#pragma unroll
      for (int j = 0; j < NJ; ++j) bfr[j] = *(short8*)&Wsc[(wcol + j * 16 + l15) * 64 + sw];
#pragma unroll
      for (int i = 0; i < 4; ++i)
#pragma unroll
        for (int j = 0; j < NJ; ++j)
          acc[i][j] = __builtin_amdgcn_mfma_f32_16x16x32_bf16(af[i], bfr[j], acc[i][j], 0, 0, 0);
    }
    __builtin_amdgcn_s_barrier();    // all waves done reading buf[cur] before it is re-staged
    cur ^= 1;
  }
#pragma unroll
  for (int i = 0; i < 4; ++i) {
#pragma unroll
    for (int j = 0; j < NJ; ++j) {
#pragma unroll
      for (int rg = 0; rg < 4; ++rg) {
        int m = m0 + wrow + i * 16 + quad * 4 + rg;
        int n = n0 + wcol + j * 16 + l15;
        float v = alpha * acc[i][j][rg];
        if (addend) v += addend[(long)m * ldc + n];
        if (OBF) ((ushort_t*)C)[(long)m * ldc + n] = f2us(v);
        else     ((float*)C)[(long)m * ldc + n] = v;
      }
    }
  }
}

// ---------------- gated GEMM (counted-vmcnt pipeline): C = gate(A@Wa^T, A@Wg^T) -------------
// MODE 0 (glu): C = a*sigmoid(g);  MODE 1 (swiglu): C = silu(a)*g.  BM=64, BN=64.
template<int MODE>
__global__ __launch_bounds__(256) void k_gemm_gate(const ushort_t* __restrict__ A, int lda,
    const ushort_t* __restrict__ Wa, const ushort_t* __restrict__ Wg,
    ushort_t* __restrict__ C, int ldc, int K) {
  __shared__ ushort_t As[2][64 * 64];
  __shared__ ushort_t Wsa[2][64 * 64];
  __shared__ ushort_t Wsg[2][64 * 64];
  int t = threadIdx.x;
  int m0 = blockIdx.y * 64, n0 = blockIdx.x * 64;
  int lane = t & 63, wv = t >> 6;
  int l15 = lane & 15, quad = lane >> 4;
  int wcol = wv * 16;
  floatx4 acca[4], accg[4];
#pragma unroll
  for (int i = 0; i < 4; ++i) { acca[i] = 0; accg[i] = 0; }
  stage_swz(A, lda, m0, 0, As[0], 512, t);
  stage_swz(Wa, K, n0, 0, Wsa[0], 512, t);
  stage_swz(Wg, K, n0, 0, Wsg[0], 512, t);
  int cur = 0;
  for (int k0 = 0; k0 < K; k0 += 64) {
    int nk = k0 + 64;
    if (nk < K) {
      stage_swz(A, lda, m0, nk, As[cur ^ 1], 512, t);
      stage_swz(Wa, K, n0, nk, Wsa[cur ^ 1], 512, t);
      stage_swz(Wg, K, n0, nk, Wsg[cur ^ 1], 512, t);
      vmwait<6>();
    } else {
      vmwait<0>();
    }
    __builtin_amdgcn_s_barrier();
    __builtin_amdgcn_sched_barrier(0);
    const ushort_t* Asc = As[cur];
    const ushort_t* Wac = Wsa[cur];
    const ushort_t* Wgc = Wsg[cur];
#pragma unroll
    for (int half = 0; half < 2; ++half) {
      int sw = ((half * 4 + quad) ^ (l15 & 7)) << 3;
      short8 af[4], ba, bg;
#pragma unroll
      for (int i = 0; i < 4; ++i) af[i] = *(short8*)&Asc[(i * 16 + l15) * 64 + sw];
      ba = *(short8*)&Wac[(wcol + l15) * 64 + sw];
      bg = *(short8*)&Wgc[(wcol + l15) * 64 + sw];
#pragma unroll
      for (int i = 0; i < 4; ++i) {
        acca[i] = __builtin_amdgcn_mfma_f32_16x16x32_bf16(af[i], ba, acca[i], 0, 0, 0);
        accg[i] = __builtin_amdgcn_mfma_f32_16x16x32_bf16(af[i], bg, accg[i], 0, 0, 0);
      }
    }
    __builtin_amdgcn_s_barrier();
    cur ^= 1;
  }
#pragma unroll
  for (int i = 0; i < 4; ++i) {
#pragma unroll
    for (int rg = 0; rg < 4; ++rg) {
      int m = m0 + i * 16 + quad * 4 + rg;
      int n = n0 + wcol + l15;
      float a = acca[i][rg], g = accg[i][rg];
      float v;
      if (MODE == 0) v = a * (1.0f / (1.0f + __expf(-g)));
      else           v = (a / (1.0f + __expf(-a))) * g;
      C[(long)m * ldc + n] = f2us(v);
    }
  }
}

// ---------------- flash attention, swapped-QK layout + grid split-K (r5-r8 structure) ----------
// qkv layout: [4096][768] bf16 — q cols 0..511, K cols 512..639 (g*64), V cols 640..767.
__global__ __launch_bounds__(256, 3) void k_attn(const ushort_t* __restrict__ qkv,
    const ushort_t* __restrict__ relL, const int* __restrict__ alen,
    ushort_t* __restrict__ out, char* __restrict__ part) {
  int bx = blockIdx.x;
  int h = blockIdx.y, b = blockIdx.z;
  int len = alen[b];
  int inv, qt, grp;
  if (bx < 16) { inv = 0; qt = bx; grp = 0; }
  else         { inv = 1; qt = (bx - 16) & 15; grp = (bx - 16) >> 4; }
  int q0 = qt * 64;
  if (inv) { if (q0 + 64 <= len) return; }
  else     { if (q0 >= len) return; }
  int nvalid = min(len - q0, 64);
  int g = h >> 2;
  __shared__ __align__(16) ushort_t UQB[8704];
  __shared__ __align__(16) ushort_t Ks[64 * 64];
  __shared__ __align__(16) ushort_t Vt[64 * 72];
  __shared__ __align__(16) ushort_t Ps[64 * 64];
  __shared__ __align__(16) float fML[128];
  ushort_t* Qs = UQB;
  ushort_t* B2t = UQB;
  int t = threadIdx.x;
  int lane = t & 63, w = t >> 6;
  int l15 = lane & 15, quad = lane >> 4;
  int qw = w * 16;
  {
    int qi = t >> 2, du = (t & 3) * 16;
    const ushort_t* src = qkv + ((long)(b * Tc + q0 + qi)) * QSTR + h * 64 + du;
    *(uint4*)&Qs[qi * 72 + du] = *(const uint4*)(src);
    *(uint4*)&Qs[qi * 72 + du + 8] = *(const uint4*)(src + 8);
  }
  const int koB = inv ? -128 : (q0 - 128);
  const int KSTEP = inv ? 4 : 1;
  const int nIt = inv ? ((grp < 2) ? 5 : 4) : 3;
  uint4 kr0, kr1, vr0, vr1;
  int kj = t >> 2, du = (t & 3) * 16, c0 = du >> 3;
  auto LOADKV = [&](int kt2) {
    int ko = koB + kt2 * 64 + kj;
    if (ko >= 0) {
      long basek = ((long)(b * Tc + ko)) * QSTR + 512 + g * 64 + du;
      kr0 = *(const uint4*)(qkv + basek);
      kr1 = *(const uint4*)(qkv + basek + 8);
      vr0 = *(const uint4*)(qkv + basek + 128);
      vr1 = *(const uint4*)(qkv + basek + 136);
    } else {
      uint4 z = {0, 0, 0, 0};
      kr0 = z; kr1 = z; vr0 = z; vr1 = z;
    }
  };
  LOADKV(grp);
  float m_ = NEGB, l_ = 0.f;
  floatx4 acc[4];
#pragma unroll
  for (int j = 0; j < 4; ++j) acc[j] = 0;
  __syncthreads();
  short8 aq0 = *(short8*)&Qs[(qw + l15) * 72 + quad * 8];
  short8 aq1 = *(short8*)&Qs[(qw + l15) * 72 + 32 + quad * 8];
  float rv_lo = 0.f, rv_hi = 0.f;
  if (inv) {
    int er = (l15 == 1) ? 382 : 0;
    short8 be0 = *(const short8*)(relL + (long)er * 64 + quad * 8);
    short8 be1 = *(const short8*)(relL + (long)er * 64 + 32 + quad * 8);
    floatx4 ec = {0.f, 0.f, 0.f, 0.f};
    ec = __builtin_amdgcn_mfma_f32_16x16x32_bf16(be0, aq0, ec, 0, 0, 0);
    ec = __builtin_amdgcn_mfma_f32_16x16x32_bf16(be1, aq1, ec, 0, 0, 0);
    rv_lo = __shfl(ec[0], l15, 64);
    rv_hi = __shfl(ec[1], l15, 64);
  }
  int sw7 = l15 & 7;
  for (int it = 0; it < nIt; ++it) {
    int kt = inv ? (grp + it * KSTEP) : it;
    int ko0 = koB + kt * 64;
    int t0 = q0 - ko0 + 191;
    bool far_hi = (q0 - ko0 - 63) >= 191;
    bool far_lo = (q0 + 63 - ko0) <= -191;
    bool near = !far_hi && !far_lo;
    int cb = min(max(t0 - 63, 0), 255);
    __syncthreads();   // A
    {
      *(uint4*)&Ks[kj * 64 + ((c0 ^ (kj & 7)) << 3)] = kr0;
      *(uint4*)&Ks[kj * 64 + (((c0 + 1) ^ (kj & 7)) << 3)] = kr1;
      uint_t wds[8] = {vr0.x, vr0.y, vr0.z, vr0.w, vr1.x, vr1.y, vr1.z, vr1.w};
#pragma unroll
      for (int u = 0; u < 8; ++u) {
        Vt[(du + 2 * u) * 72 + kj] = (ushort_t)(wds[u] & 0xffff);
        Vt[(du + 2 * u + 1) * 72 + kj] = (ushort_t)(wds[u] >> 16);
      }
    }
    if (near) {
      __builtin_amdgcn_s_setprio(1);
#pragma unroll
      for (int p = 0; p < 2; ++p) {
        short8 rw0[4], rw1[4];
#pragma unroll
        for (int j = 0; j < 4; ++j) {
          long wr = cb + (p * 4 + j) * 16 + l15;
          rw0[j] = *(const short8*)(relL + wr * 64 + quad * 8);
          rw1[j] = *(const short8*)(relL + wr * 64 + 32 + quad * 8);
        }
#pragma unroll
        for (int j = 0; j < 4; ++j) {
          floatx4 z = {0.f, 0.f, 0.f, 0.f};
          z = __builtin_amdgcn_mfma_f32_16x16x32_bf16(rw0[j], aq0, z, 0, 0, 0);
          z = __builtin_amdgcn_mfma_f32_16x16x32_bf16(rw1[j], aq1, z, 0, 0, 0);
#pragma unroll
          for (int rg = 0; rg < 4; ++rg) {
            int cpr = (p * 4 + j) * 16 + quad * 4 + rg;
            B2t[cpr * 68 + qw + l15] = f2us(z[rg]);
          }
        }
      }
      __builtin_amdgcn_s_setprio(0);
    }
    __syncthreads();   // B
    if (it + 1 < nIt) LOADKV(kt + KSTEP);
    floatx4 s[4];
    __builtin_amdgcn_s_setprio(1);
#pragma unroll
    for (int nt = 0; nt < 4; ++nt) {
      short8 ak0 = *(short8*)&Ks[(nt * 16 + l15) * 64 + ((quad ^ sw7) << 3)];
      short8 ak1 = *(short8*)&Ks[(nt * 16 + l15) * 64 + (((4 + quad) ^ sw7) << 3)];
      floatx4 z = {0.f, 0.f, 0.f, 0.f};
      z = __builtin_amdgcn_mfma_f32_16x16x32_bf16(ak0, aq0, z, 0, 0, 0);
      z = __builtin_amdgcn_mfma_f32_16x16x32_bf16(ak1, aq1, z, 0, 0, 0);
      s[nt] = z;
    }
    __builtin_amdgcn_s_setprio(0);
    if (near) {
#pragma unroll
      for (int nt = 0; nt < 4; ++nt)
#pragma unroll
        for (int rg = 0; rg < 4; ++rg) {
          int c = t0 + qw + l15 - (nt * 16 + quad * 4 + rg);
          c = min(max(c, 0), 382);
          s[nt][rg] += us2f(B2t[(c - cb) * 68 + qw + l15]);
        }
    } else {
      float rv = far_hi ? rv_hi : rv_lo;
#pragma unroll
      for (int nt = 0; nt < 4; ++nt)
#pragma unroll
        for (int rg = 0; rg < 4; ++rg) s[nt][rg] += rv;
    }
    if (!inv) {
#pragma unroll
      for (int nt = 0; nt < 4; ++nt)
#pragma unroll
        for (int rg = 0; rg < 4; ++rg) {
          int ko = ko0 + nt * 16 + quad * 4 + rg;
          if (ko >= len) s[nt][rg] = NEGB;
        }
    }
    float mx = s[0][0];
#pragma unroll
    for (int nt = 0; nt < 4; ++nt)
#pragma unroll
      for (int rg = 0; rg < 4; ++rg) mx = fmaxf(mx, s[nt][rg]);
    mx = fmaxf(mx, __shfl_xor(mx, 16, 64));
    mx = fmaxf(mx, __shfl_xor(mx, 32, 64));
    float mn = fmaxf(m_, mx);
    float al = __expf(m_ - mn);
    float ps = 0.f;
#pragma unroll
    for (int nt = 0; nt < 4; ++nt)
#pragma unroll
      for (int rg = 0; rg < 4; ++rg) {
        float p = __expf(s[nt][rg] - mn);
        s[nt][rg] = p;
        ps += p;
      }
    ps += __shfl_xor(ps, 16, 64);
    ps += __shfl_xor(ps, 32, 64);
    l_ = l_ * al + ps;
    m_ = mn;
    if (quad == 0) fML[qw + l15] = al;
#pragma unroll
    for (int nt = 0; nt < 4; ++nt)
#pragma unroll
      for (int pr = 0; pr < 2; ++pr) {
        uint_t pk = (uint_t)f2us(s[nt][2 * pr]) | ((uint_t)f2us(s[nt][2 * pr + 1]) << 16);
        int e = nt * 16 + quad * 4 + pr * 2;
        *(uint_t*)&Ps[(qw + l15) * 64 + (((e >> 3) ^ sw7) << 3) + (e & 7)] = pk;
      }
    floatx4 av = *(floatx4*)&fML[qw + quad * 4];
#pragma unroll
    for (int j = 0; j < 4; ++j)
#pragma unroll
      for (int rg = 0; rg < 4; ++rg) acc[j][rg] *= av[rg];
    short8 ap0 = *(short8*)&Ps[(qw + l15) * 64 + ((quad ^ sw7) << 3)];
    short8 ap1 = *(short8*)&Ps[(qw + l15) * 64 + (((4 + quad) ^ sw7) << 3)];
    __builtin_amdgcn_s_setprio(1);
#pragma unroll
    for (int j = 0; j < 4; ++j) {
      short8 bv0 = *(short8*)&Vt[(j * 16 + l15) * 72 + quad * 8];
      short8 bv1 = *(short8*)&Vt[(j * 16 + l15) * 72 + 32 + quad * 8];
      acc[j] = __builtin_amdgcn_mfma_f32_16x16x32_bf16(ap0, bv0, acc[j], 0, 0, 0);
      acc[j] = __builtin_amdgcn_mfma_f32_16x16x32_bf16(ap1, bv1, acc[j], 0, 0, 0);
    }
    __builtin_amdgcn_s_setprio(0);
  }
  if (inv) {
    char* pp = part + (long)((((b * 8 + h) * 16 + qt) * 4 + grp)) * PSTRIDE;
    ushort_t* Cp = (ushort_t*)pp;
    float* mp = (float*)(pp + 8192);
#pragma unroll
    for (int j = 0; j < 4; ++j)
#pragma unroll
      for (int rg = 0; rg < 4; ++rg)
        Cp[(qw + quad * 4 + rg) * 64 + j * 16 + l15] = f2us(acc[j][rg]);
    if (quad == 0) { mp[qw + l15] = m_; mp[64 + qw + l15] = l_; }
  } else {
    if (quad == 0) fML[64 + qw + l15] = l_;
    floatx4 lv = *(floatx4*)&fML[64 + qw + quad * 4];
#pragma unroll
    for (int rg = 0; rg < 4; ++rg) {
      int R = qw + quad * 4 + rg;
      if (R < nvalid) {
        float invL = 1.0f / lv[rg];
#pragma unroll
        for (int j = 0; j < 4; ++j)
          out[((long)(b * Tc + q0 + R)) * Dc + h * 64 + j * 16 + l15] = f2us(acc[j][rg] * invL);
      }
    }
  }
}

// ---------------- exact split-K combine for inv partials ----------------
__global__ __launch_bounds__(256) void k_comb(const char* __restrict__ part,
    const int* __restrict__ alen, ushort_t* __restrict__ out) {
  int qt = blockIdx.x, h = blockIdx.y, b = blockIdx.z;
  int len = alen[b];
  int q0 = qt * 64;
  if (q0 + 64 <= len) return;
  int nskip = max(len - q0, 0);
  int t = threadIdx.x;
  int d = t & 63, r0 = (t >> 6) * 16;
  const char* pb = part + (long)(((b * 8 + h) * 16 + qt) * 4) * PSTRIDE;
#pragma unroll 4
  for (int i = 0; i < 16; ++i) {
    int r = r0 + i;
    if (r < nskip) continue;
    float mg[4], lg[4], M = NEGB;
#pragma unroll
    for (int g2 = 0; g2 < 4; ++g2) {
      const float* mp = (const float*)(pb + g2 * PSTRIDE + 8192);
      mg[g2] = mp[r];
      lg[g2] = mp[64 + r];
      M = fmaxf(M, mg[g2]);
    }
    float L = 0.f, wgt[4];
#pragma unroll
    for (int g2 = 0; g2 < 4; ++g2) { wgt[g2] = __expf(mg[g2] - M); L += lg[g2] * wgt[g2]; }
    float v = 0.f;
#pragma unroll
    for (int g2 = 0; g2 < 4; ++g2)
      v += us2f(((const ushort_t*)(pb + g2 * PSTRIDE))[r * 64 + d]) * wgt[g2];
    out[((long)(b * Tc + q0 + r)) * Dc + h * 64 + d] = f2us(v / L);
  }
}

// ---------------- depthwise conv (gated input [4096][512], short8) ----------------
__global__ void k_dwconv(const ushort_t* __restrict__ in, const ushort_t* __restrict__ dwT,
                         ushort_t* __restrict__ out, int n8) {
  int i = blockIdx.x * 256 + threadIdx.x;
  if (i >= n8) return;
  int row = i >> 6;            // 0..4095
  int d8 = (i & 63) << 3;
  int t = row & (Tc - 1);
  int b = row >> 10;
  float acc[8] = {0, 0, 0, 0, 0, 0, 0, 0};
#pragma unroll
  for (int j = 0; j < 9; ++j) {
    int tt = t + j - 4;
    if (tt < 0 || tt >= Tc) continue;
    short8 vv = *(const short8*)&in[((long)(b * Tc + tt) << 9) + d8];
    short8 dv = *(const short8*)&dwT[j * 512 + d8];
#pragma unroll
    for (int e = 0; e < 8; ++e)
      acc[e] += us2f((ushort_t)vv[e]) * us2f((ushort_t)dv[e]);
  }
  short8 o8;
#pragma unroll
  for (int e = 0; e < 8; ++e)
    o8[e] = (short)f2us(acc[e] * (1.0f / (1.0f + __expf(-acc[e]))));
  *(short8*)&out[(long)row * 512 + d8] = o8;
}

extern "C" void kernel_launch(void* const* d_in, const int* in_sizes, int n_in,
                              void* d_out, int out_size, void* d_ws, size_t ws_size,
                              hipStream_t stream) {
  const void* x_in = d_in[0];
  const int*  alen = (const int*)d_in[1];
  const void* ln1w = d_in[2];
  const void* ln1b = d_in[3];
  const void* wq   = d_in[4];
  const void* wk   = d_in[5];
  const void* wv   = d_in[6];
  const void* wo   = d_in[7];
  const void* rel  = d_in[8];
  const void* ln2w = d_in[9];
  const void* ln2b = d_in[10];
  const void* pw1  = d_in[11];
  const void* dwv  = d_in[12];
  const void* pw2  = d_in[13];
  const void* ln3w = d_in[14];
  const void* ln3b = d_in[15];
  const void* w1   = d_in[16];
  const void* w2   = d_in[17];

  // ---- workspace layout (bytes) ----
  char* base = (char*)d_ws;
  int*      flag = (int*)base;                       // 256
  float*    xf   = (float*)(base + 256);             // 8 MB f32 residual
  float*    lnb  = (float*)(base + 256 + 8388608);   // 8 MB f32 LN out (addend)
  ushort_t* lnA  = (ushort_t*)(base + 16777472);     // 4 MB bf16 LN out (GEMM A)
  ushort_t* wbf  = (ushort_t*)(base + 20971776);     // bf16 weights
  char*     U    = base + 45321984;                  // phase union
  // attn phase
  ushort_t* qkv = (ushort_t*)U;                      // 6 MB fused q|K|V [4096][768]
  ushort_t* ab  = (ushort_t*)(U + 6291456);          // 4 MB
  char*     partA = U + 10485760;                    // 17.8 MB attn partials
  // conv/ffn phase
  ushort_t* big = (ushort_t*)U;                      // up to 8 MB (gated outputs)
  ushort_t* cb  = (ushort_t*)(U + 16777216);         // 4 MB
  size_t REQ = 45321984 + 16777216 + 4194304;
  size_t REQ2 = 45321984 + 35651584;
  if (REQ2 > REQ) REQ = REQ2;
  if (ws_size < REQ) return;

  // bf16 weight table offsets (elements)
  ushort_t* qkvB  = wbf + 0;         // [L][768][512] (wq pre-scaled by 0.125)
  ushort_t* woB   = wbf + 1572864;
  ushort_t* relB  = wbf + 2621440;
  ushort_t* pw1B  = wbf + 2719488;
  ushort_t* dwB   = wbf + 4816640;   // [L][9][512] transposed
  ushort_t* pw2B  = wbf + 4835072;
  ushort_t* w1B   = wbf + 5883648;
  ushort_t* w2B   = wbf + 10077952;

  k_detect<<<1, 256, 0, stream>>>(x_in, flag);
  k_in<<<(int)((NE + 255) / 256), 256, 0, stream>>>(x_in, xf, (int)NE, flag);
  k_w2all<<<47559, 256, 0, stream>>>(wq, wk, wv, wo, rel, pw1, dwv, pw2, w1, w2, wbf, flag);

  for (int i = 0; i < 4; ++i) {
    long oLN = (long)i * Dc;
    // ---- attention ----
    k_ln<<<NBT, 256, 0, stream>>>(xf, ln1w, ln1b, oLN, lnb, lnA, flag);
    k_gemm_b<64, 64, true><<<dim3(12, 64), 256, 0, stream>>>(lnA, Dc, qkvB + (long)i * 393216, qkv, QSTR, nullptr, 1.0f, 512);
    k_attn<<<dim3(80, 8, 4), 256, 0, stream>>>(qkv, relB + (long)i * 24512, alen, ab, partA);
    k_comb<<<dim3(16, 8, 4), 256, 0, stream>>>(partA, alen, ab);
    k_gemm_b<64, 64, false><<<dim3(8, 64), 256, 0, stream>>>(ab, Dc, woB + (long)i * 262144, xf, Dc, lnb, 1.0f, 512);

    // ---- conv ----
    k_ln<<<NBT, 256, 0, stream>>>(xf, ln2w, ln2b, oLN, lnb, lnA, flag);
    k_gemm_gate<0><<<dim3(8, 64), 256, 0, stream>>>(lnA, Dc, pw1B + (long)i * 524288,
        pw1B + (long)i * 524288 + 262144, big, 512, 512);
    k_dwconv<<<NBT * 512 / 8 / 256, 256, 0, stream>>>(big, dwB + (long)i * 4608, cb, NBT * 512 / 8);
    k_gemm_b<64, 64, false><<<dim3(8, 64), 256, 0, stream>>>(cb, Dc, pw2B + (long)i * 262144, xf, Dc, lnb, 1.0f, 512);

    // ---- ffn ----
    k_ln<<<NBT, 256, 0, stream>>>(xf, ln3w, ln3b, oLN, lnb, lnA, flag);
    k_gemm_gate<1><<<dim3(16, 64), 256, 0, stream>>>(lnA, Dc, w1B + (long)i * 1048576,
        w1B + (long)i * 1048576 + 524288, big, 1024, 512);
    k_gemm_b<64, 64, false><<<dim3(8, 64), 256, 0, stream>>>(big, 1024, w2B + (long)i * 524288, xf, Dc, lnb, 1.0f, 1024);
  }

  k_out<<<(int)((NE + 255) / 256), 256, 0, stream>>>(xf, d_out, (int)NE, flag);
}